// Round 1
// 994.889 us; speedup vs baseline: 1.1720x; 1.1720x over previous
//
#include <hip/hip_runtime.h>
#include <math.h>
#include <stdint.h>

// Problem constants (B=4, T=4096, D=1024, H=16, DIM=64, L=8, KB=4, R=16, S=128)
#define TT   4096
#define DD   1024
#define HH   16
#define DIMM 64
#define SS   128

typedef short bf16x8 __attribute__((ext_vector_type(8)));
typedef float f32x4  __attribute__((ext_vector_type(4)));

// fp32 -> bf16 (RNE), finite inputs
__device__ __forceinline__ unsigned short f2bf(float f) {
    uint32_t u = __float_as_uint(f);
    return (unsigned short)((u + 0x7fffu + ((u >> 16) & 1u)) >> 16);
}

// async global->LDS, 16B per lane; LDS dest = uniform base + lane*16
#define GLD16(ldsp, gp) __builtin_amdgcn_global_load_lds( \
    (const __attribute__((address_space(1))) uint32_t*)(gp), \
    (__attribute__((address_space(3))) uint32_t*)(ldsp), 16, 0, 0)

// ---------------------------------------------------------------------------
// cvt: x fp32 -> bf16 (16,777,216 elements). 8 per thread.
// ---------------------------------------------------------------------------
__global__ __launch_bounds__(256) void cvt_k(const float* __restrict__ x,
                                             unsigned short* __restrict__ xb)
{
    const size_t i = ((size_t)blockIdx.x * 256 + threadIdx.x) * 8;
    const float4 a = *(const float4*)&x[i];
    const float4 b = *(const float4*)&x[i + 4];
    uint4 r;
    r.x = (uint32_t)f2bf(a.x) | ((uint32_t)f2bf(a.y) << 16);
    r.y = (uint32_t)f2bf(a.z) | ((uint32_t)f2bf(a.w) << 16);
    r.z = (uint32_t)f2bf(b.x) | ((uint32_t)f2bf(b.y) << 16);
    r.w = (uint32_t)f2bf(b.z) | ((uint32_t)f2bf(b.w) << 16);
    *(uint4*)&xb[i] = r;
}

// ---------------------------------------------------------------------------
// tr: W (1024x1024 fp32, K-major) -> WT (1024x1024 bf16, N-major: WT[n][k]).
// ---------------------------------------------------------------------------
__global__ __launch_bounds__(256) void tr_k(const float* __restrict__ W,
                                            unsigned short* __restrict__ WT)
{
    __shared__ unsigned short tile[32][33];
    const int bx = blockIdx.x * 32;   // W col (=n) base
    const int by = blockIdx.y * 32;   // W row (=k) base
    const int tx = threadIdx.x & 31, ty = threadIdx.x >> 5;  // ty 0..7
#pragma unroll
    for (int r = 0; r < 4; r++) {
        const int row = by + ty * 4 + r;
        tile[tx][ty * 4 + r] = f2bf(W[(size_t)row * 1024 + bx + tx]);
    }
    __syncthreads();
#pragma unroll
    for (int r = 0; r < 4; r++) {
        const int col = bx + ty * 4 + r;
        WT[(size_t)col * 1024 + by + tx] = tile[ty * 4 + r][tx];
    }
}

// ---------------------------------------------------------------------------
// bf16 MFMA GEMM: C(16384x1024) = A @ B with BT given N-major. 128x128 tile,
// BK=32, 4 waves, mfma_f32_16x16x32_bf16.
// MODE 0: epilogue mask[row] -> [b][h][t][d].  MODE 1: +bias, row-major.
// ---------------------------------------------------------------------------
template<int MODE>
__global__ __launch_bounds__(256) void mgemm_k(
    const unsigned short* __restrict__ Abf, const unsigned short* __restrict__ BT,
    const float* __restrict__ aux, float* __restrict__ C)
{
    __shared__ short sA[4096];   // 8 KB
    __shared__ short sB[4096];   // 8 KB
    const int tid = threadIdx.x;
    const int w  = tid >> 6;          // wave 0..3
    const int ln = tid & 63;          // lane
    const int wm = w & 1, wn = w >> 1;
    const int row0 = blockIdx.y * 128;
    const int col0 = blockIdx.x * 128;
    const int lr = ln >> 4, lc = ln & 15;

    f32x4 acc[4][4];
#pragma unroll
    for (int i = 0; i < 4; i++)
#pragma unroll
        for (int j = 0; j < 4; j++) acc[i][j] = (f32x4){0.f, 0.f, 0.f, 0.f};

    const int ia0 = 2 * w, ia1 = 2 * w + 1;
    const size_t gA0 = (size_t)(row0 + ia0 * 16 + lc) * 1024 + lr * 8;
    const size_t gA1 = (size_t)(row0 + ia1 * 16 + lc) * 1024 + lr * 8;
    const size_t gB0 = (size_t)(col0 + ia0 * 16 + lc) * 1024 + lr * 8;
    const size_t gB1 = (size_t)(col0 + ia1 * 16 + lc) * 1024 + lr * 8;

    for (int k0 = 0; k0 < 1024; k0 += 32) {
        GLD16(&sA[ia0 * 512], Abf + gA0 + k0);
        GLD16(&sA[ia1 * 512], Abf + gA1 + k0);
        GLD16(&sB[ia0 * 512], BT  + gB0 + k0);
        GLD16(&sB[ia1 * 512], BT  + gB1 + k0);
        __syncthreads();

        bf16x8 af[4], bfr[4];
#pragma unroll
        for (int ib = 0; ib < 4; ib++)
            af[ib] = *(const bf16x8*)&sA[(wm * 4 + ib) * 512 + ln * 8];
#pragma unroll
        for (int jb = 0; jb < 4; jb++)
            bfr[jb] = *(const bf16x8*)&sB[(wn * 4 + jb) * 512 + ln * 8];
#pragma unroll
        for (int ib = 0; ib < 4; ib++)
#pragma unroll
            for (int jb = 0; jb < 4; jb++)
                acc[ib][jb] = __builtin_amdgcn_mfma_f32_16x16x32_bf16(
                    af[ib], bfr[jb], acc[ib][jb], 0, 0, 0);
        __syncthreads();
    }

    if (MODE == 0) {
        const int h = col0 / 64 + wn;
#pragma unroll
        for (int ib = 0; ib < 4; ib++) {
#pragma unroll
            for (int r = 0; r < 4; r++) {
                const int gr = row0 + wm * 64 + ib * 16 + lr * 4 + r;
                const float mval = aux[gr];
                const int b = gr >> 12, t = gr & (TT - 1);
                float* base = C + (((size_t)(b * HH + h) * TT + t) * DIMM);
#pragma unroll
                for (int jb = 0; jb < 4; jb++)
                    base[jb * 16 + lc] = acc[ib][jb][r] * mval;
            }
        }
    } else {
#pragma unroll
        for (int ib = 0; ib < 4; ib++) {
#pragma unroll
            for (int r = 0; r < 4; r++) {
                const int gr = row0 + wm * 64 + ib * 16 + lr * 4 + r;
#pragma unroll
                for (int jb = 0; jb < 4; jb++) {
                    const int col = col0 + wn * 64 + jb * 16 + lc;
                    C[(size_t)gr * 1024 + col] = acc[ib][jb][r] + aux[col];
                }
            }
        }
    }
}

// ---------------------------------------------------------------------------
// wproj: Wproj[k][h*32+p] = sum_d Wk[k][h*64+d] * planesT[d][p].
// The assignment logits only need proj = x @ Wproj (fp32-accurate); K itself
// can then take the bf16 MFMA path since scatter rounds K to bf16 anyway.
// One block per k row: Wk row (4KB) + planesT (8KB) in LDS, 2 outputs/thread.
// ---------------------------------------------------------------------------
__global__ __launch_bounds__(256) void wproj_k(
    const float* __restrict__ Wk, const float* __restrict__ planesT,
    float* __restrict__ Wp)
{
    __shared__ float sW[1024];
    __shared__ float sP[2048];
    const int tid = threadIdx.x;
    const int k = blockIdx.x;
    for (int i = tid; i < 1024; i += 256) sW[i] = Wk[(size_t)k * 1024 + i];
    for (int i = tid; i < 2048; i += 256) sP[i] = planesT[i];
    __syncthreads();
#pragma unroll
    for (int c0 = 0; c0 < 2; c0++) {
        const int c = c0 * 256 + tid;          // 0..511
        const int h = c >> 5, p = c & 31;
        float s = 0.f;
#pragma unroll
        for (int d = 0; d < 64; d++)
            s = fmaf(sW[h * 64 + d], sP[d * 32 + p], s);
        Wp[(size_t)k * 512 + c] = s;
    }
}

// ---------------------------------------------------------------------------
// proj: P = x @ Wproj, fp32 (precision carrier for the discrete top-2
// assignment: error is fp32-reassociation-level, same class as the old fp32
// K-GEMM). M=16384, N=512, K=1024 -> 17.2 GFLOP (half the old K GEMM).
// 128x128 tile, 8x8 per thread (4x arithmetic intensity of the old 64x64
// tile), BK=8, tiny LDS (8.4 KB). Epilogue: *mask[row], scatter to
// P[((b*16+h)*4096+t)*32 + p] for assign_k's coalesced 128B/thread reads.
// ---------------------------------------------------------------------------
__global__ __launch_bounds__(256) void proj_k(
    const float* __restrict__ x, const float* __restrict__ Wp,
    const float* __restrict__ mask, float* __restrict__ P)
{
    __shared__ float As[8][132];   // [k][m], +4 pad
    __shared__ float Ws[8][132];   // [k][n], +4 pad
    const int tid = threadIdx.x;
    const int row0 = blockIdx.y * 128;
    const int col0 = blockIdx.x * 128;
    const int la_m = tid >> 1, la_k = (tid & 1) * 4;
    const int lw_k = tid >> 5, lw_n = (tid & 31) * 4;
    const int tx = tid & 15, ty = tid >> 4;   // 16x16 thread grid

    float acc[8][8];
#pragma unroll
    for (int i = 0; i < 8; i++)
#pragma unroll
        for (int j = 0; j < 8; j++) acc[i][j] = 0.f;

    for (int k0 = 0; k0 < 1024; k0 += 8) {
        const float4 av = *(const float4*)&x[(size_t)(row0 + la_m) * 1024 + k0 + la_k];
        const float4 wv = *(const float4*)&Wp[(size_t)(k0 + lw_k) * 512 + col0 + lw_n];
        __syncthreads();
        As[la_k + 0][la_m] = av.x;
        As[la_k + 1][la_m] = av.y;
        As[la_k + 2][la_m] = av.z;
        As[la_k + 3][la_m] = av.w;
        *(float4*)&Ws[lw_k][lw_n] = wv;
        __syncthreads();
#pragma unroll
        for (int kk = 0; kk < 8; kk++) {
            float ar[8], br[8];
            *(float4*)&ar[0] = *(const float4*)&As[kk][ty * 8];
            *(float4*)&ar[4] = *(const float4*)&As[kk][ty * 8 + 4];
            *(float4*)&br[0] = *(const float4*)&Ws[kk][tx * 8];
            *(float4*)&br[4] = *(const float4*)&Ws[kk][tx * 8 + 4];
#pragma unroll
            for (int i = 0; i < 8; i++)
#pragma unroll
                for (int j = 0; j < 8; j++)
                    acc[i][j] = fmaf(ar[i], br[j], acc[i][j]);
        }
    }

    // epilogue: cols tx*8..tx*8+7 stay within one h (8 | 32 alignment)
    const int h  = (col0 + tx * 8) >> 5;
    const int p0 = (col0 + tx * 8) & 31;
#pragma unroll
    for (int i = 0; i < 8; i++) {
        const int r = row0 + ty * 8 + i;
        const float mval = mask[r];
        const int b = r >> 12, t = r & (TT - 1);
        float* dst = P + (((size_t)(b * HH + h) * TT + t) * 32 + p0);
        *(float4*)&dst[0] = make_float4(acc[i][0] * mval, acc[i][1] * mval,
                                        acc[i][2] * mval, acc[i][3] * mval);
        *(float4*)&dst[4] = make_float4(acc[i][4] * mval, acc[i][5] * mval,
                                        acc[i][6] * mval, acc[i][7] * mval);
    }
}

// ---------------------------------------------------------------------------
// Zero-fill gBK ++ gBV ++ gA (contiguous, 1,056,768 floats = 1032*256*4).
// ---------------------------------------------------------------------------
__global__ __launch_bounds__(256) void zero_k(float* __restrict__ p)
{
    const size_t i = ((size_t)blockIdx.x * 256 + threadIdx.x) * 4;
    *(float4*)&p[i] = make_float4(0.f, 0.f, 0.f, 0.f);
}

// ---------------------------------------------------------------------------
// Assignment: now reads precomputed fp32 proj (128B/thread, coalesced).
// ---------------------------------------------------------------------------
__global__ __launch_bounds__(256) void assign_k(
    const float* __restrict__ Pj, const float* __restrict__ protosT,
    const float* __restrict__ logit_temp,
    unsigned char* __restrict__ aIdx, float* __restrict__ aW,
    float* __restrict__ gA)
{
    __shared__ float sPr[4][16];
    __shared__ float sCnt[SS];
    const int tid = threadIdx.x;
    const int tc = blockIdx.x;
    const int bh = blockIdx.y;

    if (tid < 64)  ((float*)sPr)[tid] = protosT[tid];
    if (tid < SS)  sCnt[tid] = 0.f;
    __syncthreads();

    const float scale = fminf(fmaxf(__expf(logit_temp[0]), 0.01f), 20.0f);
    const float inv_scale = 1.0f / scale;

    const int t = tc * 256 + tid;
    const float* pr = Pj + ((size_t)bh * TT + t) * 32;
    float proj[32];
#pragma unroll
    for (int j = 0; j < 8; j++) {
        const float4 v = *(const float4*)&pr[j * 4];
        proj[j * 4 + 0] = v.x; proj[j * 4 + 1] = v.y;
        proj[j * 4 + 2] = v.z; proj[j * 4 + 3] = v.w;
    }
#pragma unroll
    for (int p = 0; p < 32; p++) proj[p] = tanhf(proj[p]) * inv_scale;

    unsigned char idx[16];
    float wv[16];
#pragma unroll
    for (int l = 0; l < 8; l++) {
        float g[16];
#pragma unroll
        for (int r = 0; r < 16; r++)
            g[r] = proj[l * 4 + 0] * sPr[0][r] + proj[l * 4 + 1] * sPr[1][r] +
                   proj[l * 4 + 2] * sPr[2][r] + proj[l * 4 + 3] * sPr[3][r];
        float mx = g[0];
#pragma unroll
        for (int r = 1; r < 16; r++) mx = fmaxf(mx, g[r]);
        float Zs = 0.f;
#pragma unroll
        for (int r = 0; r < 16; r++) Zs += __expf(g[r] - mx);
        int a = 0; float ga = g[0];
#pragma unroll
        for (int r = 1; r < 16; r++) { if (g[r] > ga) { ga = g[r]; a = r; } }
        int b2 = (a == 0) ? 1 : 0; float gb = g[b2];
#pragma unroll
        for (int r = 0; r < 16; r++) { if (r != a && g[r] > gb) { gb = g[r]; b2 = r; } }
        const float pa = __expf(ga - mx) / Zs;
        const float pb = __expf(gb - mx) / Zs;
        const float den = pa + pb + 1e-6f;
        const float wa = pa / den, wb = pb / den;
        idx[l * 2 + 0] = (unsigned char)(l * 16 + a);  wv[l * 2 + 0] = wa;
        idx[l * 2 + 1] = (unsigned char)(l * 16 + b2); wv[l * 2 + 1] = wb;
        atomicAdd(&sCnt[l * 16 + a],  wa);
        atomicAdd(&sCnt[l * 16 + b2], wb);
    }
    const size_t off = (size_t)bh * TT + t;
    uint32_t pk[4];
#pragma unroll
    for (int j = 0; j < 4; j++)
        pk[j] = (uint32_t)idx[j * 4] | ((uint32_t)idx[j * 4 + 1] << 8) |
                ((uint32_t)idx[j * 4 + 2] << 16) | ((uint32_t)idx[j * 4 + 3] << 24);
    *(uint4*)&aIdx[off * 16] = make_uint4(pk[0], pk[1], pk[2], pk[3]);
#pragma unroll
    for (int j = 0; j < 4; j++)
        *(float4*)&aW[off * 16 + j * 4] =
            make_float4(wv[j * 4], wv[j * 4 + 1], wv[j * 4 + 2], wv[j * 4 + 3]);
    __syncthreads();
    if (tid < SS) atomicAdd(&gA[bh * SS + tid], sCnt[tid]);
}

// ---------------------------------------------------------------------------
// Scatter as MFMA GEMM: C[s][n] = sum_t P^T[s][t] * KV[t][n]  (s=128, n=128,
// t = K-dim). Grid (8 t-chunks of 512, 64 bh); per block 8 sub-chunks of 64
// tokens. Numerics: bf16 on P/KV enters bucket *averages* -> safe.
// ---------------------------------------------------------------------------
__global__ __launch_bounds__(256) void scatter4_k(
    const float* __restrict__ Kb, const float* __restrict__ Vb,
    const unsigned char* __restrict__ aIdx, const float* __restrict__ aW,
    float* __restrict__ gBK, float* __restrict__ gBV)
{
    __shared__ short sA[8192];   // P^T bf16 (16 KB): A(s,k) frag layout
    __shared__ short sB[8192];   // KV  bf16 (16 KB): B(k,n) frag layout
    const int tid = threadIdx.x;
    const int tc = blockIdx.x;   // 8
    const int bh = blockIdx.y;   // 64
    const int w  = tid >> 6, ln = tid & 63;
    const int wm = w & 1, wn = w >> 1;

    f32x4 acc[4][4];
#pragma unroll
    for (int i = 0; i < 4; i++)
#pragma unroll
        for (int j = 0; j < 4; j++) acc[i][j] = (f32x4){0.f, 0.f, 0.f, 0.f};

    const int scol = tid & 127;          // 0..127: K cols 0-63 | V cols 64-127
    const int stg  = tid >> 7;           // token half: 0..1
    const float* srcrow = (scol < 64)
        ? Kb + (size_t)bh * (TT * DIMM) + scol
        : Vb + (size_t)bh * (TT * DIMM) + (scol - 64);
    const int bchunk = (scol >> 4);       // n>>4
    const int bslot8 = (scol & 15) * 8;
    const int ptt = tid >> 2, pg = tid & 3;

    for (int c = 0; c < 8; c++) {
        const int t0 = tc * 512 + c * 64;
        __syncthreads();                              // prior MFMA reads done
        {   // zero P^T region (16 KB)
            const uint4 z = make_uint4(0u, 0u, 0u, 0u);
#pragma unroll
            for (int r = 0; r < 4; r++)
                *(uint4*)&sA[(r * 256 + tid) * 8] = z;
        }
        __syncthreads();                              // zero visible
#pragma unroll 8
        for (int r = 0; r < 32; r++) {
            const int tt = stg * 32 + r;
            const float v = srcrow[(size_t)(t0 + tt) * DIMM];
            sB[((tt >> 5) * 8 + bchunk) * 512 + ((tt >> 3) & 3) * 128 +
               bslot8 + (tt & 7)] = f2bf(v);
        }
        {   // scatter P^T: A(s = idx, k = ptt)
            const size_t off = (size_t)bh * TT + (t0 + ptt);
            const uint32_t pk = ((const uint32_t*)aIdx)[off * 4 + pg];
            const float4 wv = *(const float4*)&aW[off * 16 + pg * 4];
            const float w4[4] = {wv.x, wv.y, wv.z, wv.w};
#pragma unroll
            for (int q = 0; q < 4; q++) {
                const int s = (pk >> (8 * q)) & 255;
                sA[((ptt >> 5) * 8 + (s >> 4)) * 512 + ((ptt >> 3) & 3) * 128 +
                   (s & 15) * 8 + (ptt & 7)] = f2bf(w4[q]);
            }
        }
        __syncthreads();                              // tiles ready
#pragma unroll
        for (int ks = 0; ks < 2; ks++) {
            bf16x8 af[4], bfr[4];
#pragma unroll
            for (int ib = 0; ib < 4; ib++)
                af[ib] = *(const bf16x8*)&sA[(ks * 8 + wm * 4 + ib) * 512 + ln * 8];
#pragma unroll
            for (int jb = 0; jb < 4; jb++)
                bfr[jb] = *(const bf16x8*)&sB[(ks * 8 + wn * 4 + jb) * 512 + ln * 8];
#pragma unroll
            for (int ib = 0; ib < 4; ib++)
#pragma unroll
                for (int jb = 0; jb < 4; jb++)
                    acc[ib][jb] = __builtin_amdgcn_mfma_f32_16x16x32_bf16(
                        af[ib], bfr[jb], acc[ib][jb], 0, 0, 0);
        }
    }

    // fold partials (8 blocks per bh contend per address)
    const int lr = ln >> 4, lc = ln & 15;
#pragma unroll
    for (int ib = 0; ib < 4; ib++) {
#pragma unroll
        for (int r = 0; r < 4; r++) {
            const int s = wm * 64 + ib * 16 + lr * 4 + r;
#pragma unroll
            for (int jb = 0; jb < 4; jb++) {
                const int col = wn * 64 + jb * 16 + lc;
                if (col < 64)
                    atomicAdd(&gBK[(size_t)bh * (SS * DIMM) + s * DIMM + col],
                              acc[ib][jb][r]);
                else
                    atomicAdd(&gBV[(size_t)bh * (SS * DIMM) + s * DIMM + (col - 64)],
                              acc[ib][jb][r]);
            }
        }
    }
}

// ---------------------------------------------------------------------------
// Attention (writes bf16 att in (b, t, h*d) row-major for the out-GEMM).
// ---------------------------------------------------------------------------
__global__ __launch_bounds__(256) void attn_k(
    const float* __restrict__ Qb, const float* __restrict__ gBK,
    const float* __restrict__ gBV, const float* __restrict__ gA,
    unsigned short* __restrict__ attb)
{
    __shared__ float sBK[SS][DIMM];
    __shared__ float sBV[SS][DIMM];
    const int tid = threadIdx.x;
    const int tc = blockIdx.x;
    const int bh = blockIdx.y;
    float* sk = &sBK[0][0];
    float* sv = &sBV[0][0];
    for (int i = tid * 4; i < SS * DIMM; i += 1024) {
        const int s = i >> 6;
        const float inv = 1.0f / (gA[bh * SS + s] + 1e-6f);
        float4 kv = *(const float4*)&gBK[(size_t)bh * (SS * DIMM) + i];
        float4 vv = *(const float4*)&gBV[(size_t)bh * (SS * DIMM) + i];
        kv.x *= inv; kv.y *= inv; kv.z *= inv; kv.w *= inv;
        vv.x *= inv; vv.y *= inv; vv.z *= inv; vv.w *= inv;
        *(float4*)&sk[i] = kv;
        *(float4*)&sv[i] = vv;
    }
    __syncthreads();

    const int t = tc * 256 + tid;
    const float* q = Qb + (size_t)bh * (TT * DIMM) + (size_t)t * DIMM;
    float qr[64];
#pragma unroll
    for (int d4 = 0; d4 < 16; d4++) {
        const float4 v = *(const float4*)&q[d4 * 4];
        qr[d4 * 4 + 0] = v.x; qr[d4 * 4 + 1] = v.y; qr[d4 * 4 + 2] = v.z; qr[d4 * 4 + 3] = v.w;
    }
    float m = -INFINITY, Z = 0.f, o[64];
#pragma unroll
    for (int d = 0; d < 64; d++) o[d] = 0.f;

    for (int s = 0; s < SS; s++) {
        float sc = 0.f;
#pragma unroll
        for (int d = 0; d < 64; d++) sc = fmaf(qr[d], sBK[s][d], sc);
        sc *= 0.125f;
        const float nm = fmaxf(m, sc);
        const float corr = __expf(m - nm);
        const float p = __expf(sc - nm);
        Z = Z * corr + p;
#pragma unroll
        for (int d = 0; d < 64; d++) o[d] = fmaf(p, sBV[s][d], o[d] * corr);
        m = nm;
    }
    const float invZ = 1.0f / Z;
    const int b = bh >> 4, h = bh & 15;
    unsigned short* outp = attb + ((size_t)(b * TT + t)) * DD + h * DIMM;
#pragma unroll
    for (int d2 = 0; d2 < 32; d2++) {
        const uint32_t pk = (uint32_t)f2bf(o[d2 * 2] * invZ) |
                            ((uint32_t)f2bf(o[d2 * 2 + 1] * invZ) << 16);
        *(uint32_t*)&outp[d2 * 2] = pk;
    }
}

// ---------------------------------------------------------------------------
// Launcher. Workspace (float offsets), footprint unchanged (239.1 MB):
//   Qb 0 | Kb 1<<24 | Vb 2<<24 (later attb bf16 in first half, WoutT bf16 at
//   41943040) | gBK 3<<24 | gBV +512K | gA +512K (WT bf16 aliases gBK/gBV
//   until zero_k) | aW at 51388416 (aliases xb) | aIdx at 55582720 |
//   Wproj at 56631296 (2 MB, free tail) | xb at 51388416.
//   proj (33.5 MB) lives in d_out scratch — fully overwritten by mgemm<1>.
// ---------------------------------------------------------------------------
extern "C" void kernel_launch(void* const* d_in, const int* in_sizes, int n_in,
                              void* d_out, int out_size, void* d_ws, size_t ws_size,
                              hipStream_t stream)
{
    const float* x       = (const float*)d_in[0];
    const float* mask    = (const float*)d_in[1];
    const float* Wq      = (const float*)d_in[2];
    const float* Wk      = (const float*)d_in[3];
    const float* Wv      = (const float*)d_in[4];
    const float* Wout    = (const float*)d_in[5];
    const float* b_out   = (const float*)d_in[6];
    const float* planesT = (const float*)d_in[7];
    const float* protosT = (const float*)d_in[8];
    const float* ltemp   = (const float*)d_in[9];
    float* out = (float*)d_out;

    float* ws  = (float*)d_ws;
    float* Qb  = ws;
    float* Kb  = ws + (1u << 24);
    float* Vb  = ws + (2u << 24);
    float* gBK = ws + (3u << 24);
    float* gBV = gBK + 524288;
    float* gA  = gBV + 524288;
    unsigned short* WT1   = (unsigned short*)gBK;            // dead before zero_k
    unsigned short* WvT   = (unsigned short*)gBV;
    unsigned short* xb    = (unsigned short*)(ws + 51388416);
    float*          aW    = ws + 51388416;                   // aliases xb (xb dead)
    unsigned char*  aIdx  = (unsigned char*)(ws + 55582720);
    float*          Wproj = ws + 56631296;                   // 2 MB free tail
    unsigned short* attb  = (unsigned short*)Vb;             // Vb dead after scatter
    unsigned short* WoutT = (unsigned short*)(ws + 41943040);// Vb second half
    float*          Pj    = (float*)d_out;                   // 33.5 MB scratch

    const dim3 mg(8, 128);     // mfma gemm grid
    const dim3 tg(32, 32);     // transpose grid
    const dim3 pg(4, 128);     // proj gemm grid (N=512 / 128, M=16384 / 128)

    cvt_k<<<8192, 256, 0, stream>>>(x, xb);

    tr_k<<<tg, 256, 0, stream>>>(Wq, WT1);
    mgemm_k<0><<<mg, 256, 0, stream>>>(xb, WT1, mask, Qb);
    tr_k<<<tg, 256, 0, stream>>>(Wk, WT1);                   // reuse WT1 (serial stream)
    mgemm_k<0><<<mg, 256, 0, stream>>>(xb, WT1, mask, Kb);   // K now bf16 MFMA
    tr_k<<<tg, 256, 0, stream>>>(Wv, WvT);
    mgemm_k<0><<<mg, 256, 0, stream>>>(xb, WvT, mask, Vb);

    wproj_k<<<1024, 256, 0, stream>>>(Wk, planesT, Wproj);
    proj_k<<<pg, 256, 0, stream>>>(x, Wproj, mask, Pj);      // fp32 assignment path

    zero_k<<<1032, 256, 0, stream>>>(gBK);                   // gBK ++ gBV ++ gA
    assign_k<<<dim3(16, 64), 256, 0, stream>>>(Pj, protosT, ltemp, aIdx, aW, gA);
    scatter4_k<<<dim3(8, 64), 256, 0, stream>>>(Kb, Vb, aIdx, aW, gBK, gBV);

    tr_k<<<tg, 256, 0, stream>>>(Wout, WoutT);
    attn_k<<<dim3(16, 64), 256, 0, stream>>>(Qb, gBK, gBV, gA, attb);

    mgemm_k<1><<<mg, 256, 0, stream>>>(attb, WoutT, b_out, out);
}

// Round 2
// 866.726 us; speedup vs baseline: 1.3453x; 1.1479x over previous
//
#include <hip/hip_runtime.h>
#include <math.h>
#include <stdint.h>

// Problem constants (B=4, T=4096, D=1024, H=16, DIM=64, L=8, KB=4, R=16, S=128)
#define TT   4096
#define DD   1024
#define HH   16
#define DIMM 64
#define SS   128

typedef short bf16x8 __attribute__((ext_vector_type(8)));
typedef float f32x4  __attribute__((ext_vector_type(4)));

// fp32 -> bf16 (RNE), finite inputs
__device__ __forceinline__ unsigned short f2bf(float f) {
    uint32_t u = __float_as_uint(f);
    return (unsigned short)((u + 0x7fffu + ((u >> 16) & 1u)) >> 16);
}
__device__ __forceinline__ float bf2f(unsigned short h) {
    return __uint_as_float((uint32_t)h << 16);
}

// async global->LDS, 16B per lane; LDS dest = uniform base + lane*16
#define GLD16(ldsp, gp) __builtin_amdgcn_global_load_lds( \
    (const __attribute__((address_space(1))) uint32_t*)(gp), \
    (__attribute__((address_space(3))) uint32_t*)(ldsp), 16, 0, 0)

// ---------------------------------------------------------------------------
// cvt2: x fp32 -> bf16 hi (xb) + bf16 lo residual (xlo). 8 per thread.
// lo = bf16(x - fp32(hi)): together ~2^-17 relative representation error,
// feeds the error-compensated MFMA proj GEMM.
// ---------------------------------------------------------------------------
__global__ __launch_bounds__(256) void cvt2_k(const float* __restrict__ x,
                                              unsigned short* __restrict__ xb,
                                              unsigned short* __restrict__ xlo)
{
    const size_t i = ((size_t)blockIdx.x * 256 + threadIdx.x) * 8;
    const float4 a = *(const float4*)&x[i];
    const float4 b = *(const float4*)&x[i + 4];
    const float v[8] = {a.x, a.y, a.z, a.w, b.x, b.y, b.z, b.w};
    unsigned short h[8], l[8];
#pragma unroll
    for (int j = 0; j < 8; j++) {
        h[j] = f2bf(v[j]);
        l[j] = f2bf(v[j] - bf2f(h[j]));
    }
    uint4 rh, rl;
    rh.x = (uint32_t)h[0] | ((uint32_t)h[1] << 16);
    rh.y = (uint32_t)h[2] | ((uint32_t)h[3] << 16);
    rh.z = (uint32_t)h[4] | ((uint32_t)h[5] << 16);
    rh.w = (uint32_t)h[6] | ((uint32_t)h[7] << 16);
    rl.x = (uint32_t)l[0] | ((uint32_t)l[1] << 16);
    rl.y = (uint32_t)l[2] | ((uint32_t)l[3] << 16);
    rl.z = (uint32_t)l[4] | ((uint32_t)l[5] << 16);
    rl.w = (uint32_t)l[6] | ((uint32_t)l[7] << 16);
    *(uint4*)&xb[i]  = rh;
    *(uint4*)&xlo[i] = rl;
}

// ---------------------------------------------------------------------------
// tr: W (1024x1024 fp32, K-major) -> WT (1024x1024 bf16, N-major: WT[n][k]).
// ---------------------------------------------------------------------------
__global__ __launch_bounds__(256) void tr_k(const float* __restrict__ W,
                                            unsigned short* __restrict__ WT)
{
    __shared__ unsigned short tile[32][33];
    const int bx = blockIdx.x * 32;   // W col (=n) base
    const int by = blockIdx.y * 32;   // W row (=k) base
    const int tx = threadIdx.x & 31, ty = threadIdx.x >> 5;  // ty 0..7
#pragma unroll
    for (int r = 0; r < 4; r++) {
        const int row = by + ty * 4 + r;
        tile[tx][ty * 4 + r] = f2bf(W[(size_t)row * 1024 + bx + tx]);
    }
    __syncthreads();
#pragma unroll
    for (int r = 0; r < 4; r++) {
        const int col = bx + ty * 4 + r;
        WT[(size_t)col * 1024 + by + tx] = tile[ty * 4 + r][tx];
    }
}

// ---------------------------------------------------------------------------
// tr2: Wp (1024x512 fp32, K-major) -> WphT/WplT (512x1024 bf16 hi/lo,
// N-major). hi = bf16(w), lo = bf16(w - fp32(hi)).
// ---------------------------------------------------------------------------
__global__ __launch_bounds__(256) void tr2_k(const float* __restrict__ Wp,
                                             unsigned short* __restrict__ WphT,
                                             unsigned short* __restrict__ WplT)
{
    __shared__ float tile[32][33];
    const int bx = blockIdx.x * 32;   // n base (0..511)
    const int by = blockIdx.y * 32;   // k base (0..1023)
    const int tx = threadIdx.x & 31, ty = threadIdx.x >> 5;  // ty 0..7
#pragma unroll
    for (int r = 0; r < 4; r++) {
        const int row = by + ty * 4 + r;
        tile[tx][ty * 4 + r] = Wp[(size_t)row * 512 + bx + tx];
    }
    __syncthreads();
#pragma unroll
    for (int r = 0; r < 4; r++) {
        const int col = bx + ty * 4 + r;      // n
        const float v = tile[ty * 4 + r][tx];
        const unsigned short hi = f2bf(v);
        const unsigned short lo = f2bf(v - bf2f(hi));
        WphT[(size_t)col * 1024 + by + tx] = hi;
        WplT[(size_t)col * 1024 + by + tx] = lo;
    }
}

// ---------------------------------------------------------------------------
// bf16 MFMA GEMM: C(16384x1024) = A @ B with BT given N-major. 128x128 tile,
// BK=32, 4 waves, mfma_f32_16x16x32_bf16.
// MODE 0: epilogue mask[row] -> [b][h][t][d].  MODE 1: +bias, row-major.
// ---------------------------------------------------------------------------
template<int MODE>
__global__ __launch_bounds__(256) void mgemm_k(
    const unsigned short* __restrict__ Abf, const unsigned short* __restrict__ BT,
    const float* __restrict__ aux, float* __restrict__ C)
{
    __shared__ short sA[4096];   // 8 KB
    __shared__ short sB[4096];   // 8 KB
    const int tid = threadIdx.x;
    const int w  = tid >> 6;          // wave 0..3
    const int ln = tid & 63;          // lane
    const int wm = w & 1, wn = w >> 1;
    const int row0 = blockIdx.y * 128;
    const int col0 = blockIdx.x * 128;
    const int lr = ln >> 4, lc = ln & 15;

    f32x4 acc[4][4];
#pragma unroll
    for (int i = 0; i < 4; i++)
#pragma unroll
        for (int j = 0; j < 4; j++) acc[i][j] = (f32x4){0.f, 0.f, 0.f, 0.f};

    const int ia0 = 2 * w, ia1 = 2 * w + 1;
    const size_t gA0 = (size_t)(row0 + ia0 * 16 + lc) * 1024 + lr * 8;
    const size_t gA1 = (size_t)(row0 + ia1 * 16 + lc) * 1024 + lr * 8;
    const size_t gB0 = (size_t)(col0 + ia0 * 16 + lc) * 1024 + lr * 8;
    const size_t gB1 = (size_t)(col0 + ia1 * 16 + lc) * 1024 + lr * 8;

    for (int k0 = 0; k0 < 1024; k0 += 32) {
        GLD16(&sA[ia0 * 512], Abf + gA0 + k0);
        GLD16(&sA[ia1 * 512], Abf + gA1 + k0);
        GLD16(&sB[ia0 * 512], BT  + gB0 + k0);
        GLD16(&sB[ia1 * 512], BT  + gB1 + k0);
        __syncthreads();

        bf16x8 af[4], bfr[4];
#pragma unroll
        for (int ib = 0; ib < 4; ib++)
            af[ib] = *(const bf16x8*)&sA[(wm * 4 + ib) * 512 + ln * 8];
#pragma unroll
        for (int jb = 0; jb < 4; jb++)
            bfr[jb] = *(const bf16x8*)&sB[(wn * 4 + jb) * 512 + ln * 8];
#pragma unroll
        for (int ib = 0; ib < 4; ib++)
#pragma unroll
            for (int jb = 0; jb < 4; jb++)
                acc[ib][jb] = __builtin_amdgcn_mfma_f32_16x16x32_bf16(
                    af[ib], bfr[jb], acc[ib][jb], 0, 0, 0);
        __syncthreads();
    }

    if (MODE == 0) {
        const int h = col0 / 64 + wn;
#pragma unroll
        for (int ib = 0; ib < 4; ib++) {
#pragma unroll
            for (int r = 0; r < 4; r++) {
                const int gr = row0 + wm * 64 + ib * 16 + lr * 4 + r;
                const float mval = aux[gr];
                const int b = gr >> 12, t = gr & (TT - 1);
                float* base = C + (((size_t)(b * HH + h) * TT + t) * DIMM);
#pragma unroll
                for (int jb = 0; jb < 4; jb++)
                    base[jb * 16 + lc] = acc[ib][jb][r] * mval;
            }
        }
    } else {
#pragma unroll
        for (int ib = 0; ib < 4; ib++) {
#pragma unroll
            for (int r = 0; r < 4; r++) {
                const int gr = row0 + wm * 64 + ib * 16 + lr * 4 + r;
#pragma unroll
                for (int jb = 0; jb < 4; jb++) {
                    const int col = col0 + wn * 64 + jb * 16 + lc;
                    C[(size_t)gr * 1024 + col] = acc[ib][jb][r] + aux[col];
                }
            }
        }
    }
}

// ---------------------------------------------------------------------------
// projm: error-compensated bf16x2 MFMA GEMM for the assignment projections.
// P(16384x512) = (xh+xl) @ (Wh+Wl) ~= xh@Wh + xh@Wl + xl@Wh  (fp32 MFMA acc,
// ~2^-17 input representation error -> proj noise ~1e-4 abs, far below the
// plain-bf16 noise that flips saturated-tanh top-2 gaps).
// Same tile structure as mgemm_k; 3 MFMA per fragment pair; grid (4,128).
// Epilogue: *mask[row], scatter to P[((b*16+h)*4096+t)*32 + p].
// ---------------------------------------------------------------------------
__global__ __launch_bounds__(256) void projm_k(
    const unsigned short* __restrict__ Ah, const unsigned short* __restrict__ Al,
    const unsigned short* __restrict__ Bh, const unsigned short* __restrict__ Bl,
    const float* __restrict__ mask, float* __restrict__ P)
{
    __shared__ short sAh[4096];  // 8 KB each, 32 KB total
    __shared__ short sAl[4096];
    __shared__ short sBh[4096];
    __shared__ short sBl[4096];
    const int tid = threadIdx.x;
    const int w  = tid >> 6;
    const int ln = tid & 63;
    const int wm = w & 1, wn = w >> 1;
    const int row0 = blockIdx.y * 128;
    const int col0 = blockIdx.x * 128;
    const int lr = ln >> 4, lc = ln & 15;

    f32x4 acc[4][4];
#pragma unroll
    for (int i = 0; i < 4; i++)
#pragma unroll
        for (int j = 0; j < 4; j++) acc[i][j] = (f32x4){0.f, 0.f, 0.f, 0.f};

    const int ia0 = 2 * w, ia1 = 2 * w + 1;
    const size_t gA0 = (size_t)(row0 + ia0 * 16 + lc) * 1024 + lr * 8;
    const size_t gA1 = (size_t)(row0 + ia1 * 16 + lc) * 1024 + lr * 8;
    const size_t gB0 = (size_t)(col0 + ia0 * 16 + lc) * 1024 + lr * 8;
    const size_t gB1 = (size_t)(col0 + ia1 * 16 + lc) * 1024 + lr * 8;

    for (int k0 = 0; k0 < 1024; k0 += 32) {
        GLD16(&sAh[ia0 * 512], Ah + gA0 + k0);
        GLD16(&sAh[ia1 * 512], Ah + gA1 + k0);
        GLD16(&sAl[ia0 * 512], Al + gA0 + k0);
        GLD16(&sAl[ia1 * 512], Al + gA1 + k0);
        GLD16(&sBh[ia0 * 512], Bh + gB0 + k0);
        GLD16(&sBh[ia1 * 512], Bh + gB1 + k0);
        GLD16(&sBl[ia0 * 512], Bl + gB0 + k0);
        GLD16(&sBl[ia1 * 512], Bl + gB1 + k0);
        __syncthreads();

        bf16x8 ah[4], al[4], bh[4], bl[4];
#pragma unroll
        for (int ib = 0; ib < 4; ib++) {
            ah[ib] = *(const bf16x8*)&sAh[(wm * 4 + ib) * 512 + ln * 8];
            al[ib] = *(const bf16x8*)&sAl[(wm * 4 + ib) * 512 + ln * 8];
        }
#pragma unroll
        for (int jb = 0; jb < 4; jb++) {
            bh[jb] = *(const bf16x8*)&sBh[(wn * 4 + jb) * 512 + ln * 8];
            bl[jb] = *(const bf16x8*)&sBl[(wn * 4 + jb) * 512 + ln * 8];
        }
#pragma unroll
        for (int ib = 0; ib < 4; ib++)
#pragma unroll
            for (int jb = 0; jb < 4; jb++) {
                acc[ib][jb] = __builtin_amdgcn_mfma_f32_16x16x32_bf16(
                    ah[ib], bh[jb], acc[ib][jb], 0, 0, 0);
                acc[ib][jb] = __builtin_amdgcn_mfma_f32_16x16x32_bf16(
                    ah[ib], bl[jb], acc[ib][jb], 0, 0, 0);
                acc[ib][jb] = __builtin_amdgcn_mfma_f32_16x16x32_bf16(
                    al[ib], bh[jb], acc[ib][jb], 0, 0, 0);
            }
        __syncthreads();
    }

#pragma unroll
    for (int ib = 0; ib < 4; ib++) {
#pragma unroll
        for (int r = 0; r < 4; r++) {
            const int gr = row0 + wm * 64 + ib * 16 + lr * 4 + r;
            const float mval = mask[gr];
            const int b = gr >> 12, t = gr & (TT - 1);
#pragma unroll
            for (int jb = 0; jb < 4; jb++) {
                const int c = col0 + wn * 64 + jb * 16 + lc;   // 0..511
                const int h = c >> 5, p = c & 31;
                P[(((size_t)(b * HH + h) * TT + t) * 32) + p] =
                    acc[ib][jb][r] * mval;
            }
        }
    }
}

// ---------------------------------------------------------------------------
// wproj: Wproj[k][h*32+p] = sum_d Wk[k][h*64+d] * planesT[d][p].  (fp32)
// ---------------------------------------------------------------------------
__global__ __launch_bounds__(256) void wproj_k(
    const float* __restrict__ Wk, const float* __restrict__ planesT,
    float* __restrict__ Wp)
{
    __shared__ float sW[1024];
    __shared__ float sP[2048];
    const int tid = threadIdx.x;
    const int k = blockIdx.x;
    for (int i = tid; i < 1024; i += 256) sW[i] = Wk[(size_t)k * 1024 + i];
    for (int i = tid; i < 2048; i += 256) sP[i] = planesT[i];
    __syncthreads();
#pragma unroll
    for (int c0 = 0; c0 < 2; c0++) {
        const int c = c0 * 256 + tid;          // 0..511
        const int h = c >> 5, p = c & 31;
        float s = 0.f;
#pragma unroll
        for (int d = 0; d < 64; d++)
            s = fmaf(sW[h * 64 + d], sP[d * 32 + p], s);
        Wp[(size_t)k * 512 + c] = s;
    }
}

// ---------------------------------------------------------------------------
// Zero-fill gBK ++ gBV ++ gA (contiguous, 1,056,768 floats = 1032*256*4).
// ---------------------------------------------------------------------------
__global__ __launch_bounds__(256) void zero_k(float* __restrict__ p)
{
    const size_t i = ((size_t)blockIdx.x * 256 + threadIdx.x) * 4;
    *(float4*)&p[i] = make_float4(0.f, 0.f, 0.f, 0.f);
}

// ---------------------------------------------------------------------------
// Assignment: reads precomputed fp32-accurate proj (128B/thread, coalesced).
// ---------------------------------------------------------------------------
__global__ __launch_bounds__(256) void assign_k(
    const float* __restrict__ Pj, const float* __restrict__ protosT,
    const float* __restrict__ logit_temp,
    unsigned char* __restrict__ aIdx, float* __restrict__ aW,
    float* __restrict__ gA)
{
    __shared__ float sPr[4][16];
    __shared__ float sCnt[SS];
    const int tid = threadIdx.x;
    const int tc = blockIdx.x;
    const int bh = blockIdx.y;

    if (tid < 64)  ((float*)sPr)[tid] = protosT[tid];
    if (tid < SS)  sCnt[tid] = 0.f;
    __syncthreads();

    const float scale = fminf(fmaxf(__expf(logit_temp[0]), 0.01f), 20.0f);
    const float inv_scale = 1.0f / scale;

    const int t = tc * 256 + tid;
    const float* pr = Pj + ((size_t)bh * TT + t) * 32;
    float proj[32];
#pragma unroll
    for (int j = 0; j < 8; j++) {
        const float4 v = *(const float4*)&pr[j * 4];
        proj[j * 4 + 0] = v.x; proj[j * 4 + 1] = v.y;
        proj[j * 4 + 2] = v.z; proj[j * 4 + 3] = v.w;
    }
#pragma unroll
    for (int p = 0; p < 32; p++) proj[p] = tanhf(proj[p]) * inv_scale;

    unsigned char idx[16];
    float wv[16];
#pragma unroll
    for (int l = 0; l < 8; l++) {
        float g[16];
#pragma unroll
        for (int r = 0; r < 16; r++)
            g[r] = proj[l * 4 + 0] * sPr[0][r] + proj[l * 4 + 1] * sPr[1][r] +
                   proj[l * 4 + 2] * sPr[2][r] + proj[l * 4 + 3] * sPr[3][r];
        float mx = g[0];
#pragma unroll
        for (int r = 1; r < 16; r++) mx = fmaxf(mx, g[r]);
        float Zs = 0.f;
#pragma unroll
        for (int r = 0; r < 16; r++) Zs += __expf(g[r] - mx);
        int a = 0; float ga = g[0];
#pragma unroll
        for (int r = 1; r < 16; r++) { if (g[r] > ga) { ga = g[r]; a = r; } }
        int b2 = (a == 0) ? 1 : 0; float gb = g[b2];
#pragma unroll
        for (int r = 0; r < 16; r++) { if (r != a && g[r] > gb) { gb = g[r]; b2 = r; } }
        const float pa = __expf(ga - mx) / Zs;
        const float pb = __expf(gb - mx) / Zs;
        const float den = pa + pb + 1e-6f;
        const float wa = pa / den, wb = pb / den;
        idx[l * 2 + 0] = (unsigned char)(l * 16 + a);  wv[l * 2 + 0] = wa;
        idx[l * 2 + 1] = (unsigned char)(l * 16 + b2); wv[l * 2 + 1] = wb;
        atomicAdd(&sCnt[l * 16 + a],  wa);
        atomicAdd(&sCnt[l * 16 + b2], wb);
    }
    const size_t off = (size_t)bh * TT + t;
    uint32_t pk[4];
#pragma unroll
    for (int j = 0; j < 4; j++)
        pk[j] = (uint32_t)idx[j * 4] | ((uint32_t)idx[j * 4 + 1] << 8) |
                ((uint32_t)idx[j * 4 + 2] << 16) | ((uint32_t)idx[j * 4 + 3] << 24);
    *(uint4*)&aIdx[off * 16] = make_uint4(pk[0], pk[1], pk[2], pk[3]);
#pragma unroll
    for (int j = 0; j < 4; j++)
        *(float4*)&aW[off * 16 + j * 4] =
            make_float4(wv[j * 4], wv[j * 4 + 1], wv[j * 4 + 2], wv[j * 4 + 3]);
    __syncthreads();
    if (tid < SS) atomicAdd(&gA[bh * SS + tid], sCnt[tid]);
}

// ---------------------------------------------------------------------------
// Scatter as MFMA GEMM: C[s][n] = sum_t P^T[s][t] * KV[t][n]  (s=128, n=128,
// t = K-dim). Grid (8 t-chunks of 512, 64 bh); per block 8 sub-chunks of 64
// tokens. Numerics: bf16 on P/KV enters bucket *averages* -> safe.
// ---------------------------------------------------------------------------
__global__ __launch_bounds__(256) void scatter4_k(
    const float* __restrict__ Kb, const float* __restrict__ Vb,
    const unsigned char* __restrict__ aIdx, const float* __restrict__ aW,
    float* __restrict__ gBK, float* __restrict__ gBV)
{
    __shared__ short sA[8192];   // P^T bf16 (16 KB): A(s,k) frag layout
    __shared__ short sB[8192];   // KV  bf16 (16 KB): B(k,n) frag layout
    const int tid = threadIdx.x;
    const int tc = blockIdx.x;   // 8
    const int bh = blockIdx.y;   // 64
    const int w  = tid >> 6, ln = tid & 63;
    const int wm = w & 1, wn = w >> 1;

    f32x4 acc[4][4];
#pragma unroll
    for (int i = 0; i < 4; i++)
#pragma unroll
        for (int j = 0; j < 4; j++) acc[i][j] = (f32x4){0.f, 0.f, 0.f, 0.f};

    const int scol = tid & 127;          // 0..127: K cols 0-63 | V cols 64-127
    const int stg  = tid >> 7;           // token half: 0..1
    const float* srcrow = (scol < 64)
        ? Kb + (size_t)bh * (TT * DIMM) + scol
        : Vb + (size_t)bh * (TT * DIMM) + (scol - 64);
    const int bchunk = (scol >> 4);       // n>>4
    const int bslot8 = (scol & 15) * 8;
    const int ptt = tid >> 2, pg = tid & 3;

    for (int c = 0; c < 8; c++) {
        const int t0 = tc * 512 + c * 64;
        __syncthreads();                              // prior MFMA reads done
        {   // zero P^T region (16 KB)
            const uint4 z = make_uint4(0u, 0u, 0u, 0u);
#pragma unroll
            for (int r = 0; r < 4; r++)
                *(uint4*)&sA[(r * 256 + tid) * 8] = z;
        }
        __syncthreads();                              // zero visible
#pragma unroll 8
        for (int r = 0; r < 32; r++) {
            const int tt = stg * 32 + r;
            const float v = srcrow[(size_t)(t0 + tt) * DIMM];
            sB[((tt >> 5) * 8 + bchunk) * 512 + ((tt >> 3) & 3) * 128 +
               bslot8 + (tt & 7)] = f2bf(v);
        }
        {   // scatter P^T: A(s = idx, k = ptt)
            const size_t off = (size_t)bh * TT + (t0 + ptt);
            const uint32_t pk = ((const uint32_t*)aIdx)[off * 4 + pg];
            const float4 wv = *(const float4*)&aW[off * 16 + pg * 4];
            const float w4[4] = {wv.x, wv.y, wv.z, wv.w};
#pragma unroll
            for (int q = 0; q < 4; q++) {
                const int s = (pk >> (8 * q)) & 255;
                sA[((ptt >> 5) * 8 + (s >> 4)) * 512 + ((ptt >> 3) & 3) * 128 +
                   (s & 15) * 8 + (ptt & 7)] = f2bf(w4[q]);
            }
        }
        __syncthreads();                              // tiles ready
#pragma unroll
        for (int ks = 0; ks < 2; ks++) {
            bf16x8 af[4], bfr[4];
#pragma unroll
            for (int ib = 0; ib < 4; ib++)
                af[ib] = *(const bf16x8*)&sA[(ks * 8 + wm * 4 + ib) * 512 + ln * 8];
#pragma unroll
            for (int jb = 0; jb < 4; jb++)
                bfr[jb] = *(const bf16x8*)&sB[(ks * 8 + wn * 4 + jb) * 512 + ln * 8];
#pragma unroll
            for (int ib = 0; ib < 4; ib++)
#pragma unroll
                for (int jb = 0; jb < 4; jb++)
                    acc[ib][jb] = __builtin_amdgcn_mfma_f32_16x16x32_bf16(
                        af[ib], bfr[jb], acc[ib][jb], 0, 0, 0);
        }
    }

    // fold partials (8 blocks per bh contend per address)
    const int lr = ln >> 4, lc = ln & 15;
#pragma unroll
    for (int ib = 0; ib < 4; ib++) {
#pragma unroll
        for (int r = 0; r < 4; r++) {
            const int s = wm * 64 + ib * 16 + lr * 4 + r;
#pragma unroll
            for (int jb = 0; jb < 4; jb++) {
                const int col = wn * 64 + jb * 16 + lc;
                if (col < 64)
                    atomicAdd(&gBK[(size_t)bh * (SS * DIMM) + s * DIMM + col],
                              acc[ib][jb][r]);
                else
                    atomicAdd(&gBV[(size_t)bh * (SS * DIMM) + s * DIMM + (col - 64)],
                              acc[ib][jb][r]);
            }
        }
    }
}

// ---------------------------------------------------------------------------
// Attention (writes bf16 att in (b, t, h*d) row-major for the out-GEMM).
// ---------------------------------------------------------------------------
__global__ __launch_bounds__(256) void attn_k(
    const float* __restrict__ Qb, const float* __restrict__ gBK,
    const float* __restrict__ gBV, const float* __restrict__ gA,
    unsigned short* __restrict__ attb)
{
    __shared__ float sBK[SS][DIMM];
    __shared__ float sBV[SS][DIMM];
    const int tid = threadIdx.x;
    const int tc = blockIdx.x;
    const int bh = blockIdx.y;
    float* sk = &sBK[0][0];
    float* sv = &sBV[0][0];
    for (int i = tid * 4; i < SS * DIMM; i += 1024) {
        const int s = i >> 6;
        const float inv = 1.0f / (gA[bh * SS + s] + 1e-6f);
        float4 kv = *(const float4*)&gBK[(size_t)bh * (SS * DIMM) + i];
        float4 vv = *(const float4*)&gBV[(size_t)bh * (SS * DIMM) + i];
        kv.x *= inv; kv.y *= inv; kv.z *= inv; kv.w *= inv;
        vv.x *= inv; vv.y *= inv; vv.z *= inv; vv.w *= inv;
        *(float4*)&sk[i] = kv;
        *(float4*)&sv[i] = vv;
    }
    __syncthreads();

    const int t = tc * 256 + tid;
    const float* q = Qb + (size_t)bh * (TT * DIMM) + (size_t)t * DIMM;
    float qr[64];
#pragma unroll
    for (int d4 = 0; d4 < 16; d4++) {
        const float4 v = *(const float4*)&q[d4 * 4];
        qr[d4 * 4 + 0] = v.x; qr[d4 * 4 + 1] = v.y; qr[d4 * 4 + 2] = v.z; qr[d4 * 4 + 3] = v.w;
    }
    float m = -INFINITY, Z = 0.f, o[64];
#pragma unroll
    for (int d = 0; d < 64; d++) o[d] = 0.f;

    for (int s = 0; s < SS; s++) {
        float sc = 0.f;
#pragma unroll
        for (int d = 0; d < 64; d++) sc = fmaf(qr[d], sBK[s][d], sc);
        sc *= 0.125f;
        const float nm = fmaxf(m, sc);
        const float corr = __expf(m - nm);
        const float p = __expf(sc - nm);
        Z = Z * corr + p;
#pragma unroll
        for (int d = 0; d < 64; d++) o[d] = fmaf(p, sBV[s][d], o[d] * corr);
        m = nm;
    }
    const float invZ = 1.0f / Z;
    const int b = bh >> 4, h = bh & 15;
    unsigned short* outp = attb + ((size_t)(b * TT + t)) * DD + h * DIMM;
#pragma unroll
    for (int d2 = 0; d2 < 32; d2++) {
        const uint32_t pk = (uint32_t)f2bf(o[d2 * 2] * invZ) |
                            ((uint32_t)f2bf(o[d2 * 2 + 1] * invZ) << 16);
        *(uint32_t*)&outp[d2 * 2] = pk;
    }
}

// ---------------------------------------------------------------------------
// Launcher. Workspace (float offsets), footprint unchanged (239.1 MB):
//   Qb 0 (first 4 MB double as Wp fp32 / WphT / WplT scratch before Q-GEMM) |
//   Kb 1<<24 | Vb 2<<24 (xlo bf16 lives here until projm; later attb bf16 in
//   first half, WoutT bf16 at 41943040) | gBK 3<<24 | gBV +512K | gA +512K
//   (WT bf16 aliases gBK/gBV during the projection GEMMs) | xb at 51388416
//   (aW aliases it after all mgemm<0> uses; aIdx at 55582720).
//   Pj (33.5 MB) lives in d_out scratch — fully overwritten by mgemm<1>.
// ---------------------------------------------------------------------------
extern "C" void kernel_launch(void* const* d_in, const int* in_sizes, int n_in,
                              void* d_out, int out_size, void* d_ws, size_t ws_size,
                              hipStream_t stream)
{
    const float* x       = (const float*)d_in[0];
    const float* mask    = (const float*)d_in[1];
    const float* Wq      = (const float*)d_in[2];
    const float* Wk      = (const float*)d_in[3];
    const float* Wv      = (const float*)d_in[4];
    const float* Wout    = (const float*)d_in[5];
    const float* b_out   = (const float*)d_in[6];
    const float* planesT = (const float*)d_in[7];
    const float* protosT = (const float*)d_in[8];
    const float* ltemp   = (const float*)d_in[9];
    float* out = (float*)d_out;

    float* ws  = (float*)d_ws;
    float* Qb  = ws;
    float* Kb  = ws + (1u << 24);
    float* Vb  = ws + (2u << 24);
    float* gBK = ws + (3u << 24);
    float* gBV = gBK + 524288;
    float* gA  = gBV + 524288;
    unsigned short* WT1   = (unsigned short*)gBK;            // dead before zero_k
    unsigned short* WvT   = (unsigned short*)gBV;
    unsigned short* xb    = (unsigned short*)(ws + 51388416);
    unsigned short* xlo   = (unsigned short*)Vb;             // dead before V-GEMM
    float*          Wp    = ws;                              // Qb scratch (2 MB)
    unsigned short* WphT  = (unsigned short*)(ws + 524288);  // Qb scratch (1 MB)
    unsigned short* WplT  = (unsigned short*)(ws + 786432);  // Qb scratch (1 MB)
    float*          aW    = ws + 51388416;                   // aliases xb (xb dead)
    unsigned char*  aIdx  = (unsigned char*)(ws + 55582720);
    unsigned short* attb  = (unsigned short*)Vb;             // Vb dead after scatter
    unsigned short* WoutT = (unsigned short*)(ws + 41943040);// Vb second half
    float*          Pj    = (float*)d_out;                   // 33.5 MB scratch

    const dim3 mg(8, 128);     // mfma gemm grid
    const dim3 tg(32, 32);     // transpose grid
    const dim3 t2g(16, 32);    // Wp transpose grid (n=512, k=1024)
    const dim3 pg(4, 128);     // projm grid (N=512/128, M=16384/128)

    cvt2_k<<<8192, 256, 0, stream>>>(x, xb, xlo);

    // assignment projections first (xlo occupies Vb; Wp/WphT/WplT occupy Qb)
    wproj_k<<<1024, 256, 0, stream>>>(Wk, planesT, Wp);
    tr2_k<<<t2g, 256, 0, stream>>>(Wp, WphT, WplT);
    projm_k<<<pg, 256, 0, stream>>>(xb, xlo, WphT, WplT, mask, Pj);

    // Q / K / V projections (overwrite Qb and xlo/Vb scratch)
    tr_k<<<tg, 256, 0, stream>>>(Wq, WT1);
    mgemm_k<0><<<mg, 256, 0, stream>>>(xb, WT1, mask, Qb);
    tr_k<<<tg, 256, 0, stream>>>(Wk, WT1);                   // reuse WT1 (serial stream)
    mgemm_k<0><<<mg, 256, 0, stream>>>(xb, WT1, mask, Kb);
    tr_k<<<tg, 256, 0, stream>>>(Wv, WvT);
    mgemm_k<0><<<mg, 256, 0, stream>>>(xb, WvT, mask, Vb);

    zero_k<<<1032, 256, 0, stream>>>(gBK);                   // gBK ++ gBV ++ gA
    assign_k<<<dim3(16, 64), 256, 0, stream>>>(Pj, protosT, ltemp, aIdx, aW, gA);
    scatter4_k<<<dim3(8, 64), 256, 0, stream>>>(Kb, Vb, aIdx, aW, gBK, gBV);

    tr_k<<<tg, 256, 0, stream>>>(Wout, WoutT);
    attn_k<<<dim3(16, 64), 256, 0, stream>>>(Qb, gBK, gBV, gA, attb);

    mgemm_k<1><<<mg, 256, 0, stream>>>(attb, WoutT, b_out, out);
}

// Round 3
// 686.039 us; speedup vs baseline: 1.6996x; 1.2634x over previous
//
#include <hip/hip_runtime.h>
#include <math.h>
#include <stdint.h>

// Problem constants (B=4, T=4096, D=1024, H=16, DIM=64, L=8, KB=4, R=16, S=128)
#define TT   4096
#define DD   1024
#define HH   16
#define DIMM 64
#define SS   128

typedef short bf16x8 __attribute__((ext_vector_type(8)));
typedef float f32x4  __attribute__((ext_vector_type(4)));

// fp32 -> bf16 (RNE), finite inputs
__device__ __forceinline__ unsigned short f2bf(float f) {
    uint32_t u = __float_as_uint(f);
    return (unsigned short)((u + 0x7fffu + ((u >> 16) & 1u)) >> 16);
}
__device__ __forceinline__ float bf2f(unsigned short h) {
    return __uint_as_float((uint32_t)h << 16);
}

// async global->LDS, 16B per lane; LDS dest = WAVE-UNIFORM base + lane*16
#define GLD16(ldsp, gp) __builtin_amdgcn_global_load_lds( \
    (const __attribute__((address_space(1))) uint32_t*)(gp), \
    (__attribute__((address_space(3))) uint32_t*)(ldsp), 16, 0, 0)

// ---------------------------------------------------------------------------
// cvt2: x fp32 -> bf16 hi (xb) + bf16 lo residual (xlo). 8 per thread.
// ---------------------------------------------------------------------------
__global__ __launch_bounds__(256) void cvt2_k(const float* __restrict__ x,
                                              unsigned short* __restrict__ xb,
                                              unsigned short* __restrict__ xlo)
{
    const size_t i = ((size_t)blockIdx.x * 256 + threadIdx.x) * 8;
    const float4 a = *(const float4*)&x[i];
    const float4 b = *(const float4*)&x[i + 4];
    const float v[8] = {a.x, a.y, a.z, a.w, b.x, b.y, b.z, b.w};
    unsigned short h[8], l[8];
#pragma unroll
    for (int j = 0; j < 8; j++) {
        h[j] = f2bf(v[j]);
        l[j] = f2bf(v[j] - bf2f(h[j]));
    }
    uint4 rh, rl;
    rh.x = (uint32_t)h[0] | ((uint32_t)h[1] << 16);
    rh.y = (uint32_t)h[2] | ((uint32_t)h[3] << 16);
    rh.z = (uint32_t)h[4] | ((uint32_t)h[5] << 16);
    rh.w = (uint32_t)h[6] | ((uint32_t)h[7] << 16);
    rl.x = (uint32_t)l[0] | ((uint32_t)l[1] << 16);
    rl.y = (uint32_t)l[2] | ((uint32_t)l[3] << 16);
    rl.z = (uint32_t)l[4] | ((uint32_t)l[5] << 16);
    rl.w = (uint32_t)l[6] | ((uint32_t)l[7] << 16);
    *(uint4*)&xb[i]  = rh;
    *(uint4*)&xlo[i] = rl;
}

// ---------------------------------------------------------------------------
// tr: W (1024x1024 fp32, K-major) -> WT (1024x1024 bf16, N-major: WT[n][k]).
// ---------------------------------------------------------------------------
__global__ __launch_bounds__(256) void tr_k(const float* __restrict__ W,
                                            unsigned short* __restrict__ WT)
{
    __shared__ unsigned short tile[32][33];
    const int bx = blockIdx.x * 32;   // W col (=n) base
    const int by = blockIdx.y * 32;   // W row (=k) base
    const int tx = threadIdx.x & 31, ty = threadIdx.x >> 5;  // ty 0..7
#pragma unroll
    for (int r = 0; r < 4; r++) {
        const int row = by + ty * 4 + r;
        tile[tx][ty * 4 + r] = f2bf(W[(size_t)row * 1024 + bx + tx]);
    }
    __syncthreads();
#pragma unroll
    for (int r = 0; r < 4; r++) {
        const int col = bx + ty * 4 + r;
        WT[(size_t)col * 1024 + by + tx] = tile[ty * 4 + r][tx];
    }
}

// ---------------------------------------------------------------------------
// tr2: Wp (1024x512 fp32, K-major) -> WphT/WplT (512x1024 bf16 hi/lo).
// ---------------------------------------------------------------------------
__global__ __launch_bounds__(256) void tr2_k(const float* __restrict__ Wp,
                                             unsigned short* __restrict__ WphT,
                                             unsigned short* __restrict__ WplT)
{
    __shared__ float tile[32][33];
    const int bx = blockIdx.x * 32;   // n base (0..511)
    const int by = blockIdx.y * 32;   // k base (0..1023)
    const int tx = threadIdx.x & 31, ty = threadIdx.x >> 5;
#pragma unroll
    for (int r = 0; r < 4; r++) {
        const int row = by + ty * 4 + r;
        tile[tx][ty * 4 + r] = Wp[(size_t)row * 512 + bx + tx];
    }
    __syncthreads();
#pragma unroll
    for (int r = 0; r < 4; r++) {
        const int col = bx + ty * 4 + r;      // n
        const float v = tile[ty * 4 + r][tx];
        const unsigned short hi = f2bf(v);
        const unsigned short lo = f2bf(v - bf2f(hi));
        WphT[(size_t)col * 1024 + by + tx] = hi;
        WplT[(size_t)col * 1024 + by + tx] = lo;
    }
}

// ---------------------------------------------------------------------------
// bf16 MFMA GEMM: C(16384x1024) = A @ B, BT N-major. 128x128 tile, BK=32.
// MODE 0: *mask[row] -> fp32 [b][h][t][d].    MODE 1: +bias, fp32 row-major.
// MODE 2 (Q): *mask[row] -> bf16 Qf in MFMA A-fragment-linear layout:
//   per (bh, 128-token tile): elem ((tt>>4)*2+(d>>5))*512
//     + ((tt&15)+((d>>3)&3)*16)*8 + (d&7), so attn_m can GLD16 it linearly.
// ---------------------------------------------------------------------------
template<int MODE>
__global__ __launch_bounds__(256) void mgemm_k(
    const unsigned short* __restrict__ Abf, const unsigned short* __restrict__ BT,
    const float* __restrict__ aux, float* __restrict__ C)
{
    __shared__ short sA[4096];   // 8 KB
    __shared__ short sB[4096];   // 8 KB
    const int tid = threadIdx.x;
    const int w  = tid >> 6;          // wave 0..3
    const int ln = tid & 63;          // lane
    const int wm = w & 1, wn = w >> 1;
    const int row0 = blockIdx.y * 128;
    const int col0 = blockIdx.x * 128;
    const int lr = ln >> 4, lc = ln & 15;

    f32x4 acc[4][4];
#pragma unroll
    for (int i = 0; i < 4; i++)
#pragma unroll
        for (int j = 0; j < 4; j++) acc[i][j] = (f32x4){0.f, 0.f, 0.f, 0.f};

    const int ia0 = 2 * w, ia1 = 2 * w + 1;
    const size_t gA0 = (size_t)(row0 + ia0 * 16 + lc) * 1024 + lr * 8;
    const size_t gA1 = (size_t)(row0 + ia1 * 16 + lc) * 1024 + lr * 8;
    const size_t gB0 = (size_t)(col0 + ia0 * 16 + lc) * 1024 + lr * 8;
    const size_t gB1 = (size_t)(col0 + ia1 * 16 + lc) * 1024 + lr * 8;

    for (int k0 = 0; k0 < 1024; k0 += 32) {
        GLD16(&sA[ia0 * 512], Abf + gA0 + k0);
        GLD16(&sA[ia1 * 512], Abf + gA1 + k0);
        GLD16(&sB[ia0 * 512], BT  + gB0 + k0);
        GLD16(&sB[ia1 * 512], BT  + gB1 + k0);
        __syncthreads();

        bf16x8 af[4], bfr[4];
#pragma unroll
        for (int ib = 0; ib < 4; ib++)
            af[ib] = *(const bf16x8*)&sA[(wm * 4 + ib) * 512 + ln * 8];
#pragma unroll
        for (int jb = 0; jb < 4; jb++)
            bfr[jb] = *(const bf16x8*)&sB[(wn * 4 + jb) * 512 + ln * 8];
#pragma unroll
        for (int ib = 0; ib < 4; ib++)
#pragma unroll
            for (int jb = 0; jb < 4; jb++)
                acc[ib][jb] = __builtin_amdgcn_mfma_f32_16x16x32_bf16(
                    af[ib], bfr[jb], acc[ib][jb], 0, 0, 0);
        __syncthreads();
    }

    if (MODE == 0) {
        const int h = col0 / 64 + wn;
#pragma unroll
        for (int ib = 0; ib < 4; ib++) {
#pragma unroll
            for (int r = 0; r < 4; r++) {
                const int gr = row0 + wm * 64 + ib * 16 + lr * 4 + r;
                const float mval = aux[gr];
                const int b = gr >> 12, t = gr & (TT - 1);
                float* base = C + (((size_t)(b * HH + h) * TT + t) * DIMM);
#pragma unroll
                for (int jb = 0; jb < 4; jb++)
                    base[jb * 16 + lc] = acc[ib][jb][r] * mval;
            }
        }
    } else if (MODE == 1) {
#pragma unroll
        for (int ib = 0; ib < 4; ib++) {
#pragma unroll
            for (int r = 0; r < 4; r++) {
                const int gr = row0 + wm * 64 + ib * 16 + lr * 4 + r;
#pragma unroll
                for (int jb = 0; jb < 4; jb++) {
                    const int col = col0 + wn * 64 + jb * 16 + lc;
                    C[(size_t)gr * 1024 + col] = acc[ib][jb][r] + aux[col];
                }
            }
        }
    } else {  // MODE 2: bf16 fragment-linear Q
        const int h = col0 / 64 + wn;
        unsigned short* Qf = (unsigned short*)C;
#pragma unroll
        for (int ib = 0; ib < 4; ib++) {
#pragma unroll
            for (int r = 0; r < 4; r++) {
                const int gr = row0 + wm * 64 + ib * 16 + lr * 4 + r;
                const float mval = aux[gr];
                const int b = gr >> 12;
                const int tt = gr & 127;
                const size_t tbase = (size_t)(b * HH + h) * 262144
                                   + (size_t)((gr & (TT - 1)) >> 7) * 8192;
#pragma unroll
                for (int jb = 0; jb < 4; jb++) {
                    const int d = jb * 16 + lc;
                    const int e = ((tt >> 4) * 2 + (d >> 5)) * 512 +
                                  ((tt & 15) + ((d >> 3) & 3) * 16) * 8 + (d & 7);
                    Qf[tbase + e] = f2bf(acc[ib][jb][r] * mval);
                }
            }
        }
    }
}

// ---------------------------------------------------------------------------
// projm: error-compensated bf16x2 MFMA GEMM for the assignment projections.
// ---------------------------------------------------------------------------
__global__ __launch_bounds__(256) void projm_k(
    const unsigned short* __restrict__ Ah, const unsigned short* __restrict__ Al,
    const unsigned short* __restrict__ Bh, const unsigned short* __restrict__ Bl,
    const float* __restrict__ mask, float* __restrict__ P)
{
    __shared__ short sAh[4096];
    __shared__ short sAl[4096];
    __shared__ short sBh[4096];
    __shared__ short sBl[4096];
    const int tid = threadIdx.x;
    const int w  = tid >> 6;
    const int ln = tid & 63;
    const int wm = w & 1, wn = w >> 1;
    const int row0 = blockIdx.y * 128;
    const int col0 = blockIdx.x * 128;
    const int lr = ln >> 4, lc = ln & 15;

    f32x4 acc[4][4];
#pragma unroll
    for (int i = 0; i < 4; i++)
#pragma unroll
        for (int j = 0; j < 4; j++) acc[i][j] = (f32x4){0.f, 0.f, 0.f, 0.f};

    const int ia0 = 2 * w, ia1 = 2 * w + 1;
    const size_t gA0 = (size_t)(row0 + ia0 * 16 + lc) * 1024 + lr * 8;
    const size_t gA1 = (size_t)(row0 + ia1 * 16 + lc) * 1024 + lr * 8;
    const size_t gB0 = (size_t)(col0 + ia0 * 16 + lc) * 1024 + lr * 8;
    const size_t gB1 = (size_t)(col0 + ia1 * 16 + lc) * 1024 + lr * 8;

    for (int k0 = 0; k0 < 1024; k0 += 32) {
        GLD16(&sAh[ia0 * 512], Ah + gA0 + k0);
        GLD16(&sAh[ia1 * 512], Ah + gA1 + k0);
        GLD16(&sAl[ia0 * 512], Al + gA0 + k0);
        GLD16(&sAl[ia1 * 512], Al + gA1 + k0);
        GLD16(&sBh[ia0 * 512], Bh + gB0 + k0);
        GLD16(&sBh[ia1 * 512], Bh + gB1 + k0);
        GLD16(&sBl[ia0 * 512], Bl + gB0 + k0);
        GLD16(&sBl[ia1 * 512], Bl + gB1 + k0);
        __syncthreads();

        bf16x8 ah[4], al[4], bh[4], bl[4];
#pragma unroll
        for (int ib = 0; ib < 4; ib++) {
            ah[ib] = *(const bf16x8*)&sAh[(wm * 4 + ib) * 512 + ln * 8];
            al[ib] = *(const bf16x8*)&sAl[(wm * 4 + ib) * 512 + ln * 8];
        }
#pragma unroll
        for (int jb = 0; jb < 4; jb++) {
            bh[jb] = *(const bf16x8*)&sBh[(wn * 4 + jb) * 512 + ln * 8];
            bl[jb] = *(const bf16x8*)&sBl[(wn * 4 + jb) * 512 + ln * 8];
        }
#pragma unroll
        for (int ib = 0; ib < 4; ib++)
#pragma unroll
            for (int jb = 0; jb < 4; jb++) {
                acc[ib][jb] = __builtin_amdgcn_mfma_f32_16x16x32_bf16(
                    ah[ib], bh[jb], acc[ib][jb], 0, 0, 0);
                acc[ib][jb] = __builtin_amdgcn_mfma_f32_16x16x32_bf16(
                    ah[ib], bl[jb], acc[ib][jb], 0, 0, 0);
                acc[ib][jb] = __builtin_amdgcn_mfma_f32_16x16x32_bf16(
                    al[ib], bh[jb], acc[ib][jb], 0, 0, 0);
            }
        __syncthreads();
    }

#pragma unroll
    for (int ib = 0; ib < 4; ib++) {
#pragma unroll
        for (int r = 0; r < 4; r++) {
            const int gr = row0 + wm * 64 + ib * 16 + lr * 4 + r;
            const float mval = mask[gr];
            const int b = gr >> 12, t = gr & (TT - 1);
#pragma unroll
            for (int jb = 0; jb < 4; jb++) {
                const int c = col0 + wn * 64 + jb * 16 + lc;   // 0..511
                const int h = c >> 5, p = c & 31;
                P[(((size_t)(b * HH + h) * TT + t) * 32) + p] =
                    acc[ib][jb][r] * mval;
            }
        }
    }
}

// ---------------------------------------------------------------------------
// wproj: Wproj[k][h*32+p] = sum_d Wk[k][h*64+d] * planesT[d][p].  (fp32)
// ---------------------------------------------------------------------------
__global__ __launch_bounds__(256) void wproj_k(
    const float* __restrict__ Wk, const float* __restrict__ planesT,
    float* __restrict__ Wp)
{
    __shared__ float sW[1024];
    __shared__ float sP[2048];
    const int tid = threadIdx.x;
    const int k = blockIdx.x;
    for (int i = tid; i < 1024; i += 256) sW[i] = Wk[(size_t)k * 1024 + i];
    for (int i = tid; i < 2048; i += 256) sP[i] = planesT[i];
    __syncthreads();
#pragma unroll
    for (int c0 = 0; c0 < 2; c0++) {
        const int c = c0 * 256 + tid;          // 0..511
        const int h = c >> 5, p = c & 31;
        float s = 0.f;
#pragma unroll
        for (int d = 0; d < 64; d++)
            s = fmaf(sW[h * 64 + d], sP[d * 32 + p], s);
        Wp[(size_t)k * 512 + c] = s;
    }
}

// ---------------------------------------------------------------------------
// Zero-fill gBK ++ gBV ++ gA (contiguous, 1,056,768 floats).
// ---------------------------------------------------------------------------
__global__ __launch_bounds__(256) void zero_k(float* __restrict__ p)
{
    const size_t i = ((size_t)blockIdx.x * 256 + threadIdx.x) * 4;
    *(float4*)&p[i] = make_float4(0.f, 0.f, 0.f, 0.f);
}

// ---------------------------------------------------------------------------
// Assignment: reads precomputed fp32-accurate proj.
// ---------------------------------------------------------------------------
__global__ __launch_bounds__(256) void assign_k(
    const float* __restrict__ Pj, const float* __restrict__ protosT,
    const float* __restrict__ logit_temp,
    unsigned char* __restrict__ aIdx, float* __restrict__ aW,
    float* __restrict__ gA)
{
    __shared__ float sPr[4][16];
    __shared__ float sCnt[SS];
    const int tid = threadIdx.x;
    const int tc = blockIdx.x;
    const int bh = blockIdx.y;

    if (tid < 64)  ((float*)sPr)[tid] = protosT[tid];
    if (tid < SS)  sCnt[tid] = 0.f;
    __syncthreads();

    const float scale = fminf(fmaxf(__expf(logit_temp[0]), 0.01f), 20.0f);
    const float inv_scale = 1.0f / scale;

    const int t = tc * 256 + tid;
    const float* pr = Pj + ((size_t)bh * TT + t) * 32;
    float proj[32];
#pragma unroll
    for (int j = 0; j < 8; j++) {
        const float4 v = *(const float4*)&pr[j * 4];
        proj[j * 4 + 0] = v.x; proj[j * 4 + 1] = v.y;
        proj[j * 4 + 2] = v.z; proj[j * 4 + 3] = v.w;
    }
#pragma unroll
    for (int p = 0; p < 32; p++) proj[p] = tanhf(proj[p]) * inv_scale;

    unsigned char idx[16];
    float wv[16];
#pragma unroll
    for (int l = 0; l < 8; l++) {
        float g[16];
#pragma unroll
        for (int r = 0; r < 16; r++)
            g[r] = proj[l * 4 + 0] * sPr[0][r] + proj[l * 4 + 1] * sPr[1][r] +
                   proj[l * 4 + 2] * sPr[2][r] + proj[l * 4 + 3] * sPr[3][r];
        float mx = g[0];
#pragma unroll
        for (int r = 1; r < 16; r++) mx = fmaxf(mx, g[r]);
        float Zs = 0.f;
#pragma unroll
        for (int r = 0; r < 16; r++) Zs += __expf(g[r] - mx);
        int a = 0; float ga = g[0];
#pragma unroll
        for (int r = 1; r < 16; r++) { if (g[r] > ga) { ga = g[r]; a = r; } }
        int b2 = (a == 0) ? 1 : 0; float gb = g[b2];
#pragma unroll
        for (int r = 0; r < 16; r++) { if (r != a && g[r] > gb) { gb = g[r]; b2 = r; } }
        const float pa = __expf(ga - mx) / Zs;
        const float pb = __expf(gb - mx) / Zs;
        const float den = pa + pb + 1e-6f;
        const float wa = pa / den, wb = pb / den;
        idx[l * 2 + 0] = (unsigned char)(l * 16 + a);  wv[l * 2 + 0] = wa;
        idx[l * 2 + 1] = (unsigned char)(l * 16 + b2); wv[l * 2 + 1] = wb;
        atomicAdd(&sCnt[l * 16 + a],  wa);
        atomicAdd(&sCnt[l * 16 + b2], wb);
    }
    const size_t off = (size_t)bh * TT + t;
    uint32_t pk[4];
#pragma unroll
    for (int j = 0; j < 4; j++)
        pk[j] = (uint32_t)idx[j * 4] | ((uint32_t)idx[j * 4 + 1] << 8) |
                ((uint32_t)idx[j * 4 + 2] << 16) | ((uint32_t)idx[j * 4 + 3] << 24);
    *(uint4*)&aIdx[off * 16] = make_uint4(pk[0], pk[1], pk[2], pk[3]);
#pragma unroll
    for (int j = 0; j < 4; j++)
        *(float4*)&aW[off * 16 + j * 4] =
            make_float4(wv[j * 4], wv[j * 4 + 1], wv[j * 4 + 2], wv[j * 4 + 3]);
    __syncthreads();
    if (tid < SS) atomicAdd(&gA[bh * SS + tid], sCnt[tid]);
}

// ---------------------------------------------------------------------------
// Scatter as MFMA GEMM (unchanged).
// ---------------------------------------------------------------------------
__global__ __launch_bounds__(256) void scatter4_k(
    const float* __restrict__ Kb, const float* __restrict__ Vb,
    const unsigned char* __restrict__ aIdx, const float* __restrict__ aW,
    float* __restrict__ gBK, float* __restrict__ gBV)
{
    __shared__ short sA[8192];
    __shared__ short sB[8192];
    const int tid = threadIdx.x;
    const int tc = blockIdx.x;   // 8
    const int bh = blockIdx.y;   // 64
    const int w  = tid >> 6, ln = tid & 63;
    const int wm = w & 1, wn = w >> 1;

    f32x4 acc[4][4];
#pragma unroll
    for (int i = 0; i < 4; i++)
#pragma unroll
        for (int j = 0; j < 4; j++) acc[i][j] = (f32x4){0.f, 0.f, 0.f, 0.f};

    const int scol = tid & 127;
    const int stg  = tid >> 7;
    const float* srcrow = (scol < 64)
        ? Kb + (size_t)bh * (TT * DIMM) + scol
        : Vb + (size_t)bh * (TT * DIMM) + (scol - 64);
    const int bchunk = (scol >> 4);
    const int bslot8 = (scol & 15) * 8;
    const int ptt = tid >> 2, pg = tid & 3;

    for (int c = 0; c < 8; c++) {
        const int t0 = tc * 512 + c * 64;
        __syncthreads();
        {
            const uint4 z = make_uint4(0u, 0u, 0u, 0u);
#pragma unroll
            for (int r = 0; r < 4; r++)
                *(uint4*)&sA[(r * 256 + tid) * 8] = z;
        }
        __syncthreads();
#pragma unroll 8
        for (int r = 0; r < 32; r++) {
            const int tt = stg * 32 + r;
            const float v = srcrow[(size_t)(t0 + tt) * DIMM];
            sB[((tt >> 5) * 8 + bchunk) * 512 + ((tt >> 3) & 3) * 128 +
               bslot8 + (tt & 7)] = f2bf(v);
        }
        {
            const size_t off = (size_t)bh * TT + (t0 + ptt);
            const uint32_t pk = ((const uint32_t*)aIdx)[off * 4 + pg];
            const float4 wv = *(const float4*)&aW[off * 16 + pg * 4];
            const float w4[4] = {wv.x, wv.y, wv.z, wv.w};
#pragma unroll
            for (int q = 0; q < 4; q++) {
                const int s = (pk >> (8 * q)) & 255;
                sA[((ptt >> 5) * 8 + (s >> 4)) * 512 + ((ptt >> 3) & 3) * 128 +
                   (s & 15) * 8 + (ptt & 7)] = f2bf(w4[q]);
            }
        }
        __syncthreads();
#pragma unroll
        for (int ks = 0; ks < 2; ks++) {
            bf16x8 af[4], bfr[4];
#pragma unroll
            for (int ib = 0; ib < 4; ib++)
                af[ib] = *(const bf16x8*)&sA[(ks * 8 + wm * 4 + ib) * 512 + ln * 8];
#pragma unroll
            for (int jb = 0; jb < 4; jb++)
                bfr[jb] = *(const bf16x8*)&sB[(ks * 8 + wn * 4 + jb) * 512 + ln * 8];
#pragma unroll
            for (int ib = 0; ib < 4; ib++)
#pragma unroll
                for (int jb = 0; jb < 4; jb++)
                    acc[ib][jb] = __builtin_amdgcn_mfma_f32_16x16x32_bf16(
                        af[ib], bfr[jb], acc[ib][jb], 0, 0, 0);
        }
    }

    const int lr = ln >> 4, lc = ln & 15;
#pragma unroll
    for (int ib = 0; ib < 4; ib++) {
#pragma unroll
        for (int r = 0; r < 4; r++) {
            const int s = wm * 64 + ib * 16 + lr * 4 + r;
#pragma unroll
            for (int jb = 0; jb < 4; jb++) {
                const int col = wn * 64 + jb * 16 + lc;
                if (col < 64)
                    atomicAdd(&gBK[(size_t)bh * (SS * DIMM) + s * DIMM + col],
                              acc[ib][jb][r]);
                else
                    atomicAdd(&gBV[(size_t)bh * (SS * DIMM) + s * DIMM + (col - 64)],
                              acc[ib][jb][r]);
            }
        }
    }
}

// ---------------------------------------------------------------------------
// bprep: bucket K/V fp32 -> count-normalized bf16 in MFMA fragment-linear
// layouts. Kf (B-frag for QK: n=s, k=d); VTf (B-frag for PV: n=d, k=s).
// 2 MB total -> L2-resident for all attn tiles.
// ---------------------------------------------------------------------------
__global__ __launch_bounds__(256) void bprep_k(
    const float* __restrict__ gBK, const float* __restrict__ gBV,
    const float* __restrict__ gA,
    unsigned short* __restrict__ Kf, unsigned short* __restrict__ VTf)
{
    __shared__ float sInv[SS];
    const int tid = threadIdx.x;
    const int bh = blockIdx.y;
    if (tid < SS) sInv[tid] = 1.0f / (gA[bh * SS + tid] + 1e-6f);
    __syncthreads();
#pragma unroll
    for (int it = 0; it < 8; it++) {
        const int i = (blockIdx.x * 8 + it) * 256 + tid;   // 0..8191
        const int s = i >> 6, d = i & 63;
        const float kv = gBK[(size_t)bh * 8192 + i] * sInv[s];
        const float vv = gBV[(size_t)bh * 8192 + i] * sInv[s];
        const int ek = ((s >> 4) * 2 + (d >> 5)) * 512 +
                       ((s & 15) + ((d >> 3) & 3) * 16) * 8 + (d & 7);
        const int ev = ((d >> 4) * 4 + (s >> 5)) * 512 +
                       ((d & 15) + ((s >> 3) & 3) * 16) * 8 + (s & 7);
        Kf[(size_t)bh * 8192 + ek]  = f2bf(kv);
        VTf[(size_t)bh * 8192 + ev] = f2bf(vv);
    }
}

// ---------------------------------------------------------------------------
// MFMA attention. Grid (32 token-tiles of 128, 64 bh), 256 thr = 4 waves.
// Wave w owns 32 tokens. QK: 32 mfma/wave (M=32,N=128,K=64); row softmax via
// 8 local + shfl_xor{1,2,4,8} reduce (row lives in 16 lanes x 8 jb); P bf16
// -> sP in XOR-swizzled PV-A-frag layout (write ~2-way banks, read linear,
// same-wave so no barrier); PV: 32 mfma/wave (M=32,N=64,K=128).
// LDS 80 KB -> 2 blocks/CU.
// ---------------------------------------------------------------------------
__global__ __launch_bounds__(256) void attn_m(
    const unsigned short* __restrict__ Qf, const unsigned short* __restrict__ Kf,
    const unsigned short* __restrict__ VTf, unsigned short* __restrict__ attb)
{
    __shared__ short sQ[8192];     // 16 KB  A-frag tiles (t x d)
    __shared__ short sK[8192];     // 16 KB  B-frag tiles (s x d)
    __shared__ short sVT[8192];    // 16 KB  B-frag tiles (d x s)
    __shared__ short sP[16384];    // 32 KB  A-frag tiles (t x s), swizzled
    const int tid = threadIdx.x;
    const int tc = blockIdx.x;     // 32 tiles of 128 tokens
    const int bh = blockIdx.y;     // 64
    const int w = tid >> 6, l = tid & 63;

    const size_t qbase  = (size_t)bh * 262144 + (size_t)tc * 8192;
    const size_t kvbase = (size_t)bh * 8192;
#pragma unroll
    for (int i = 0; i < 4; i++) {
        const int o = (i * 256 + w * 64) * 8;       // wave-uniform LDS base
        GLD16(&sQ[o],  Qf  + qbase  + o + l * 8);
        GLD16(&sK[o],  Kf  + kvbase + o + l * 8);
        GLD16(&sVT[o], VTf + kvbase + o + l * 8);
    }
    __syncthreads();

    // ---- QK^T: acc[ib][jb], t = w*32+ib*16+(l>>4)*4+reg, s = jb*16+(l&15)
    f32x4 acc[2][8];
#pragma unroll
    for (int i = 0; i < 2; i++)
#pragma unroll
        for (int j = 0; j < 8; j++) acc[i][j] = (f32x4){0.f, 0.f, 0.f, 0.f};

#pragma unroll
    for (int ks = 0; ks < 2; ks++) {
        const bf16x8 a0 = *(const bf16x8*)&sQ[((w * 2 + 0) * 2 + ks) * 512 + l * 8];
        const bf16x8 a1 = *(const bf16x8*)&sQ[((w * 2 + 1) * 2 + ks) * 512 + l * 8];
#pragma unroll
        for (int jb = 0; jb < 8; jb++) {
            const bf16x8 b = *(const bf16x8*)&sK[(jb * 2 + ks) * 512 + l * 8];
            acc[0][jb] = __builtin_amdgcn_mfma_f32_16x16x32_bf16(a0, b, acc[0][jb], 0, 0, 0);
            acc[1][jb] = __builtin_amdgcn_mfma_f32_16x16x32_bf16(a1, b, acc[1][jb], 0, 0, 0);
        }
    }

    // ---- softmax rows + write P bf16 to sP (PV A-frag layout, swizzled)
#pragma unroll
    for (int ib = 0; ib < 2; ib++) {
        const int mb = w * 2 + ib;
#pragma unroll
        for (int r = 0; r < 4; r++) {
            float v[8];
            float mx = -INFINITY;
#pragma unroll
            for (int jb = 0; jb < 8; jb++) {
                v[jb] = acc[ib][jb][r] * 0.125f;
                mx = fmaxf(mx, v[jb]);
            }
            mx = fmaxf(mx, __shfl_xor(mx, 1));
            mx = fmaxf(mx, __shfl_xor(mx, 2));
            mx = fmaxf(mx, __shfl_xor(mx, 4));
            mx = fmaxf(mx, __shfl_xor(mx, 8));
            float Z = 0.f;
#pragma unroll
            for (int jb = 0; jb < 8; jb++) { v[jb] = __expf(v[jb] - mx); Z += v[jb]; }
            Z += __shfl_xor(Z, 1);
            Z += __shfl_xor(Z, 2);
            Z += __shfl_xor(Z, 4);
            Z += __shfl_xor(Z, 8);
            const float invZ = 1.0f / Z;
            const int ttl = (l >> 4) * 4 + r;       // t & 15
#pragma unroll
            for (int jb = 0; jb < 8; jb++) {
                int e = (mb * 4 + (jb >> 1)) * 512 +
                        (ttl + (((jb * 2 + ((l >> 3) & 1)) & 3) * 16)) * 8 + (l & 7);
                e ^= ((e >> 7) & 3) << 4;           // bank swizzle
                sP[e] = (short)f2bf(v[jb] * invZ);
            }
        }
    }
    // no barrier: each wave reads only its own sP blocks (mb = w*2+ib)

    // ---- PV: out[t][d], A = sP (k=s), B = sVT (n=d, k=s)
    f32x4 acc2[2][4];
#pragma unroll
    for (int i = 0; i < 2; i++)
#pragma unroll
        for (int j = 0; j < 4; j++) acc2[i][j] = (f32x4){0.f, 0.f, 0.f, 0.f};

#pragma unroll
    for (int ks = 0; ks < 4; ks++) {
        bf16x8 a[2];
#pragma unroll
        for (int ib = 0; ib < 2; ib++) {
            int ia = ((w * 2 + ib) * 4 + ks) * 512 + l * 8;
            ia ^= ((ia >> 7) & 3) << 4;
            a[ib] = *(const bf16x8*)&sP[ia];
        }
#pragma unroll
        for (int jb = 0; jb < 4; jb++) {
            const bf16x8 b = *(const bf16x8*)&sVT[(jb * 4 + ks) * 512 + l * 8];
            acc2[0][jb] = __builtin_amdgcn_mfma_f32_16x16x32_bf16(a[0], b, acc2[0][jb], 0, 0, 0);
            acc2[1][jb] = __builtin_amdgcn_mfma_f32_16x16x32_bf16(a[1], b, acc2[1][jb], 0, 0, 0);
        }
    }

    // ---- epilogue: attb[(b*4096 + t)*1024 + h*64 + d] bf16
    const int b = bh >> 4, h = bh & 15;
#pragma unroll
    for (int ib = 0; ib < 2; ib++) {
#pragma unroll
        for (int r = 0; r < 4; r++) {
            const int t = tc * 128 + w * 32 + ib * 16 + (l >> 4) * 4 + r;
            unsigned short* outp = attb + ((size_t)(b * TT + t)) * DD + h * DIMM;
#pragma unroll
            for (int jb = 0; jb < 4; jb++)
                outp[jb * 16 + (l & 15)] = f2bf(acc2[ib][jb][r]);
        }
    }
}

// ---------------------------------------------------------------------------
// Launcher. Workspace (float offsets), footprint unchanged:
//   Qf bf16 at ws+0 (32 MB; Wp/WphT/WplT scratch there before Q-GEMM) |
//   Kb 1<<24 | Vb 2<<24 (xlo until projm; attb after scatter; WoutT at
//   41943040) | gBK 3<<24 | gBV +512K | gA +512K (WT1/WvT alias gBK/gBV
//   until zero_k) | xb at 51388416 (aW aliases after last mgemm use; aIdx
//   at 55582720) | Kf at 56631296, VTf at 56893440 (xb dead by bprep).
//   Pj (33.5 MB) in d_out scratch — overwritten by final mgemm<1>.
// ---------------------------------------------------------------------------
extern "C" void kernel_launch(void* const* d_in, const int* in_sizes, int n_in,
                              void* d_out, int out_size, void* d_ws, size_t ws_size,
                              hipStream_t stream)
{
    const float* x       = (const float*)d_in[0];
    const float* mask    = (const float*)d_in[1];
    const float* Wq      = (const float*)d_in[2];
    const float* Wk      = (const float*)d_in[3];
    const float* Wv      = (const float*)d_in[4];
    const float* Wout    = (const float*)d_in[5];
    const float* b_out   = (const float*)d_in[6];
    const float* planesT = (const float*)d_in[7];
    const float* protosT = (const float*)d_in[8];
    const float* ltemp   = (const float*)d_in[9];
    float* out = (float*)d_out;

    float* ws  = (float*)d_ws;
    float* Kb  = ws + (1u << 24);
    float* Vb  = ws + (2u << 24);
    float* gBK = ws + (3u << 24);
    float* gBV = gBK + 524288;
    float* gA  = gBV + 524288;
    unsigned short* Qf    = (unsigned short*)ws;
    unsigned short* WT1   = (unsigned short*)gBK;            // dead before zero_k
    unsigned short* WvT   = (unsigned short*)gBV;
    unsigned short* xb    = (unsigned short*)(ws + 51388416);
    unsigned short* xlo   = (unsigned short*)Vb;             // dead before V-GEMM
    float*          Wp    = ws;                              // dead before Q-GEMM
    unsigned short* WphT  = (unsigned short*)(ws + 524288);
    unsigned short* WplT  = (unsigned short*)(ws + 786432);
    float*          aW    = ws + 51388416;                   // aliases xb (dead)
    unsigned char*  aIdx  = (unsigned char*)(ws + 55582720);
    unsigned short* Kf    = (unsigned short*)(ws + 56631296);
    unsigned short* VTf   = (unsigned short*)(ws + 56893440);
    unsigned short* attb  = (unsigned short*)Vb;             // Vb dead after scatter
    unsigned short* WoutT = (unsigned short*)(ws + 41943040);
    float*          Pj    = (float*)d_out;                   // 33.5 MB scratch

    const dim3 mg(8, 128);     // mfma gemm grid
    const dim3 tg(32, 32);     // transpose grid
    const dim3 t2g(16, 32);    // Wp transpose grid
    const dim3 pg(4, 128);     // projm grid

    cvt2_k<<<8192, 256, 0, stream>>>(x, xb, xlo);

    // assignment projections (xlo in Vb; Wp/WphT/WplT in Qf region)
    wproj_k<<<1024, 256, 0, stream>>>(Wk, planesT, Wp);
    tr2_k<<<t2g, 256, 0, stream>>>(Wp, WphT, WplT);
    projm_k<<<pg, 256, 0, stream>>>(xb, xlo, WphT, WplT, mask, Pj);

    // Q (bf16 fragment-linear) / K / V projections
    tr_k<<<tg, 256, 0, stream>>>(Wq, WT1);
    mgemm_k<2><<<mg, 256, 0, stream>>>(xb, WT1, mask, (float*)Qf);
    tr_k<<<tg, 256, 0, stream>>>(Wk, WT1);
    mgemm_k<0><<<mg, 256, 0, stream>>>(xb, WT1, mask, Kb);
    tr_k<<<tg, 256, 0, stream>>>(Wv, WvT);
    mgemm_k<0><<<mg, 256, 0, stream>>>(xb, WvT, mask, Vb);

    zero_k<<<1032, 256, 0, stream>>>(gBK);                   // gBK ++ gBV ++ gA
    assign_k<<<dim3(16, 64), 256, 0, stream>>>(Pj, protosT, ltemp, aIdx, aW, gA);
    scatter4_k<<<dim3(8, 64), 256, 0, stream>>>(Kb, Vb, aIdx, aW, gBK, gBV);

    bprep_k<<<dim3(4, 64), 256, 0, stream>>>(gBK, gBV, gA, Kf, VTf);
    tr_k<<<tg, 256, 0, stream>>>(Wout, WoutT);
    attn_m<<<dim3(32, 64), 256, 0, stream>>>(Qf, Kf, VTf, attb);

    mgemm_k<1><<<mg, 256, 0, stream>>>(attb, WoutT, b_out, out);
}

// Round 5
// 659.860 us; speedup vs baseline: 1.7670x; 1.0397x over previous
//
#include <hip/hip_runtime.h>
#include <math.h>
#include <stdint.h>

// Problem constants (B=4, T=4096, D=1024, H=16, DIM=64, L=8, KB=4, R=16, S=128)
#define TT   4096
#define DD   1024
#define HH   16
#define DIMM 64
#define SS   128

typedef short bf16x8 __attribute__((ext_vector_type(8)));
typedef float f32x4  __attribute__((ext_vector_type(4)));

// fp32 -> bf16 (RNE), finite inputs
__device__ __forceinline__ unsigned short f2bf(float f) {
    uint32_t u = __float_as_uint(f);
    return (unsigned short)((u + 0x7fffu + ((u >> 16) & 1u)) >> 16);
}
__device__ __forceinline__ float bf2f(unsigned short h) {
    return __uint_as_float((uint32_t)h << 16);
}

// async global->LDS, 16B per lane; LDS dest = WAVE-UNIFORM base + lane*16
#define GLD16(ldsp, gp) __builtin_amdgcn_global_load_lds( \
    (const __attribute__((address_space(1))) uint32_t*)(gp), \
    (__attribute__((address_space(3))) uint32_t*)(ldsp), 16, 0, 0)

// ---------------------------------------------------------------------------
// cvt2: x fp32 -> bf16 hi (xb) + bf16 lo residual (xlo). 8 per thread.
// ---------------------------------------------------------------------------
__global__ __launch_bounds__(256) void cvt2_k(const float* __restrict__ x,
                                              unsigned short* __restrict__ xb,
                                              unsigned short* __restrict__ xlo)
{
    const size_t i = ((size_t)blockIdx.x * 256 + threadIdx.x) * 8;
    const float4 a = *(const float4*)&x[i];
    const float4 b = *(const float4*)&x[i + 4];
    const float v[8] = {a.x, a.y, a.z, a.w, b.x, b.y, b.z, b.w};
    unsigned short h[8], l[8];
#pragma unroll
    for (int j = 0; j < 8; j++) {
        h[j] = f2bf(v[j]);
        l[j] = f2bf(v[j] - bf2f(h[j]));
    }
    uint4 rh, rl;
    rh.x = (uint32_t)h[0] | ((uint32_t)h[1] << 16);
    rh.y = (uint32_t)h[2] | ((uint32_t)h[3] << 16);
    rh.z = (uint32_t)h[4] | ((uint32_t)h[5] << 16);
    rh.w = (uint32_t)h[6] | ((uint32_t)h[7] << 16);
    rl.x = (uint32_t)l[0] | ((uint32_t)l[1] << 16);
    rl.y = (uint32_t)l[2] | ((uint32_t)l[3] << 16);
    rl.z = (uint32_t)l[4] | ((uint32_t)l[5] << 16);
    rl.w = (uint32_t)l[6] | ((uint32_t)l[7] << 16);
    *(uint4*)&xb[i]  = rh;
    *(uint4*)&xlo[i] = rl;
}

// ---------------------------------------------------------------------------
// tr: W (1024x1024 fp32, K-major) -> WT (1024x1024 bf16, N-major: WT[n][k]).
// ---------------------------------------------------------------------------
__global__ __launch_bounds__(256) void tr_k(const float* __restrict__ W,
                                            unsigned short* __restrict__ WT)
{
    __shared__ unsigned short tile[32][33];
    const int bx = blockIdx.x * 32;   // W col (=n) base
    const int by = blockIdx.y * 32;   // W row (=k) base
    const int tx = threadIdx.x & 31, ty = threadIdx.x >> 5;  // ty 0..7
#pragma unroll
    for (int r = 0; r < 4; r++) {
        const int row = by + ty * 4 + r;
        tile[tx][ty * 4 + r] = f2bf(W[(size_t)row * 1024 + bx + tx]);
    }
    __syncthreads();
#pragma unroll
    for (int r = 0; r < 4; r++) {
        const int col = bx + ty * 4 + r;
        WT[(size_t)col * 1024 + by + tx] = tile[ty * 4 + r][tx];
    }
}

// ---------------------------------------------------------------------------
// tr2: Wp (1024x512 fp32, K-major) -> WphT/WplT (512x1024 bf16 hi/lo).
// ---------------------------------------------------------------------------
__global__ __launch_bounds__(256) void tr2_k(const float* __restrict__ Wp,
                                             unsigned short* __restrict__ WphT,
                                             unsigned short* __restrict__ WplT)
{
    __shared__ float tile[32][33];
    const int bx = blockIdx.x * 32;   // n base (0..511)
    const int by = blockIdx.y * 32;   // k base (0..1023)
    const int tx = threadIdx.x & 31, ty = threadIdx.x >> 5;
#pragma unroll
    for (int r = 0; r < 4; r++) {
        const int row = by + ty * 4 + r;
        tile[tx][ty * 4 + r] = Wp[(size_t)row * 512 + bx + tx];
    }
    __syncthreads();
#pragma unroll
    for (int r = 0; r < 4; r++) {
        const int col = bx + ty * 4 + r;      // n
        const float v = tile[ty * 4 + r][tx];
        const unsigned short hi = f2bf(v);
        const unsigned short lo = f2bf(v - bf2f(hi));
        WphT[(size_t)col * 1024 + by + tx] = hi;
        WplT[(size_t)col * 1024 + by + tx] = lo;
    }
}

// ---------------------------------------------------------------------------
// qkv: fused Q/K/V projection. C(16384x3072) = xb @ [WqT;WkT;WvT]^T.
// 128x128 tile, BK=32, 4 waves, 2-phase double-buffered LDS (stage next tile
// BEFORE compute; barrier's vmcnt(0) drain then lands after the MFMAs).
// XCD-bijective remap: each XCD owns 16 complete row-bands.
// Epilogue by column region: Q -> bf16 fragment-linear Qf; K/V -> fp32
// [b][h][t][d] (all *mask[row]).
// ---------------------------------------------------------------------------
__global__ __launch_bounds__(256) void qkv_k(
    const unsigned short* __restrict__ Abf, const unsigned short* __restrict__ BT,
    const float* __restrict__ mask, unsigned short* __restrict__ Qf,
    float* __restrict__ Kb, float* __restrict__ Vb)
{
    __shared__ short sA[2][4096];   // 16 KB
    __shared__ short sB[2][4096];   // 16 KB
    const int tid = threadIdx.x;
    const int w  = tid >> 6;          // wave 0..3
    const int ln = tid & 63;          // lane
    const int wm = w & 1, wn = w >> 1;
    // XCD-bijective remap (nwg = 3072 = 8 XCD x 16 bands x 24 colblks)
    const int id   = blockIdx.y * 24 + blockIdx.x;
    const int xcd  = id & 7, kk = id >> 3;        // kk in [0,384)
    const int band = xcd * 16 + kk / 24;
    const int colblk = kk % 24;
    const int row0 = band * 128;
    const int col0 = colblk * 128;
    const int lr = ln >> 4, lc = ln & 15;

    f32x4 acc[4][4];
#pragma unroll
    for (int i = 0; i < 4; i++)
#pragma unroll
        for (int j = 0; j < 4; j++) acc[i][j] = (f32x4){0.f, 0.f, 0.f, 0.f};

    const int ia0 = 2 * w, ia1 = 2 * w + 1;
    const size_t gA0 = (size_t)(row0 + ia0 * 16 + lc) * 1024 + lr * 8;
    const size_t gA1 = (size_t)(row0 + ia1 * 16 + lc) * 1024 + lr * 8;
    const size_t gB0 = (size_t)(col0 + ia0 * 16 + lc) * 1024 + lr * 8;
    const size_t gB1 = (size_t)(col0 + ia1 * 16 + lc) * 1024 + lr * 8;

    auto STAGE = [&](int buf, int k0) {
        GLD16(&sA[buf][ia0 * 512], Abf + gA0 + k0);
        GLD16(&sA[buf][ia1 * 512], Abf + gA1 + k0);
        GLD16(&sB[buf][ia0 * 512], BT  + gB0 + k0);
        GLD16(&sB[buf][ia1 * 512], BT  + gB1 + k0);
    };

    STAGE(0, 0);
    __syncthreads();                       // drains vmcnt(0)
    for (int t = 0; t < 32; t++) {
        const int cur = t & 1;
        if (t < 31) STAGE(cur ^ 1, (t + 1) * 32);   // prefetch next tile
        bf16x8 af[4], bfr[4];
#pragma unroll
        for (int ib = 0; ib < 4; ib++)
            af[ib] = *(const bf16x8*)&sA[cur][(wm * 4 + ib) * 512 + ln * 8];
#pragma unroll
        for (int jb = 0; jb < 4; jb++)
            bfr[jb] = *(const bf16x8*)&sB[cur][(wn * 4 + jb) * 512 + ln * 8];
#pragma unroll
        for (int ib = 0; ib < 4; ib++)
#pragma unroll
            for (int jb = 0; jb < 4; jb++)
                acc[ib][jb] = __builtin_amdgcn_mfma_f32_16x16x32_bf16(
                    af[ib], bfr[jb], acc[ib][jb], 0, 0, 0);
        __syncthreads();                   // drains this step's prefetch
    }

    const int proj = colblk >> 3;          // 0=Q 1=K 2=V
    const int c0l  = (colblk & 7) * 128;   // local col base within 1024
    const int h    = c0l / 64 + wn;
    if (proj == 0) {
#pragma unroll
        for (int ib = 0; ib < 4; ib++) {
#pragma unroll
            for (int r = 0; r < 4; r++) {
                const int gr = row0 + wm * 64 + ib * 16 + lr * 4 + r;
                const float mval = mask[gr];
                const int b = gr >> 12;
                const int tt = gr & 127;
                const size_t tbase = (size_t)(b * HH + h) * 262144
                                   + (size_t)((gr & (TT - 1)) >> 7) * 8192;
#pragma unroll
                for (int jb = 0; jb < 4; jb++) {
                    const int d = jb * 16 + lc;
                    const int e = ((tt >> 4) * 2 + (d >> 5)) * 512 +
                                  ((tt & 15) + ((d >> 3) & 3) * 16) * 8 + (d & 7);
                    Qf[tbase + e] = f2bf(acc[ib][jb][r] * mval);
                }
            }
        }
    } else {
        float* C = (proj == 1) ? Kb : Vb;
#pragma unroll
        for (int ib = 0; ib < 4; ib++) {
#pragma unroll
            for (int r = 0; r < 4; r++) {
                const int gr = row0 + wm * 64 + ib * 16 + lr * 4 + r;
                const float mval = mask[gr];
                const int b = gr >> 12, t = gr & (TT - 1);
                float* base = C + (((size_t)(b * HH + h) * TT + t) * DIMM);
#pragma unroll
                for (int jb = 0; jb < 4; jb++)
                    base[jb * 16 + lc] = acc[ib][jb][r] * mval;
            }
        }
    }
}

// ---------------------------------------------------------------------------
// out: C(16384x1024) = attb @ WoutT^T + bias, fp32 row-major. Same 2-phase
// double-buffered structure + XCD remap (nwg = 1024 = 8 x 16 x 8).
// ---------------------------------------------------------------------------
__global__ __launch_bounds__(256) void out_k(
    const unsigned short* __restrict__ Abf, const unsigned short* __restrict__ BT,
    const float* __restrict__ bias, float* __restrict__ C)
{
    __shared__ short sA[2][4096];
    __shared__ short sB[2][4096];
    const int tid = threadIdx.x;
    const int w  = tid >> 6, ln = tid & 63;
    const int wm = w & 1, wn = w >> 1;
    const int id  = blockIdx.y * 8 + blockIdx.x;
    const int xcd = id & 7, kk = id >> 3;          // kk in [0,128)
    const int row0 = (xcd * 16 + (kk >> 3)) * 128;
    const int col0 = (kk & 7) * 128;
    const int lr = ln >> 4, lc = ln & 15;

    f32x4 acc[4][4];
#pragma unroll
    for (int i = 0; i < 4; i++)
#pragma unroll
        for (int j = 0; j < 4; j++) acc[i][j] = (f32x4){0.f, 0.f, 0.f, 0.f};

    const int ia0 = 2 * w, ia1 = 2 * w + 1;
    const size_t gA0 = (size_t)(row0 + ia0 * 16 + lc) * 1024 + lr * 8;
    const size_t gA1 = (size_t)(row0 + ia1 * 16 + lc) * 1024 + lr * 8;
    const size_t gB0 = (size_t)(col0 + ia0 * 16 + lc) * 1024 + lr * 8;
    const size_t gB1 = (size_t)(col0 + ia1 * 16 + lc) * 1024 + lr * 8;

    auto STAGE = [&](int buf, int k0) {
        GLD16(&sA[buf][ia0 * 512], Abf + gA0 + k0);
        GLD16(&sA[buf][ia1 * 512], Abf + gA1 + k0);
        GLD16(&sB[buf][ia0 * 512], BT  + gB0 + k0);
        GLD16(&sB[buf][ia1 * 512], BT  + gB1 + k0);
    };

    STAGE(0, 0);
    __syncthreads();
    for (int t = 0; t < 32; t++) {
        const int cur = t & 1;
        if (t < 31) STAGE(cur ^ 1, (t + 1) * 32);
        bf16x8 af[4], bfr[4];
#pragma unroll
        for (int ib = 0; ib < 4; ib++)
            af[ib] = *(const bf16x8*)&sA[cur][(wm * 4 + ib) * 512 + ln * 8];
#pragma unroll
        for (int jb = 0; jb < 4; jb++)
            bfr[jb] = *(const bf16x8*)&sB[cur][(wn * 4 + jb) * 512 + ln * 8];
#pragma unroll
        for (int ib = 0; ib < 4; ib++)
#pragma unroll
            for (int jb = 0; jb < 4; jb++)
                acc[ib][jb] = __builtin_amdgcn_mfma_f32_16x16x32_bf16(
                    af[ib], bfr[jb], acc[ib][jb], 0, 0, 0);
        __syncthreads();
    }

#pragma unroll
    for (int ib = 0; ib < 4; ib++) {
#pragma unroll
        for (int r = 0; r < 4; r++) {
            const int gr = row0 + wm * 64 + ib * 16 + lr * 4 + r;
#pragma unroll
            for (int jb = 0; jb < 4; jb++) {
                const int col = col0 + wn * 64 + jb * 16 + lc;
                C[(size_t)gr * 1024 + col] = acc[ib][jb][r] + bias[col];
            }
        }
    }
}

// ---------------------------------------------------------------------------
// projm: error-compensated bf16x2 MFMA GEMM for the assignment projections.
// 2-phase double-buffered (64 KB LDS) + XCD remap (nwg = 512 = 8 x 16 x 4).
// ---------------------------------------------------------------------------
__global__ __launch_bounds__(256) void projm_k(
    const unsigned short* __restrict__ Ah, const unsigned short* __restrict__ Al,
    const unsigned short* __restrict__ Bh, const unsigned short* __restrict__ Bl,
    const float* __restrict__ mask, float* __restrict__ P)
{
    __shared__ short sAh[2][4096];
    __shared__ short sAl[2][4096];
    __shared__ short sBh[2][4096];
    __shared__ short sBl[2][4096];
    const int tid = threadIdx.x;
    const int w  = tid >> 6;
    const int ln = tid & 63;
    const int wm = w & 1, wn = w >> 1;
    const int id  = blockIdx.y * 4 + blockIdx.x;
    const int xcd = id & 7, kk = id >> 3;          // kk in [0,64)
    const int row0 = (xcd * 16 + (kk >> 2)) * 128;
    const int col0 = (kk & 3) * 128;
    const int lr = ln >> 4, lc = ln & 15;

    f32x4 acc[4][4];
#pragma unroll
    for (int i = 0; i < 4; i++)
#pragma unroll
        for (int j = 0; j < 4; j++) acc[i][j] = (f32x4){0.f, 0.f, 0.f, 0.f};

    const int ia0 = 2 * w, ia1 = 2 * w + 1;
    const size_t gA0 = (size_t)(row0 + ia0 * 16 + lc) * 1024 + lr * 8;
    const size_t gA1 = (size_t)(row0 + ia1 * 16 + lc) * 1024 + lr * 8;
    const size_t gB0 = (size_t)(col0 + ia0 * 16 + lc) * 1024 + lr * 8;
    const size_t gB1 = (size_t)(col0 + ia1 * 16 + lc) * 1024 + lr * 8;

    auto STAGE = [&](int buf, int k0) {
        GLD16(&sAh[buf][ia0 * 512], Ah + gA0 + k0);
        GLD16(&sAh[buf][ia1 * 512], Ah + gA1 + k0);
        GLD16(&sAl[buf][ia0 * 512], Al + gA0 + k0);
        GLD16(&sAl[buf][ia1 * 512], Al + gA1 + k0);
        GLD16(&sBh[buf][ia0 * 512], Bh + gB0 + k0);
        GLD16(&sBh[buf][ia1 * 512], Bh + gB1 + k0);
        GLD16(&sBl[buf][ia0 * 512], Bl + gB0 + k0);
        GLD16(&sBl[buf][ia1 * 512], Bl + gB1 + k0);
    };

    STAGE(0, 0);
    __syncthreads();
    for (int t = 0; t < 32; t++) {
        const int cur = t & 1;
        if (t < 31) STAGE(cur ^ 1, (t + 1) * 32);
        bf16x8 ah[4], al[4], bh[4], bl[4];
#pragma unroll
        for (int ib = 0; ib < 4; ib++) {
            ah[ib] = *(const bf16x8*)&sAh[cur][(wm * 4 + ib) * 512 + ln * 8];
            al[ib] = *(const bf16x8*)&sAl[cur][(wm * 4 + ib) * 512 + ln * 8];
        }
#pragma unroll
        for (int jb = 0; jb < 4; jb++) {
            bh[jb] = *(const bf16x8*)&sBh[cur][(wn * 4 + jb) * 512 + ln * 8];
            bl[jb] = *(const bf16x8*)&sBl[cur][(wn * 4 + jb) * 512 + ln * 8];
        }
#pragma unroll
        for (int ib = 0; ib < 4; ib++)
#pragma unroll
            for (int jb = 0; jb < 4; jb++) {
                acc[ib][jb] = __builtin_amdgcn_mfma_f32_16x16x32_bf16(
                    ah[ib], bh[jb], acc[ib][jb], 0, 0, 0);
                acc[ib][jb] = __builtin_amdgcn_mfma_f32_16x16x32_bf16(
                    ah[ib], bl[jb], acc[ib][jb], 0, 0, 0);
                acc[ib][jb] = __builtin_amdgcn_mfma_f32_16x16x32_bf16(
                    al[ib], bh[jb], acc[ib][jb], 0, 0, 0);
            }
        __syncthreads();
    }

#pragma unroll
    for (int ib = 0; ib < 4; ib++) {
#pragma unroll
        for (int r = 0; r < 4; r++) {
            const int gr = row0 + wm * 64 + ib * 16 + lr * 4 + r;
            const float mval = mask[gr];
            const int b = gr >> 12, t = gr & (TT - 1);
#pragma unroll
            for (int jb = 0; jb < 4; jb++) {
                const int c = col0 + wn * 64 + jb * 16 + lc;   // 0..511
                const int h = c >> 5, p = c & 31;
                P[(((size_t)(b * HH + h) * TT + t) * 32) + p] =
                    acc[ib][jb][r] * mval;
            }
        }
    }
}

// ---------------------------------------------------------------------------
// wproj: Wproj[k][h*32+p] = sum_d Wk[k][h*64+d] * planesT[d][p].  (fp32)
// ---------------------------------------------------------------------------
__global__ __launch_bounds__(256) void wproj_k(
    const float* __restrict__ Wk, const float* __restrict__ planesT,
    float* __restrict__ Wp)
{
    __shared__ float sW[1024];
    __shared__ float sP[2048];
    const int tid = threadIdx.x;
    const int k = blockIdx.x;
    for (int i = tid; i < 1024; i += 256) sW[i] = Wk[(size_t)k * 1024 + i];
    for (int i = tid; i < 2048; i += 256) sP[i] = planesT[i];
    __syncthreads();
#pragma unroll
    for (int c0 = 0; c0 < 2; c0++) {
        const int c = c0 * 256 + tid;          // 0..511
        const int h = c >> 5, p = c & 31;
        float s = 0.f;
#pragma unroll
        for (int d = 0; d < 64; d++)
            s = fmaf(sW[h * 64 + d], sP[d * 32 + p], s);
        Wp[(size_t)k * 512 + c] = s;
    }
}

// ---------------------------------------------------------------------------
// Zero-fill gBK ++ gBV ++ gA (contiguous, 1,056,768 floats).
// ---------------------------------------------------------------------------
__global__ __launch_bounds__(256) void zero_k(float* __restrict__ p)
{
    const size_t i = ((size_t)blockIdx.x * 256 + threadIdx.x) * 4;
    *(float4*)&p[i] = make_float4(0.f, 0.f, 0.f, 0.f);
}

// ---------------------------------------------------------------------------
// Assignment: reads precomputed fp32-accurate proj.
// ---------------------------------------------------------------------------
__global__ __launch_bounds__(256) void assign_k(
    const float* __restrict__ Pj, const float* __restrict__ protosT,
    const float* __restrict__ logit_temp,
    unsigned char* __restrict__ aIdx, float* __restrict__ aW,
    float* __restrict__ gA)
{
    __shared__ float sPr[4][16];
    __shared__ float sCnt[SS];
    const int tid = threadIdx.x;
    const int tc = blockIdx.x;
    const int bh = blockIdx.y;

    if (tid < 64)  ((float*)sPr)[tid] = protosT[tid];
    if (tid < SS)  sCnt[tid] = 0.f;
    __syncthreads();

    const float scale = fminf(fmaxf(__expf(logit_temp[0]), 0.01f), 20.0f);
    const float inv_scale = 1.0f / scale;

    const int t = tc * 256 + tid;
    const float* pr = Pj + ((size_t)bh * TT + t) * 32;
    float proj[32];
#pragma unroll
    for (int j = 0; j < 8; j++) {
        const float4 v = *(const float4*)&pr[j * 4];
        proj[j * 4 + 0] = v.x; proj[j * 4 + 1] = v.y;
        proj[j * 4 + 2] = v.z; proj[j * 4 + 3] = v.w;
    }
#pragma unroll
    for (int p = 0; p < 32; p++) proj[p] = tanhf(proj[p]) * inv_scale;

    unsigned char idx[16];
    float wv[16];
#pragma unroll
    for (int l = 0; l < 8; l++) {
        float g[16];
#pragma unroll
        for (int r = 0; r < 16; r++)
            g[r] = proj[l * 4 + 0] * sPr[0][r] + proj[l * 4 + 1] * sPr[1][r] +
                   proj[l * 4 + 2] * sPr[2][r] + proj[l * 4 + 3] * sPr[3][r];
        float mx = g[0];
#pragma unroll
        for (int r = 1; r < 16; r++) mx = fmaxf(mx, g[r]);
        float Zs = 0.f;
#pragma unroll
        for (int r = 0; r < 16; r++) Zs += __expf(g[r] - mx);
        int a = 0; float ga = g[0];
#pragma unroll
        for (int r = 1; r < 16; r++) { if (g[r] > ga) { ga = g[r]; a = r; } }
        int b2 = (a == 0) ? 1 : 0; float gb = g[b2];
#pragma unroll
        for (int r = 0; r < 16; r++) { if (r != a && g[r] > gb) { gb = g[r]; b2 = r; } }
        const float pa = __expf(ga - mx) / Zs;
        const float pb = __expf(gb - mx) / Zs;
        const float den = pa + pb + 1e-6f;
        const float wa = pa / den, wb = pb / den;
        idx[l * 2 + 0] = (unsigned char)(l * 16 + a);  wv[l * 2 + 0] = wa;
        idx[l * 2 + 1] = (unsigned char)(l * 16 + b2); wv[l * 2 + 1] = wb;
        atomicAdd(&sCnt[l * 16 + a],  wa);
        atomicAdd(&sCnt[l * 16 + b2], wb);
    }
    const size_t off = (size_t)bh * TT + t;
    uint32_t pk[4];
#pragma unroll
    for (int j = 0; j < 4; j++)
        pk[j] = (uint32_t)idx[j * 4] | ((uint32_t)idx[j * 4 + 1] << 8) |
                ((uint32_t)idx[j * 4 + 2] << 16) | ((uint32_t)idx[j * 4 + 3] << 24);
    *(uint4*)&aIdx[off * 16] = make_uint4(pk[0], pk[1], pk[2], pk[3]);
#pragma unroll
    for (int j = 0; j < 4; j++)
        *(float4*)&aW[off * 16 + j * 4] =
            make_float4(wv[j * 4], wv[j * 4 + 1], wv[j * 4 + 2], wv[j * 4 + 3]);
    __syncthreads();
    if (tid < SS) atomicAdd(&gA[bh * SS + tid], sCnt[tid]);
}

// ---------------------------------------------------------------------------
// Scatter as MFMA GEMM (unchanged).
// ---------------------------------------------------------------------------
__global__ __launch_bounds__(256) void scatter4_k(
    const float* __restrict__ Kb, const float* __restrict__ Vb,
    const unsigned char* __restrict__ aIdx, const float* __restrict__ aW,
    float* __restrict__ gBK, float* __restrict__ gBV)
{
    __shared__ short sA[8192];
    __shared__ short sB[8192];
    const int tid = threadIdx.x;
    const int tc = blockIdx.x;   // 8
    const int bh = blockIdx.y;   // 64
    const int w  = tid >> 6, ln = tid & 63;
    const int wm = w & 1, wn = w >> 1;

    f32x4 acc[4][4];
#pragma unroll
    for (int i = 0; i < 4; i++)
#pragma unroll
        for (int j = 0; j < 4; j++) acc[i][j] = (f32x4){0.f, 0.f, 0.f, 0.f};

    const int scol = tid & 127;
    const int stg  = tid >> 7;
    const float* srcrow = (scol < 64)
        ? Kb + (size_t)bh * (TT * DIMM) + scol
        : Vb + (size_t)bh * (TT * DIMM) + (scol - 64);
    const int bchunk = (scol >> 4);
    const int bslot8 = (scol & 15) * 8;
    const int ptt = tid >> 2, pg = tid & 3;

    for (int c = 0; c < 8; c++) {
        const int t0 = tc * 512 + c * 64;
        __syncthreads();
        {
            const uint4 z = make_uint4(0u, 0u, 0u, 0u);
#pragma unroll
            for (int r = 0; r < 4; r++)
                *(uint4*)&sA[(r * 256 + tid) * 8] = z;
        }
        __syncthreads();
#pragma unroll 8
        for (int r = 0; r < 32; r++) {
            const int tt = stg * 32 + r;
            const float v = srcrow[(size_t)(t0 + tt) * DIMM];
            sB[((tt >> 5) * 8 + bchunk) * 512 + ((tt >> 3) & 3) * 128 +
               bslot8 + (tt & 7)] = f2bf(v);
        }
        {
            const size_t off = (size_t)bh * TT + (t0 + ptt);
            const uint32_t pk = ((const uint32_t*)aIdx)[off * 4 + pg];
            const float4 wv = *(const float4*)&aW[off * 16 + pg * 4];
            const float w4[4] = {wv.x, wv.y, wv.z, wv.w};
#pragma unroll
            for (int q = 0; q < 4; q++) {
                const int s = (pk >> (8 * q)) & 255;
                sA[((ptt >> 5) * 8 + (s >> 4)) * 512 + ((ptt >> 3) & 3) * 128 +
                   (s & 15) * 8 + (ptt & 7)] = f2bf(w4[q]);
            }
        }
        __syncthreads();
#pragma unroll
        for (int ks = 0; ks < 2; ks++) {
            bf16x8 af[4], bfr[4];
#pragma unroll
            for (int ib = 0; ib < 4; ib++)
                af[ib] = *(const bf16x8*)&sA[(ks * 8 + wm * 4 + ib) * 512 + ln * 8];
#pragma unroll
            for (int jb = 0; jb < 4; jb++)
                bfr[jb] = *(const bf16x8*)&sB[(ks * 8 + wn * 4 + jb) * 512 + ln * 8];
#pragma unroll
            for (int ib = 0; ib < 4; ib++)
#pragma unroll
                for (int jb = 0; jb < 4; jb++)
                    acc[ib][jb] = __builtin_amdgcn_mfma_f32_16x16x32_bf16(
                        af[ib], bfr[jb], acc[ib][jb], 0, 0, 0);
        }
    }

    const int lr = ln >> 4, lc = ln & 15;
#pragma unroll
    for (int ib = 0; ib < 4; ib++) {
#pragma unroll
        for (int r = 0; r < 4; r++) {
            const int s = wm * 64 + ib * 16 + lr * 4 + r;
#pragma unroll
            for (int jb = 0; jb < 4; jb++) {
                const int col = wn * 64 + jb * 16 + lc;
                if (col < 64)
                    atomicAdd(&gBK[(size_t)bh * (SS * DIMM) + s * DIMM + col],
                              acc[ib][jb][r]);
                else
                    atomicAdd(&gBV[(size_t)bh * (SS * DIMM) + s * DIMM + (col - 64)],
                              acc[ib][jb][r]);
            }
        }
    }
}

// ---------------------------------------------------------------------------
// bprep: bucket K/V fp32 -> count-normalized bf16 fragment-linear layouts.
// ---------------------------------------------------------------------------
__global__ __launch_bounds__(256) void bprep_k(
    const float* __restrict__ gBK, const float* __restrict__ gBV,
    const float* __restrict__ gA,
    unsigned short* __restrict__ Kf, unsigned short* __restrict__ VTf)
{
    __shared__ float sInv[SS];
    const int tid = threadIdx.x;
    const int bh = blockIdx.y;
    if (tid < SS) sInv[tid] = 1.0f / (gA[bh * SS + tid] + 1e-6f);
    __syncthreads();
#pragma unroll
    for (int it = 0; it < 8; it++) {
        const int i = (blockIdx.x * 8 + it) * 256 + tid;   // 0..8191
        const int s = i >> 6, d = i & 63;
        const float kv = gBK[(size_t)bh * 8192 + i] * sInv[s];
        const float vv = gBV[(size_t)bh * 8192 + i] * sInv[s];
        const int ek = ((s >> 4) * 2 + (d >> 5)) * 512 +
                       ((s & 15) + ((d >> 3) & 3) * 16) * 8 + (d & 7);
        const int ev = ((d >> 4) * 4 + (s >> 5)) * 512 +
                       ((d & 15) + ((s >> 3) & 3) * 16) * 8 + (s & 7);
        Kf[(size_t)bh * 8192 + ek]  = f2bf(kv);
        VTf[(size_t)bh * 8192 + ev] = f2bf(vv);
    }
}

// ---------------------------------------------------------------------------
// MFMA attention (unchanged).
// ---------------------------------------------------------------------------
__global__ __launch_bounds__(256) void attn_m(
    const unsigned short* __restrict__ Qf, const unsigned short* __restrict__ Kf,
    const unsigned short* __restrict__ VTf, unsigned short* __restrict__ attb)
{
    __shared__ short sQ[8192];
    __shared__ short sK[8192];
    __shared__ short sVT[8192];
    __shared__ short sP[16384];
    const int tid = threadIdx.x;
    const int tc = blockIdx.x;     // 32 tiles of 128 tokens
    const int bh = blockIdx.y;     // 64
    const int w = tid >> 6, l = tid & 63;

    const size_t qbase  = (size_t)bh * 262144 + (size_t)tc * 8192;
    const size_t kvbase = (size_t)bh * 8192;
#pragma unroll
    for (int i = 0; i < 4; i++) {
        const int o = (i * 256 + w * 64) * 8;
        GLD16(&sQ[o],  Qf  + qbase  + o + l * 8);
        GLD16(&sK[o],  Kf  + kvbase + o + l * 8);
        GLD16(&sVT[o], VTf + kvbase + o + l * 8);
    }
    __syncthreads();

    f32x4 acc[2][8];
#pragma unroll
    for (int i = 0; i < 2; i++)
#pragma unroll
        for (int j = 0; j < 8; j++) acc[i][j] = (f32x4){0.f, 0.f, 0.f, 0.f};

#pragma unroll
    for (int ks = 0; ks < 2; ks++) {
        const bf16x8 a0 = *(const bf16x8*)&sQ[((w * 2 + 0) * 2 + ks) * 512 + l * 8];
        const bf16x8 a1 = *(const bf16x8*)&sQ[((w * 2 + 1) * 2 + ks) * 512 + l * 8];
#pragma unroll
        for (int jb = 0; jb < 8; jb++) {
            const bf16x8 b = *(const bf16x8*)&sK[(jb * 2 + ks) * 512 + l * 8];
            acc[0][jb] = __builtin_amdgcn_mfma_f32_16x16x32_bf16(a0, b, acc[0][jb], 0, 0, 0);
            acc[1][jb] = __builtin_amdgcn_mfma_f32_16x16x32_bf16(a1, b, acc[1][jb], 0, 0, 0);
        }
    }

#pragma unroll
    for (int ib = 0; ib < 2; ib++) {
        const int mb = w * 2 + ib;
#pragma unroll
        for (int r = 0; r < 4; r++) {
            float v[8];
            float mx = -INFINITY;
#pragma unroll
            for (int jb = 0; jb < 8; jb++) {
                v[jb] = acc[ib][jb][r] * 0.125f;
                mx = fmaxf(mx, v[jb]);
            }
            mx = fmaxf(mx, __shfl_xor(mx, 1));
            mx = fmaxf(mx, __shfl_xor(mx, 2));
            mx = fmaxf(mx, __shfl_xor(mx, 4));
            mx = fmaxf(mx, __shfl_xor(mx, 8));
            float Z = 0.f;
#pragma unroll
            for (int jb = 0; jb < 8; jb++) { v[jb] = __expf(v[jb] - mx); Z += v[jb]; }
            Z += __shfl_xor(Z, 1);
            Z += __shfl_xor(Z, 2);
            Z += __shfl_xor(Z, 4);
            Z += __shfl_xor(Z, 8);
            const float invZ = 1.0f / Z;
            const int ttl = (l >> 4) * 4 + r;
#pragma unroll
            for (int jb = 0; jb < 8; jb++) {
                int e = (mb * 4 + (jb >> 1)) * 512 +
                        (ttl + (((jb * 2 + ((l >> 3) & 1)) & 3) * 16)) * 8 + (l & 7);
                e ^= ((e >> 7) & 3) << 4;
                sP[e] = (short)f2bf(v[jb] * invZ);
            }
        }
    }

    f32x4 acc2[2][4];
#pragma unroll
    for (int i = 0; i < 2; i++)
#pragma unroll
        for (int j = 0; j < 4; j++) acc2[i][j] = (f32x4){0.f, 0.f, 0.f, 0.f};

#pragma unroll
    for (int ks = 0; ks < 4; ks++) {
        bf16x8 a[2];
#pragma unroll
        for (int ib = 0; ib < 2; ib++) {
            int ia = ((w * 2 + ib) * 4 + ks) * 512 + l * 8;
            ia ^= ((ia >> 7) & 3) << 4;
            a[ib] = *(const bf16x8*)&sP[ia];
        }
#pragma unroll
        for (int jb = 0; jb < 4; jb++) {
            const bf16x8 b = *(const bf16x8*)&sVT[(jb * 4 + ks) * 512 + l * 8];
            acc2[0][jb] = __builtin_amdgcn_mfma_f32_16x16x32_bf16(a[0], b, acc2[0][jb], 0, 0, 0);
            acc2[1][jb] = __builtin_amdgcn_mfma_f32_16x16x32_bf16(a[1], b, acc2[1][jb], 0, 0, 0);
        }
    }

    const int b = bh >> 4, h = bh & 15;
#pragma unroll
    for (int ib = 0; ib < 2; ib++) {
#pragma unroll
        for (int r = 0; r < 4; r++) {
            const int t = tc * 128 + w * 32 + ib * 16 + (l >> 4) * 4 + r;
            unsigned short* outp = attb + ((size_t)(b * TT + t)) * DD + h * DIMM;
#pragma unroll
            for (int jb = 0; jb < 4; jb++)
                outp[jb * 16 + (l & 15)] = f2bf(acc2[ib][jb][r]);
        }
    }
}

// ---------------------------------------------------------------------------
// Launcher. Workspace (float offsets):
//   Qf bf16 at ws+0 (32 MB; Wp/WphT/WplT scratch there before qkv) |
//   Kb 1<<24 | Vb 2<<24 (xlo until projm; attb after scatter; WoutT at
//   41943040) | gBK 3<<24 | gBV +512K | gA +512K | xb at 51388416
//   ([51388416, 59777024) — aW/aIdx/Kf/VTf alias it ONLY after qkv's last
//   read).  BTall (3072x1024 bf16, 6 MB) lives in d_out's SECOND half
//   (d_out+8388608 floats): Pj uses d_out[0:8388608); both dead before the
//   final out_k overwrites d_out.  [r4 bug: BTall at ws+57155584 was inside
//   xb -> tr_k clobbered x rows 11264-14335 before qkv read them.]
// ---------------------------------------------------------------------------
extern "C" void kernel_launch(void* const* d_in, const int* in_sizes, int n_in,
                              void* d_out, int out_size, void* d_ws, size_t ws_size,
                              hipStream_t stream)
{
    const float* x       = (const float*)d_in[0];
    const float* mask    = (const float*)d_in[1];
    const float* Wq      = (const float*)d_in[2];
    const float* Wk      = (const float*)d_in[3];
    const float* Wv      = (const float*)d_in[4];
    const float* Wout    = (const float*)d_in[5];
    const float* b_out   = (const float*)d_in[6];
    const float* planesT = (const float*)d_in[7];
    const float* protosT = (const float*)d_in[8];
    const float* ltemp   = (const float*)d_in[9];
    float* out = (float*)d_out;

    float* ws  = (float*)d_ws;
    float* Kb  = ws + (1u << 24);
    float* Vb  = ws + (2u << 24);
    float* gBK = ws + (3u << 24);
    float* gBV = gBK + 524288;
    float* gA  = gBV + 524288;
    unsigned short* Qf    = (unsigned short*)ws;
    unsigned short* xb    = (unsigned short*)(ws + 51388416);
    unsigned short* xlo   = (unsigned short*)Vb;             // dead before qkv
    float*          Wp    = ws;                              // dead before qkv
    unsigned short* WphT  = (unsigned short*)(ws + 524288);
    unsigned short* WplT  = (unsigned short*)(ws + 786432);
    float*          aW    = ws + 51388416;                   // aliases xb (dead)
    unsigned char*  aIdx  = (unsigned char*)(ws + 55582720);
    unsigned short* Kf    = (unsigned short*)(ws + 56631296);
    unsigned short* VTf   = (unsigned short*)(ws + 56893440);
    unsigned short* attb  = (unsigned short*)Vb;             // Vb dead after scatter
    unsigned short* WoutT = (unsigned short*)(ws + 41943040);
    float*          Pj    = (float*)d_out;                   // d_out[0 : 8388608)
    unsigned short* BTall = (unsigned short*)((float*)d_out + 8388608); // d_out 2nd half

    const dim3 tg(32, 32);     // transpose grid
    const dim3 t2g(16, 32);    // Wp transpose grid
    const dim3 pg(4, 128);     // projm grid
    const dim3 qg(24, 128);    // fused qkv grid
    const dim3 og(8, 128);     // out gemm grid

    cvt2_k<<<8192, 256, 0, stream>>>(x, xb, xlo);

    // assignment projections (xlo in Vb; Wp/WphT/WplT in Qf region)
    wproj_k<<<1024, 256, 0, stream>>>(Wk, planesT, Wp);
    tr2_k<<<t2g, 256, 0, stream>>>(Wp, WphT, WplT);
    projm_k<<<pg, 256, 0, stream>>>(xb, xlo, WphT, WplT, mask, Pj);

    // fused Q/K/V projection (BTall in d_out second half — NOT in xb!)
    tr_k<<<tg, 256, 0, stream>>>(Wq, BTall);
    tr_k<<<tg, 256, 0, stream>>>(Wk, BTall + 1048576);
    tr_k<<<tg, 256, 0, stream>>>(Wv, BTall + 2097152);
    qkv_k<<<qg, 256, 0, stream>>>(xb, BTall, mask, Qf, Kb, Vb);

    zero_k<<<1032, 256, 0, stream>>>(gBK);                   // gBK ++ gBV ++ gA
    assign_k<<<dim3(16, 64), 256, 0, stream>>>(Pj, protosT, ltemp, aIdx, aW, gA);
    scatter4_k<<<dim3(8, 64), 256, 0, stream>>>(Kb, Vb, aIdx, aW, gBK, gBV);

    bprep_k<<<dim3(4, 64), 256, 0, stream>>>(gBK, gBV, gA, Kf, VTf);
    tr_k<<<tg, 256, 0, stream>>>(Wout, WoutT);
    attn_m<<<dim3(32, 64), 256, 0, stream>>>(Qf, Kf, VTf, attb);

    out_k<<<og, 256, 0, stream>>>(attb, WoutT, b_out, out);
}

// Round 6
// 629.852 us; speedup vs baseline: 1.8512x; 1.0476x over previous
//
#include <hip/hip_runtime.h>
#include <math.h>
#include <stdint.h>

// Problem constants (B=4, T=4096, D=1024, H=16, DIM=64, L=8, KB=4, R=16, S=128)
#define TT   4096
#define DD   1024
#define HH   16
#define DIMM 64
#define SS   128

typedef short bf16x8 __attribute__((ext_vector_type(8)));
typedef float f32x4  __attribute__((ext_vector_type(4)));

// fp32 -> bf16 (RNE), finite inputs
__device__ __forceinline__ unsigned short f2bf(float f) {
    uint32_t u = __float_as_uint(f);
    return (unsigned short)((u + 0x7fffu + ((u >> 16) & 1u)) >> 16);
}
__device__ __forceinline__ float bf2f(unsigned short h) {
    return __uint_as_float((uint32_t)h << 16);
}

// async global->LDS, 16B per lane; LDS dest = WAVE-UNIFORM base + lane*16
#define GLD16(ldsp, gp) __builtin_amdgcn_global_load_lds( \
    (const __attribute__((address_space(1))) uint32_t*)(gp), \
    (__attribute__((address_space(3))) uint32_t*)(ldsp), 16, 0, 0)

// ---------------------------------------------------------------------------
// cvt2: x fp32 -> bf16 hi (xb) + bf16 lo residual (xlo). 8 per thread.
// ---------------------------------------------------------------------------
__global__ __launch_bounds__(256) void cvt2_k(const float* __restrict__ x,
                                              unsigned short* __restrict__ xb,
                                              unsigned short* __restrict__ xlo)
{
    const size_t i = ((size_t)blockIdx.x * 256 + threadIdx.x) * 8;
    const float4 a = *(const float4*)&x[i];
    const float4 b = *(const float4*)&x[i + 4];
    const float v[8] = {a.x, a.y, a.z, a.w, b.x, b.y, b.z, b.w};
    unsigned short h[8], l[8];
#pragma unroll
    for (int j = 0; j < 8; j++) {
        h[j] = f2bf(v[j]);
        l[j] = f2bf(v[j] - bf2f(h[j]));
    }
    uint4 rh, rl;
    rh.x = (uint32_t)h[0] | ((uint32_t)h[1] << 16);
    rh.y = (uint32_t)h[2] | ((uint32_t)h[3] << 16);
    rh.z = (uint32_t)h[4] | ((uint32_t)h[5] << 16);
    rh.w = (uint32_t)h[6] | ((uint32_t)h[7] << 16);
    rl.x = (uint32_t)l[0] | ((uint32_t)l[1] << 16);
    rl.y = (uint32_t)l[2] | ((uint32_t)l[3] << 16);
    rl.z = (uint32_t)l[4] | ((uint32_t)l[5] << 16);
    rl.w = (uint32_t)l[6] | ((uint32_t)l[7] << 16);
    *(uint4*)&xb[i]  = rh;
    *(uint4*)&xlo[i] = rl;
}

// ---------------------------------------------------------------------------
// tr: W (1024x1024 fp32, K-major) -> WT (1024x1024 bf16, N-major: WT[n][k]).
// ---------------------------------------------------------------------------
__global__ __launch_bounds__(256) void tr_k(const float* __restrict__ W,
                                            unsigned short* __restrict__ WT)
{
    __shared__ unsigned short tile[32][33];
    const int bx = blockIdx.x * 32;   // W col (=n) base
    const int by = blockIdx.y * 32;   // W row (=k) base
    const int tx = threadIdx.x & 31, ty = threadIdx.x >> 5;  // ty 0..7
#pragma unroll
    for (int r = 0; r < 4; r++) {
        const int row = by + ty * 4 + r;
        tile[tx][ty * 4 + r] = f2bf(W[(size_t)row * 1024 + bx + tx]);
    }
    __syncthreads();
#pragma unroll
    for (int r = 0; r < 4; r++) {
        const int col = bx + ty * 4 + r;
        WT[(size_t)col * 1024 + by + tx] = tile[ty * 4 + r][tx];
    }
}

// ---------------------------------------------------------------------------
// tr2: Wp (1024x512 fp32, K-major) -> WphT/WplT (512x1024 bf16 hi/lo).
// ---------------------------------------------------------------------------
__global__ __launch_bounds__(256) void tr2_k(const float* __restrict__ Wp,
                                             unsigned short* __restrict__ WphT,
                                             unsigned short* __restrict__ WplT)
{
    __shared__ float tile[32][33];
    const int bx = blockIdx.x * 32;   // n base (0..511)
    const int by = blockIdx.y * 32;   // k base (0..1023)
    const int tx = threadIdx.x & 31, ty = threadIdx.x >> 5;
#pragma unroll
    for (int r = 0; r < 4; r++) {
        const int row = by + ty * 4 + r;
        tile[tx][ty * 4 + r] = Wp[(size_t)row * 512 + bx + tx];
    }
    __syncthreads();
#pragma unroll
    for (int r = 0; r < 4; r++) {
        const int col = bx + ty * 4 + r;      // n
        const float v = tile[ty * 4 + r][tx];
        const unsigned short hi = f2bf(v);
        const unsigned short lo = f2bf(v - bf2f(hi));
        WphT[(size_t)col * 1024 + by + tx] = hi;
        WplT[(size_t)col * 1024 + by + tx] = lo;
    }
}

// ---------------------------------------------------------------------------
// qkv: fused Q/K/V projection. (16384x3072) = xb @ [WqT;WkT;WvT]^T.
// 128x128 tile, BK=32, 2-phase dbuf LDS. XCD remap with 12-colblk groups
// (B-group 3MB stays L2-hot across the 16 bands per XCD; A refetched x2).
// Epilogues go acc -> 32KB LDS tile (reusing K-loop buffers) -> coalesced
// 16B stores:
//   Q (colblk 0-7):  bf16 Qf in attn fragment-linear layout.
//   K (8-15)/V (16-23): bf16 KVf[bh][chunk64][scatter-B-frag] (K at n 0-63,
//   V at n 64-127 within each 16KB chunk tile). Same f2bf(acc*mask) bits
//   as the old fp32->scatter-f2bf path => numerics identical.
// ---------------------------------------------------------------------------
__global__ __launch_bounds__(256) void qkv_k(
    const unsigned short* __restrict__ Abf, const unsigned short* __restrict__ BT,
    const float* __restrict__ mask, unsigned short* __restrict__ Qf,
    unsigned short* __restrict__ KVf)
{
    __shared__ short sMem[16384];   // 32 KB: [2][4096] A ++ [2][4096] B; epilogue tile
    short* sA = sMem;
    short* sB = sMem + 8192;
    const int tid = threadIdx.x;
    const int w  = tid >> 6;          // wave 0..3
    const int ln = tid & 63;          // lane
    const int wm = w & 1, wn = w >> 1;
    // XCD remap: (xcd, colgroup of 12, band of 16, colblk-in-group)
    const int id   = blockIdx.y * 24 + blockIdx.x;
    const int xcd  = id & 7, kk = id >> 3;        // kk in [0,384)
    const int cg   = kk / 192, rem = kk % 192;
    const int band = xcd * 16 + rem / 12;
    const int colblk = cg * 12 + rem % 12;
    const int row0 = band * 128;
    const int col0 = colblk * 128;
    const int lr = ln >> 4, lc = ln & 15;

    f32x4 acc[4][4];
#pragma unroll
    for (int i = 0; i < 4; i++)
#pragma unroll
        for (int j = 0; j < 4; j++) acc[i][j] = (f32x4){0.f, 0.f, 0.f, 0.f};

    const int ia0 = 2 * w, ia1 = 2 * w + 1;
    const size_t gA0 = (size_t)(row0 + ia0 * 16 + lc) * 1024 + lr * 8;
    const size_t gA1 = (size_t)(row0 + ia1 * 16 + lc) * 1024 + lr * 8;
    const size_t gB0 = (size_t)(col0 + ia0 * 16 + lc) * 1024 + lr * 8;
    const size_t gB1 = (size_t)(col0 + ia1 * 16 + lc) * 1024 + lr * 8;

    auto STAGE = [&](int buf, int k0) {
        GLD16(&sA[buf * 4096 + ia0 * 512], Abf + gA0 + k0);
        GLD16(&sA[buf * 4096 + ia1 * 512], Abf + gA1 + k0);
        GLD16(&sB[buf * 4096 + ia0 * 512], BT  + gB0 + k0);
        GLD16(&sB[buf * 4096 + ia1 * 512], BT  + gB1 + k0);
    };

    STAGE(0, 0);
    __syncthreads();
    for (int t = 0; t < 32; t++) {
        const int cur = t & 1;
        if (t < 31) STAGE(cur ^ 1, (t + 1) * 32);
        bf16x8 af[4], bfr[4];
#pragma unroll
        for (int ib = 0; ib < 4; ib++)
            af[ib] = *(const bf16x8*)&sA[cur * 4096 + (wm * 4 + ib) * 512 + ln * 8];
#pragma unroll
        for (int jb = 0; jb < 4; jb++)
            bfr[jb] = *(const bf16x8*)&sB[cur * 4096 + (wn * 4 + jb) * 512 + ln * 8];
#pragma unroll
        for (int ib = 0; ib < 4; ib++)
#pragma unroll
            for (int jb = 0; jb < 4; jb++)
                acc[ib][jb] = __builtin_amdgcn_mfma_f32_16x16x32_bf16(
                    af[ib], bfr[jb], acc[ib][jb], 0, 0, 0);
        __syncthreads();                 // also makes sMem safe for epilogue reuse
    }

    const int proj = colblk >> 3;        // 0=Q 1=K 2=V
    const int b    = row0 >> 12;
    const int h0   = (colblk & 7) * 2;
    short* sT = sMem;                    // 32 KB epilogue tile

    if (proj == 0) {
        // stage: sT[wn*8192 + e]
#pragma unroll
        for (int ib = 0; ib < 4; ib++) {
#pragma unroll
            for (int r = 0; r < 4; r++) {
                const int tt = wm * 64 + ib * 16 + lr * 4 + r;   // 0..127
                const float mval = mask[row0 + tt];
#pragma unroll
                for (int jb = 0; jb < 4; jb++) {
                    const int d = jb * 16 + lc;
                    const int e = ((tt >> 4) * 2 + (d >> 5)) * 512 +
                                  ((tt & 15) + ((d >> 3) & 3) * 16) * 8 + (d & 7);
                    sT[wn * 8192 + e] = (short)f2bf(acc[ib][jb][r] * mval);
                }
            }
        }
        __syncthreads();
        const int tile = (row0 & (TT - 1)) >> 7;
#pragma unroll
        for (int i = 0; i < 8; i++) {
            const int flat = i * 256 + tid;          // 16B chunk id 0..2047
            const int h_l  = flat >> 10;
            const int off  = (flat & 1023) * 8;
            unsigned short* dst = Qf + (size_t)(b * HH + h0 + h_l) * 262144
                                + (size_t)tile * 8192 + off;
            *(uint4*)dst = *(const uint4*)&sT[h_l * 8192 + off];
        }
    } else {
        const int voff = (proj == 2) ? 4 : 0;
        // stage: sT[(wn*2+chunk)*4096 + ((tt6>>5)*4+jb)*512 + ((tt6>>3)&3)*128
        //          + lc*8 + (tt6&7)]
#pragma unroll
        for (int ib = 0; ib < 4; ib++) {
#pragma unroll
            for (int r = 0; r < 4; r++) {
                const int tt128 = wm * 64 + ib * 16 + lr * 4 + r;
                const float mval = mask[row0 + tt128];
                const int chunk = tt128 >> 6, tt6 = tt128 & 63;
                const int rbase = (wn * 2 + chunk) * 4096 +
                                  ((tt6 >> 3) & 3) * 128 + lc * 8 + (tt6 & 7);
                const int t5 = (tt6 >> 5) * 4 * 512;
#pragma unroll
                for (int jb = 0; jb < 4; jb++)
                    sT[rbase + t5 + jb * 512] = (short)f2bf(acc[ib][jb][r] * mval);
            }
        }
        __syncthreads();
        const int gc0 = (row0 & (TT - 1)) >> 6;
#pragma unroll
        for (int i = 0; i < 8; i++) {
            const int flat = i * 256 + tid;          // 16B chunk id 0..2047
            const int bf = flat >> 6;                // 1KB block 0..31
            const int wi = flat & 63;
            const int h_l = bf >> 4, chunk = (bf >> 3) & 1;
            const int tt5 = (bf >> 2) & 1, nb = bf & 3;
            const int lidx = (h_l * 2 + chunk) * 4096 + (tt5 * 4 + nb) * 512 + wi * 8;
            const size_t gidx = (size_t)(b * HH + h0 + h_l) * 524288
                              + (size_t)(gc0 + chunk) * 8192
                              + (size_t)(tt5 * 8 + nb + voff) * 512 + wi * 8;
            *(uint4*)&KVf[gidx] = *(const uint4*)&sT[lidx];
        }
    }
}

// ---------------------------------------------------------------------------
// out: C(16384x1024) = attb @ WoutT^T + bias, fp32 row-major. 2-phase dbuf
// + XCD remap (nwg = 1024 = 8 x 16 x 8).
// ---------------------------------------------------------------------------
__global__ __launch_bounds__(256) void out_k(
    const unsigned short* __restrict__ Abf, const unsigned short* __restrict__ BT,
    const float* __restrict__ bias, float* __restrict__ C)
{
    __shared__ short sA[2][4096];
    __shared__ short sB[2][4096];
    const int tid = threadIdx.x;
    const int w  = tid >> 6, ln = tid & 63;
    const int wm = w & 1, wn = w >> 1;
    const int id  = blockIdx.y * 8 + blockIdx.x;
    const int xcd = id & 7, kk = id >> 3;          // kk in [0,128)
    const int row0 = (xcd * 16 + (kk >> 3)) * 128;
    const int col0 = (kk & 7) * 128;
    const int lr = ln >> 4, lc = ln & 15;

    f32x4 acc[4][4];
#pragma unroll
    for (int i = 0; i < 4; i++)
#pragma unroll
        for (int j = 0; j < 4; j++) acc[i][j] = (f32x4){0.f, 0.f, 0.f, 0.f};

    const int ia0 = 2 * w, ia1 = 2 * w + 1;
    const size_t gA0 = (size_t)(row0 + ia0 * 16 + lc) * 1024 + lr * 8;
    const size_t gA1 = (size_t)(row0 + ia1 * 16 + lc) * 1024 + lr * 8;
    const size_t gB0 = (size_t)(col0 + ia0 * 16 + lc) * 1024 + lr * 8;
    const size_t gB1 = (size_t)(col0 + ia1 * 16 + lc) * 1024 + lr * 8;

    auto STAGE = [&](int buf, int k0) {
        GLD16(&sA[buf][ia0 * 512], Abf + gA0 + k0);
        GLD16(&sA[buf][ia1 * 512], Abf + gA1 + k0);
        GLD16(&sB[buf][ia0 * 512], BT  + gB0 + k0);
        GLD16(&sB[buf][ia1 * 512], BT  + gB1 + k0);
    };

    STAGE(0, 0);
    __syncthreads();
    for (int t = 0; t < 32; t++) {
        const int cur = t & 1;
        if (t < 31) STAGE(cur ^ 1, (t + 1) * 32);
        bf16x8 af[4], bfr[4];
#pragma unroll
        for (int ib = 0; ib < 4; ib++)
            af[ib] = *(const bf16x8*)&sA[cur][(wm * 4 + ib) * 512 + ln * 8];
#pragma unroll
        for (int jb = 0; jb < 4; jb++)
            bfr[jb] = *(const bf16x8*)&sB[cur][(wn * 4 + jb) * 512 + ln * 8];
#pragma unroll
        for (int ib = 0; ib < 4; ib++)
#pragma unroll
            for (int jb = 0; jb < 4; jb++)
                acc[ib][jb] = __builtin_amdgcn_mfma_f32_16x16x32_bf16(
                    af[ib], bfr[jb], acc[ib][jb], 0, 0, 0);
        __syncthreads();
    }

#pragma unroll
    for (int ib = 0; ib < 4; ib++) {
#pragma unroll
        for (int r = 0; r < 4; r++) {
            const int gr = row0 + wm * 64 + ib * 16 + lr * 4 + r;
#pragma unroll
            for (int jb = 0; jb < 4; jb++) {
                const int col = col0 + wn * 64 + jb * 16 + lc;
                C[(size_t)gr * 1024 + col] = acc[ib][jb][r] + bias[col];
            }
        }
    }
}

// ---------------------------------------------------------------------------
// projm: error-compensated bf16x2 MFMA GEMM for the assignment projections.
// ---------------------------------------------------------------------------
__global__ __launch_bounds__(256) void projm_k(
    const unsigned short* __restrict__ Ah, const unsigned short* __restrict__ Al,
    const unsigned short* __restrict__ Bh, const unsigned short* __restrict__ Bl,
    const float* __restrict__ mask, float* __restrict__ P)
{
    __shared__ short sAh[2][4096];
    __shared__ short sAl[2][4096];
    __shared__ short sBh[2][4096];
    __shared__ short sBl[2][4096];
    const int tid = threadIdx.x;
    const int w  = tid >> 6;
    const int ln = tid & 63;
    const int wm = w & 1, wn = w >> 1;
    const int id  = blockIdx.y * 4 + blockIdx.x;
    const int xcd = id & 7, kk = id >> 3;          // kk in [0,64)
    const int row0 = (xcd * 16 + (kk >> 2)) * 128;
    const int col0 = (kk & 3) * 128;
    const int lr = ln >> 4, lc = ln & 15;

    f32x4 acc[4][4];
#pragma unroll
    for (int i = 0; i < 4; i++)
#pragma unroll
        for (int j = 0; j < 4; j++) acc[i][j] = (f32x4){0.f, 0.f, 0.f, 0.f};

    const int ia0 = 2 * w, ia1 = 2 * w + 1;
    const size_t gA0 = (size_t)(row0 + ia0 * 16 + lc) * 1024 + lr * 8;
    const size_t gA1 = (size_t)(row0 + ia1 * 16 + lc) * 1024 + lr * 8;
    const size_t gB0 = (size_t)(col0 + ia0 * 16 + lc) * 1024 + lr * 8;
    const size_t gB1 = (size_t)(col0 + ia1 * 16 + lc) * 1024 + lr * 8;

    auto STAGE = [&](int buf, int k0) {
        GLD16(&sAh[buf][ia0 * 512], Ah + gA0 + k0);
        GLD16(&sAh[buf][ia1 * 512], Ah + gA1 + k0);
        GLD16(&sAl[buf][ia0 * 512], Al + gA0 + k0);
        GLD16(&sAl[buf][ia1 * 512], Al + gA1 + k0);
        GLD16(&sBh[buf][ia0 * 512], Bh + gB0 + k0);
        GLD16(&sBh[buf][ia1 * 512], Bh + gB1 + k0);
        GLD16(&sBl[buf][ia0 * 512], Bl + gB0 + k0);
        GLD16(&sBl[buf][ia1 * 512], Bl + gB1 + k0);
    };

    STAGE(0, 0);
    __syncthreads();
    for (int t = 0; t < 32; t++) {
        const int cur = t & 1;
        if (t < 31) STAGE(cur ^ 1, (t + 1) * 32);
        bf16x8 ah[4], al[4], bh[4], bl[4];
#pragma unroll
        for (int ib = 0; ib < 4; ib++) {
            ah[ib] = *(const bf16x8*)&sAh[cur][(wm * 4 + ib) * 512 + ln * 8];
            al[ib] = *(const bf16x8*)&sAl[cur][(wm * 4 + ib) * 512 + ln * 8];
        }
#pragma unroll
        for (int jb = 0; jb < 4; jb++) {
            bh[jb] = *(const bf16x8*)&sBh[cur][(wn * 4 + jb) * 512 + ln * 8];
            bl[jb] = *(const bf16x8*)&sBl[cur][(wn * 4 + jb) * 512 + ln * 8];
        }
#pragma unroll
        for (int ib = 0; ib < 4; ib++)
#pragma unroll
            for (int jb = 0; jb < 4; jb++) {
                acc[ib][jb] = __builtin_amdgcn_mfma_f32_16x16x32_bf16(
                    ah[ib], bh[jb], acc[ib][jb], 0, 0, 0);
                acc[ib][jb] = __builtin_amdgcn_mfma_f32_16x16x32_bf16(
                    ah[ib], bl[jb], acc[ib][jb], 0, 0, 0);
                acc[ib][jb] = __builtin_amdgcn_mfma_f32_16x16x32_bf16(
                    al[ib], bh[jb], acc[ib][jb], 0, 0, 0);
            }
        __syncthreads();
    }

#pragma unroll
    for (int ib = 0; ib < 4; ib++) {
#pragma unroll
        for (int r = 0; r < 4; r++) {
            const int gr = row0 + wm * 64 + ib * 16 + lr * 4 + r;
            const float mval = mask[gr];
            const int b = gr >> 12, t = gr & (TT - 1);
#pragma unroll
            for (int jb = 0; jb < 4; jb++) {
                const int c = col0 + wn * 64 + jb * 16 + lc;   // 0..511
                const int h = c >> 5, p = c & 31;
                P[(((size_t)(b * HH + h) * TT + t) * 32) + p] =
                    acc[ib][jb][r] * mval;
            }
        }
    }
}

// ---------------------------------------------------------------------------
// wproj: Wproj[k][h*32+p] = sum_d Wk[k][h*64+d] * planesT[d][p].  (fp32)
// ---------------------------------------------------------------------------
__global__ __launch_bounds__(256) void wproj_k(
    const float* __restrict__ Wk, const float* __restrict__ planesT,
    float* __restrict__ Wp)
{
    __shared__ float sW[1024];
    __shared__ float sP[2048];
    const int tid = threadIdx.x;
    const int k = blockIdx.x;
    for (int i = tid; i < 1024; i += 256) sW[i] = Wk[(size_t)k * 1024 + i];
    for (int i = tid; i < 2048; i += 256) sP[i] = planesT[i];
    __syncthreads();
#pragma unroll
    for (int c0 = 0; c0 < 2; c0++) {
        const int c = c0 * 256 + tid;          // 0..511
        const int h = c >> 5, p = c & 31;
        float s = 0.f;
#pragma unroll
        for (int d = 0; d < 64; d++)
            s = fmaf(sW[h * 64 + d], sP[d * 32 + p], s);
        Wp[(size_t)k * 512 + c] = s;
    }
}

// ---------------------------------------------------------------------------
// Zero-fill gBK ++ gBV ++ gA (contiguous, 1,056,768 floats).
// ---------------------------------------------------------------------------
__global__ __launch_bounds__(256) void zero_k(float* __restrict__ p)
{
    const size_t i = ((size_t)blockIdx.x * 256 + threadIdx.x) * 4;
    *(float4*)&p[i] = make_float4(0.f, 0.f, 0.f, 0.f);
}

// ---------------------------------------------------------------------------
// Assignment: reads precomputed fp32-accurate proj.
// ---------------------------------------------------------------------------
__global__ __launch_bounds__(256) void assign_k(
    const float* __restrict__ Pj, const float* __restrict__ protosT,
    const float* __restrict__ logit_temp,
    unsigned char* __restrict__ aIdx, float* __restrict__ aW,
    float* __restrict__ gA)
{
    __shared__ float sPr[4][16];
    __shared__ float sCnt[SS];
    const int tid = threadIdx.x;
    const int tc = blockIdx.x;
    const int bh = blockIdx.y;

    if (tid < 64)  ((float*)sPr)[tid] = protosT[tid];
    if (tid < SS)  sCnt[tid] = 0.f;
    __syncthreads();

    const float scale = fminf(fmaxf(__expf(logit_temp[0]), 0.01f), 20.0f);
    const float inv_scale = 1.0f / scale;

    const int t = tc * 256 + tid;
    const float* pr = Pj + ((size_t)bh * TT + t) * 32;
    float proj[32];
#pragma unroll
    for (int j = 0; j < 8; j++) {
        const float4 v = *(const float4*)&pr[j * 4];
        proj[j * 4 + 0] = v.x; proj[j * 4 + 1] = v.y;
        proj[j * 4 + 2] = v.z; proj[j * 4 + 3] = v.w;
    }
#pragma unroll
    for (int p = 0; p < 32; p++) proj[p] = tanhf(proj[p]) * inv_scale;

    unsigned char idx[16];
    float wv[16];
#pragma unroll
    for (int l = 0; l < 8; l++) {
        float g[16];
#pragma unroll
        for (int r = 0; r < 16; r++)
            g[r] = proj[l * 4 + 0] * sPr[0][r] + proj[l * 4 + 1] * sPr[1][r] +
                   proj[l * 4 + 2] * sPr[2][r] + proj[l * 4 + 3] * sPr[3][r];
        float mx = g[0];
#pragma unroll
        for (int r = 1; r < 16; r++) mx = fmaxf(mx, g[r]);
        float Zs = 0.f;
#pragma unroll
        for (int r = 0; r < 16; r++) Zs += __expf(g[r] - mx);
        int a = 0; float ga = g[0];
#pragma unroll
        for (int r = 1; r < 16; r++) { if (g[r] > ga) { ga = g[r]; a = r; } }
        int b2 = (a == 0) ? 1 : 0; float gb = g[b2];
#pragma unroll
        for (int r = 0; r < 16; r++) { if (r != a && g[r] > gb) { gb = g[r]; b2 = r; } }
        const float pa = __expf(ga - mx) / Zs;
        const float pb = __expf(gb - mx) / Zs;
        const float den = pa + pb + 1e-6f;
        const float wa = pa / den, wb = pb / den;
        idx[l * 2 + 0] = (unsigned char)(l * 16 + a);  wv[l * 2 + 0] = wa;
        idx[l * 2 + 1] = (unsigned char)(l * 16 + b2); wv[l * 2 + 1] = wb;
        atomicAdd(&sCnt[l * 16 + a],  wa);
        atomicAdd(&sCnt[l * 16 + b2], wb);
    }
    const size_t off = (size_t)bh * TT + t;
    uint32_t pk[4];
#pragma unroll
    for (int j = 0; j < 4; j++)
        pk[j] = (uint32_t)idx[j * 4] | ((uint32_t)idx[j * 4 + 1] << 8) |
                ((uint32_t)idx[j * 4 + 2] << 16) | ((uint32_t)idx[j * 4 + 3] << 24);
    *(uint4*)&aIdx[off * 16] = make_uint4(pk[0], pk[1], pk[2], pk[3]);
#pragma unroll
    for (int j = 0; j < 4; j++)
        *(float4*)&aW[off * 16 + j * 4] =
            make_float4(wv[j * 4], wv[j * 4 + 1], wv[j * 4 + 2], wv[j * 4 + 3]);
    __syncthreads();
    if (tid < SS) atomicAdd(&gA[bh * SS + tid], sCnt[tid]);
}

// ---------------------------------------------------------------------------
// Scatter as MFMA GEMM. KV tiles now arrive pre-formatted (KVf) -> staged
// with 4 GLD16/wave instead of 32 scalar loads + f2bf per thread.
// ---------------------------------------------------------------------------
__global__ __launch_bounds__(256) void scatter4_k(
    const unsigned short* __restrict__ KVf,
    const unsigned char* __restrict__ aIdx, const float* __restrict__ aW,
    float* __restrict__ gBK, float* __restrict__ gBV)
{
    __shared__ short sA[8192];
    __shared__ short sB[8192];
    const int tid = threadIdx.x;
    const int tc = blockIdx.x;   // 8
    const int bh = blockIdx.y;   // 64
    const int w  = tid >> 6, ln = tid & 63;
    const int wm = w & 1, wn = w >> 1;

    f32x4 acc[4][4];
#pragma unroll
    for (int i = 0; i < 4; i++)
#pragma unroll
        for (int j = 0; j < 4; j++) acc[i][j] = (f32x4){0.f, 0.f, 0.f, 0.f};

    const size_t kvbase = (size_t)bh * 524288;
    const int ptt = tid >> 2, pg = tid & 3;

    for (int c = 0; c < 8; c++) {
        __syncthreads();                 // prior MFMA reads of sA/sB done
        // async-stage the pre-formatted 16KB KV tile (latency hides under
        // the zero + P^T scatter below; drained by the barrier before MFMA)
        const size_t cbase = kvbase + (size_t)(tc * 8 + c) * 8192;
#pragma unroll
        for (int i = 0; i < 4; i++) {
            const int seg = w * 4 + i;   // wave-uniform
            GLD16(&sB[seg * 512], KVf + cbase + seg * 512 + ln * 8);
        }
        {   // zero P^T region (16 KB)
            const uint4 z = make_uint4(0u, 0u, 0u, 0u);
#pragma unroll
            for (int r = 0; r < 4; r++)
                *(uint4*)&sA[(r * 256 + tid) * 8] = z;
        }
        __syncthreads();                 // zero visible
        {   // scatter P^T: A(s = idx, k = ptt)
            const int t0 = tc * 512 + c * 64;
            const size_t off = (size_t)bh * TT + (t0 + ptt);
            const uint32_t pk = ((const uint32_t*)aIdx)[off * 4 + pg];
            const float4 wv = *(const float4*)&aW[off * 16 + pg * 4];
            const float w4[4] = {wv.x, wv.y, wv.z, wv.w};
#pragma unroll
            for (int q = 0; q < 4; q++) {
                const int s = (pk >> (8 * q)) & 255;
                sA[((ptt >> 5) * 8 + (s >> 4)) * 512 + ((ptt >> 3) & 3) * 128 +
                   (s & 15) * 8 + (ptt & 7)] = f2bf(w4[q]);
            }
        }
        __syncthreads();                 // tiles ready (drains GLD16 vmcnt)
#pragma unroll
        for (int ks = 0; ks < 2; ks++) {
            bf16x8 af[4], bfr[4];
#pragma unroll
            for (int ib = 0; ib < 4; ib++)
                af[ib] = *(const bf16x8*)&sA[(ks * 8 + wm * 4 + ib) * 512 + ln * 8];
#pragma unroll
            for (int jb = 0; jb < 4; jb++)
                bfr[jb] = *(const bf16x8*)&sB[(ks * 8 + wn * 4 + jb) * 512 + ln * 8];
#pragma unroll
            for (int ib = 0; ib < 4; ib++)
#pragma unroll
                for (int jb = 0; jb < 4; jb++)
                    acc[ib][jb] = __builtin_amdgcn_mfma_f32_16x16x32_bf16(
                        af[ib], bfr[jb], acc[ib][jb], 0, 0, 0);
        }
    }

    const int lr = ln >> 4, lc = ln & 15;
#pragma unroll
    for (int ib = 0; ib < 4; ib++) {
#pragma unroll
        for (int r = 0; r < 4; r++) {
            const int s = wm * 64 + ib * 16 + lr * 4 + r;
#pragma unroll
            for (int jb = 0; jb < 4; jb++) {
                const int col = wn * 64 + jb * 16 + lc;
                if (col < 64)
                    atomicAdd(&gBK[(size_t)bh * (SS * DIMM) + s * DIMM + col],
                              acc[ib][jb][r]);
                else
                    atomicAdd(&gBV[(size_t)bh * (SS * DIMM) + s * DIMM + (col - 64)],
                              acc[ib][jb][r]);
            }
        }
    }
}

// ---------------------------------------------------------------------------
// bprep: bucket K/V fp32 -> count-normalized bf16 fragment-linear layouts.
// ---------------------------------------------------------------------------
__global__ __launch_bounds__(256) void bprep_k(
    const float* __restrict__ gBK, const float* __restrict__ gBV,
    const float* __restrict__ gA,
    unsigned short* __restrict__ Kf, unsigned short* __restrict__ VTf)
{
    __shared__ float sInv[SS];
    const int tid = threadIdx.x;
    const int bh = blockIdx.y;
    if (tid < SS) sInv[tid] = 1.0f / (gA[bh * SS + tid] + 1e-6f);
    __syncthreads();
#pragma unroll
    for (int it = 0; it < 8; it++) {
        const int i = (blockIdx.x * 8 + it) * 256 + tid;   // 0..8191
        const int s = i >> 6, d = i & 63;
        const float kv = gBK[(size_t)bh * 8192 + i] * sInv[s];
        const float vv = gBV[(size_t)bh * 8192 + i] * sInv[s];
        const int ek = ((s >> 4) * 2 + (d >> 5)) * 512 +
                       ((s & 15) + ((d >> 3) & 3) * 16) * 8 + (d & 7);
        const int ev = ((d >> 4) * 4 + (s >> 5)) * 512 +
                       ((d & 15) + ((s >> 3) & 3) * 16) * 8 + (s & 7);
        Kf[(size_t)bh * 8192 + ek]  = f2bf(kv);
        VTf[(size_t)bh * 8192 + ev] = f2bf(vv);
    }
}

// ---------------------------------------------------------------------------
// MFMA attention (unchanged).
// ---------------------------------------------------------------------------
__global__ __launch_bounds__(256) void attn_m(
    const unsigned short* __restrict__ Qf, const unsigned short* __restrict__ Kf,
    const unsigned short* __restrict__ VTf, unsigned short* __restrict__ attb)
{
    __shared__ short sQ[8192];
    __shared__ short sK[8192];
    __shared__ short sVT[8192];
    __shared__ short sP[16384];
    const int tid = threadIdx.x;
    const int tc = blockIdx.x;     // 32 tiles of 128 tokens
    const int bh = blockIdx.y;     // 64
    const int w = tid >> 6, l = tid & 63;

    const size_t qbase  = (size_t)bh * 262144 + (size_t)tc * 8192;
    const size_t kvbase = (size_t)bh * 8192;
#pragma unroll
    for (int i = 0; i < 4; i++) {
        const int o = (i * 256 + w * 64) * 8;
        GLD16(&sQ[o],  Qf  + qbase  + o + l * 8);
        GLD16(&sK[o],  Kf  + kvbase + o + l * 8);
        GLD16(&sVT[o], VTf + kvbase + o + l * 8);
    }
    __syncthreads();

    f32x4 acc[2][8];
#pragma unroll
    for (int i = 0; i < 2; i++)
#pragma unroll
        for (int j = 0; j < 8; j++) acc[i][j] = (f32x4){0.f, 0.f, 0.f, 0.f};

#pragma unroll
    for (int ks = 0; ks < 2; ks++) {
        const bf16x8 a0 = *(const bf16x8*)&sQ[((w * 2 + 0) * 2 + ks) * 512 + l * 8];
        const bf16x8 a1 = *(const bf16x8*)&sQ[((w * 2 + 1) * 2 + ks) * 512 + l * 8];
#pragma unroll
        for (int jb = 0; jb < 8; jb++) {
            const bf16x8 b = *(const bf16x8*)&sK[(jb * 2 + ks) * 512 + l * 8];
            acc[0][jb] = __builtin_amdgcn_mfma_f32_16x16x32_bf16(a0, b, acc[0][jb], 0, 0, 0);
            acc[1][jb] = __builtin_amdgcn_mfma_f32_16x16x32_bf16(a1, b, acc[1][jb], 0, 0, 0);
        }
    }

#pragma unroll
    for (int ib = 0; ib < 2; ib++) {
        const int mb = w * 2 + ib;
#pragma unroll
        for (int r = 0; r < 4; r++) {
            float v[8];
            float mx = -INFINITY;
#pragma unroll
            for (int jb = 0; jb < 8; jb++) {
                v[jb] = acc[ib][jb][r] * 0.125f;
                mx = fmaxf(mx, v[jb]);
            }
            mx = fmaxf(mx, __shfl_xor(mx, 1));
            mx = fmaxf(mx, __shfl_xor(mx, 2));
            mx = fmaxf(mx, __shfl_xor(mx, 4));
            mx = fmaxf(mx, __shfl_xor(mx, 8));
            float Z = 0.f;
#pragma unroll
            for (int jb = 0; jb < 8; jb++) { v[jb] = __expf(v[jb] - mx); Z += v[jb]; }
            Z += __shfl_xor(Z, 1);
            Z += __shfl_xor(Z, 2);
            Z += __shfl_xor(Z, 4);
            Z += __shfl_xor(Z, 8);
            const float invZ = 1.0f / Z;
            const int ttl = (l >> 4) * 4 + r;
#pragma unroll
            for (int jb = 0; jb < 8; jb++) {
                int e = (mb * 4 + (jb >> 1)) * 512 +
                        (ttl + (((jb * 2 + ((l >> 3) & 1)) & 3) * 16)) * 8 + (l & 7);
                e ^= ((e >> 7) & 3) << 4;
                sP[e] = (short)f2bf(v[jb] * invZ);
            }
        }
    }

    f32x4 acc2[2][4];
#pragma unroll
    for (int i = 0; i < 2; i++)
#pragma unroll
        for (int j = 0; j < 4; j++) acc2[i][j] = (f32x4){0.f, 0.f, 0.f, 0.f};

#pragma unroll
    for (int ks = 0; ks < 4; ks++) {
        bf16x8 a[2];
#pragma unroll
        for (int ib = 0; ib < 2; ib++) {
            int ia = ((w * 2 + ib) * 4 + ks) * 512 + l * 8;
            ia ^= ((ia >> 7) & 3) << 4;
            a[ib] = *(const bf16x8*)&sP[ia];
        }
#pragma unroll
        for (int jb = 0; jb < 4; jb++) {
            const bf16x8 b = *(const bf16x8*)&sVT[(jb * 4 + ks) * 512 + l * 8];
            acc2[0][jb] = __builtin_amdgcn_mfma_f32_16x16x32_bf16(a[0], b, acc2[0][jb], 0, 0, 0);
            acc2[1][jb] = __builtin_amdgcn_mfma_f32_16x16x32_bf16(a[1], b, acc2[1][jb], 0, 0, 0);
        }
    }

    const int b = bh >> 4, h = bh & 15;
#pragma unroll
    for (int ib = 0; ib < 2; ib++) {
#pragma unroll
        for (int r = 0; r < 4; r++) {
            const int t = tc * 128 + w * 32 + ib * 16 + (l >> 4) * 4 + r;
            unsigned short* outp = attb + ((size_t)(b * TT + t)) * DD + h * DIMM;
#pragma unroll
            for (int jb = 0; jb < 4; jb++)
                outp[jb * 16 + (l & 15)] = f2bf(acc2[ib][jb][r]);
        }
    }
}

// ---------------------------------------------------------------------------
// Launcher. Workspace (float offsets):
//   ws+0: Qf bf16 32MB (Wp/WphT/WplT scratch there before qkv) |
//   ws+(1<<24): BTall bf16 6MB (region otherwise dead) |
//   ws+(2<<24): xlo (until projm) -> KVf bf16 33.5MB (qkv..scatter) ->
//     attb bf16 (after scatter); WoutT at ws+41943040 (disjoint) |
//   ws+(3<<24): gBK | +512K gBV | +512K gA |
//   ws+51388416: xb (dead after qkv; then aW; aIdx at 55582720;
//     Kf 56631296; VTf 56893440).
//   d_out: Pj fp32 [0, 8388608) — overwritten by final out_k.
// ---------------------------------------------------------------------------
extern "C" void kernel_launch(void* const* d_in, const int* in_sizes, int n_in,
                              void* d_out, int out_size, void* d_ws, size_t ws_size,
                              hipStream_t stream)
{
    const float* x       = (const float*)d_in[0];
    const float* mask    = (const float*)d_in[1];
    const float* Wq      = (const float*)d_in[2];
    const float* Wk      = (const float*)d_in[3];
    const float* Wv      = (const float*)d_in[4];
    const float* Wout    = (const float*)d_in[5];
    const float* b_out   = (const float*)d_in[6];
    const float* planesT = (const float*)d_in[7];
    const float* protosT = (const float*)d_in[8];
    const float* ltemp   = (const float*)d_in[9];
    float* out = (float*)d_out;

    float* ws  = (float*)d_ws;
    float* gBK = ws + (3u << 24);
    float* gBV = gBK + 524288;
    float* gA  = gBV + 524288;
    unsigned short* Qf    = (unsigned short*)ws;
    unsigned short* BTall = (unsigned short*)(ws + (1u << 24));
    unsigned short* KVf   = (unsigned short*)(ws + (2u << 24));
    unsigned short* xlo   = KVf;                             // dead before qkv
    unsigned short* xb    = (unsigned short*)(ws + 51388416);
    float*          Wp    = ws;                              // dead before qkv
    unsigned short* WphT  = (unsigned short*)(ws + 524288);
    unsigned short* WplT  = (unsigned short*)(ws + 786432);
    float*          aW    = ws + 51388416;                   // aliases xb (dead)
    unsigned char*  aIdx  = (unsigned char*)(ws + 55582720);
    unsigned short* Kf    = (unsigned short*)(ws + 56631296);
    unsigned short* VTf   = (unsigned short*)(ws + 56893440);
    unsigned short* attb  = KVf;                             // KVf dead after scatter
    unsigned short* WoutT = (unsigned short*)(ws + 41943040);
    float*          Pj    = (float*)d_out;                   // d_out[0 : 8388608)

    const dim3 tg(32, 32);     // transpose grid
    const dim3 t2g(16, 32);    // Wp transpose grid
    const dim3 pg(4, 128);     // projm grid
    const dim3 qg(24, 128);    // fused qkv grid
    const dim3 og(8, 128);     // out gemm grid

    cvt2_k<<<8192, 256, 0, stream>>>(x, xb, xlo);

    // assignment projections (xlo in KVf region; Wp/WphT/WplT in Qf region)
    wproj_k<<<1024, 256, 0, stream>>>(Wk, planesT, Wp);
    tr2_k<<<t2g, 256, 0, stream>>>(Wp, WphT, WplT);
    projm_k<<<pg, 256, 0, stream>>>(xb, xlo, WphT, WplT, mask, Pj);

    // fused Q/K/V projection (BTall in its own dead region)
    tr_k<<<tg, 256, 0, stream>>>(Wq, BTall);
    tr_k<<<tg, 256, 0, stream>>>(Wk, BTall + 1048576);
    tr_k<<<tg, 256, 0, stream>>>(Wv, BTall + 2097152);
    qkv_k<<<qg, 256, 0, stream>>>(xb, BTall, mask, Qf, KVf);

    zero_k<<<1032, 256, 0, stream>>>(gBK);                   // gBK ++ gBV ++ gA
    assign_k<<<dim3(16, 64), 256, 0, stream>>>(Pj, protosT, ltemp, aIdx, aW, gA);
    scatter4_k<<<dim3(8, 64), 256, 0, stream>>>(KVf, aIdx, aW, gBK, gBV);

    bprep_k<<<dim3(4, 64), 256, 0, stream>>>(gBK, gBV, gA, Kf, VTf);
    tr_k<<<tg, 256, 0, stream>>>(Wout, WoutT);
    attn_m<<<dim3(32, 64), 256, 0, stream>>>(Qf, Kf, VTf, attb);

    out_k<<<og, 256, 0, stream>>>(attb, WoutT, b_out, out);
}

// Round 7
// 617.170 us; speedup vs baseline: 1.8893x; 1.0205x over previous
//
#include <hip/hip_runtime.h>
#include <math.h>
#include <stdint.h>

// Problem constants (B=4, T=4096, D=1024, H=16, DIM=64, L=8, KB=4, R=16, S=128)
#define TT   4096
#define DD   1024
#define HH   16
#define DIMM 64
#define SS   128

typedef short bf16x8 __attribute__((ext_vector_type(8)));
typedef float f32x4  __attribute__((ext_vector_type(4)));

// fp32 -> bf16 (RNE), finite inputs
__device__ __forceinline__ unsigned short f2bf(float f) {
    uint32_t u = __float_as_uint(f);
    return (unsigned short)((u + 0x7fffu + ((u >> 16) & 1u)) >> 16);
}
__device__ __forceinline__ float bf2f(unsigned short h) {
    return __uint_as_float((uint32_t)h << 16);
}

// async global->LDS, 16B per lane; LDS dest = WAVE-UNIFORM base + lane*16
#define GLD16(ldsp, gp) __builtin_amdgcn_global_load_lds( \
    (const __attribute__((address_space(1))) uint32_t*)(gp), \
    (__attribute__((address_space(3))) uint32_t*)(ldsp), 16, 0, 0)

// ---------------------------------------------------------------------------
// cvt2: x fp32 -> bf16 hi (xb) + bf16 lo residual (xlo). 8 per thread.
// ---------------------------------------------------------------------------
__global__ __launch_bounds__(256) void cvt2_k(const float* __restrict__ x,
                                              unsigned short* __restrict__ xb,
                                              unsigned short* __restrict__ xlo)
{
    const size_t i = ((size_t)blockIdx.x * 256 + threadIdx.x) * 8;
    const float4 a = *(const float4*)&x[i];
    const float4 b = *(const float4*)&x[i + 4];
    const float v[8] = {a.x, a.y, a.z, a.w, b.x, b.y, b.z, b.w};
    unsigned short h[8], l[8];
#pragma unroll
    for (int j = 0; j < 8; j++) {
        h[j] = f2bf(v[j]);
        l[j] = f2bf(v[j] - bf2f(h[j]));
    }
    uint4 rh, rl;
    rh.x = (uint32_t)h[0] | ((uint32_t)h[1] << 16);
    rh.y = (uint32_t)h[2] | ((uint32_t)h[3] << 16);
    rh.z = (uint32_t)h[4] | ((uint32_t)h[5] << 16);
    rh.w = (uint32_t)h[6] | ((uint32_t)h[7] << 16);
    rl.x = (uint32_t)l[0] | ((uint32_t)l[1] << 16);
    rl.y = (uint32_t)l[2] | ((uint32_t)l[3] << 16);
    rl.z = (uint32_t)l[4] | ((uint32_t)l[5] << 16);
    rl.w = (uint32_t)l[6] | ((uint32_t)l[7] << 16);
    *(uint4*)&xb[i]  = rh;
    *(uint4*)&xlo[i] = rl;
}

// ---------------------------------------------------------------------------
// tr: W (1024x1024 fp32, K-major) -> WT (1024x1024 bf16, N-major: WT[n][k]).
// ---------------------------------------------------------------------------
__global__ __launch_bounds__(256) void tr_k(const float* __restrict__ W,
                                            unsigned short* __restrict__ WT)
{
    __shared__ unsigned short tile[32][33];
    const int bx = blockIdx.x * 32;   // W col (=n) base
    const int by = blockIdx.y * 32;   // W row (=k) base
    const int tx = threadIdx.x & 31, ty = threadIdx.x >> 5;  // ty 0..7
#pragma unroll
    for (int r = 0; r < 4; r++) {
        const int row = by + ty * 4 + r;
        tile[tx][ty * 4 + r] = f2bf(W[(size_t)row * 1024 + bx + tx]);
    }
    __syncthreads();
#pragma unroll
    for (int r = 0; r < 4; r++) {
        const int col = bx + ty * 4 + r;
        WT[(size_t)col * 1024 + by + tx] = tile[ty * 4 + r][tx];
    }
}

// ---------------------------------------------------------------------------
// tr2: Wp (1024x512 fp32, K-major) -> WphT/WplT (512x1024 bf16 hi/lo).
// ---------------------------------------------------------------------------
__global__ __launch_bounds__(256) void tr2_k(const float* __restrict__ Wp,
                                             unsigned short* __restrict__ WphT,
                                             unsigned short* __restrict__ WplT)
{
    __shared__ float tile[32][33];
    const int bx = blockIdx.x * 32;   // n base (0..511)
    const int by = blockIdx.y * 32;   // k base (0..1023)
    const int tx = threadIdx.x & 31, ty = threadIdx.x >> 5;
#pragma unroll
    for (int r = 0; r < 4; r++) {
        const int row = by + ty * 4 + r;
        tile[tx][ty * 4 + r] = Wp[(size_t)row * 512 + bx + tx];
    }
    __syncthreads();
#pragma unroll
    for (int r = 0; r < 4; r++) {
        const int col = bx + ty * 4 + r;      // n
        const float v = tile[ty * 4 + r][tx];
        const unsigned short hi = f2bf(v);
        const unsigned short lo = f2bf(v - bf2f(hi));
        WphT[(size_t)col * 1024 + by + tx] = hi;
        WplT[(size_t)col * 1024 + by + tx] = lo;
    }
}

// ---------------------------------------------------------------------------
// qkv: fused Q/K/V projection. (16384x3072) = xb @ [WqT;WkT;WvT]^T.
// 128x128 tile, BK=32, TRIPLE-buffered LDS + counted vmcnt (T4): each step
// prefetches tile t+2 and ends with s_waitcnt vmcnt(4) + raw s_barrier, so
// the wait covers only loads issued a FULL STEP earlier — the just-issued 4
// stay in flight (never drain to 0 in the loop; m218's +38-73% lever).
// Tail steps stage a dummy tile (k0=0) into the unused buffer to keep the
// outstanding count uniform; a full __syncthreads() drains before epilogue.
// Epilogues unchanged from r6 (bit-identical math): acc -> LDS tile ->
// coalesced 16B stores; Q -> Qf frag-linear, K/V -> KVf scatter-B-frag.
// ---------------------------------------------------------------------------
__global__ __launch_bounds__(256) void qkv_k(
    const unsigned short* __restrict__ Abf, const unsigned short* __restrict__ BT,
    const float* __restrict__ mask, unsigned short* __restrict__ Qf,
    unsigned short* __restrict__ KVf)
{
    __shared__ short sMem[24576];   // 48 KB: 3 x (A 8KB ++ B 8KB); epilogue tile
    const int tid = threadIdx.x;
    const int w  = tid >> 6;          // wave 0..3
    const int ln = tid & 63;          // lane
    const int wm = w & 1, wn = w >> 1;
    // XCD remap: (xcd, colgroup of 12, band of 16, colblk-in-group)
    const int id   = blockIdx.y * 24 + blockIdx.x;
    const int xcd  = id & 7, kk = id >> 3;        // kk in [0,384)
    const int cg   = kk / 192, rem = kk % 192;
    const int band = xcd * 16 + rem / 12;
    const int colblk = cg * 12 + rem % 12;
    const int row0 = band * 128;
    const int col0 = colblk * 128;
    const int lr = ln >> 4, lc = ln & 15;

    f32x4 acc[4][4];
#pragma unroll
    for (int i = 0; i < 4; i++)
#pragma unroll
        for (int j = 0; j < 4; j++) acc[i][j] = (f32x4){0.f, 0.f, 0.f, 0.f};

    const int ia0 = 2 * w, ia1 = 2 * w + 1;
    const size_t gA0 = (size_t)(row0 + ia0 * 16 + lc) * 1024 + lr * 8;
    const size_t gA1 = (size_t)(row0 + ia1 * 16 + lc) * 1024 + lr * 8;
    const size_t gB0 = (size_t)(col0 + ia0 * 16 + lc) * 1024 + lr * 8;
    const size_t gB1 = (size_t)(col0 + ia1 * 16 + lc) * 1024 + lr * 8;

    auto STAGE = [&](int buf, int k0) {
        short* bb = sMem + buf * 8192;
        GLD16(&bb[ia0 * 512], Abf + gA0 + k0);
        GLD16(&bb[ia1 * 512], Abf + gA1 + k0);
        GLD16(&bb[4096 + ia0 * 512], BT + gB0 + k0);
        GLD16(&bb[4096 + ia1 * 512], BT + gB1 + k0);
    };

    STAGE(0, 0);
    STAGE(1, 32);
    asm volatile("s_waitcnt vmcnt(4)" ::: "memory");   // buf0 ready; buf1 in flight
    __builtin_amdgcn_s_barrier();
    for (int t = 0; t < 32; t++) {
        STAGE((t + 2) % 3, (t + 2 < 32) ? (t + 2) * 32 : 0);  // tail: dummy stage
        const short* bb = sMem + (t % 3) * 8192;
        bf16x8 af[4], bfr[4];
#pragma unroll
        for (int ib = 0; ib < 4; ib++)
            af[ib] = *(const bf16x8*)&bb[(wm * 4 + ib) * 512 + ln * 8];
#pragma unroll
        for (int jb = 0; jb < 4; jb++)
            bfr[jb] = *(const bf16x8*)&bb[4096 + (wn * 4 + jb) * 512 + ln * 8];
#pragma unroll
        for (int ib = 0; ib < 4; ib++)
#pragma unroll
            for (int jb = 0; jb < 4; jb++)
                acc[ib][jb] = __builtin_amdgcn_mfma_f32_16x16x32_bf16(
                    af[ib], bfr[jb], acc[ib][jb], 0, 0, 0);
        asm volatile("s_waitcnt vmcnt(4)" ::: "memory");  // next tile ready; this
        __builtin_amdgcn_s_barrier();                     // step's 4 stay in flight
    }
    __syncthreads();                     // drain all (incl. dummy) before reuse

    const int proj = colblk >> 3;        // 0=Q 1=K 2=V
    const int b    = row0 >> 12;
    const int h0   = (colblk & 7) * 2;
    short* sT = sMem;                    // 32 KB epilogue tile (of 48 KB)

    if (proj == 0) {
#pragma unroll
        for (int ib = 0; ib < 4; ib++) {
#pragma unroll
            for (int r = 0; r < 4; r++) {
                const int tt = wm * 64 + ib * 16 + lr * 4 + r;   // 0..127
                const float mval = mask[row0 + tt];
#pragma unroll
                for (int jb = 0; jb < 4; jb++) {
                    const int d = jb * 16 + lc;
                    const int e = ((tt >> 4) * 2 + (d >> 5)) * 512 +
                                  ((tt & 15) + ((d >> 3) & 3) * 16) * 8 + (d & 7);
                    sT[wn * 8192 + e] = (short)f2bf(acc[ib][jb][r] * mval);
                }
            }
        }
        __syncthreads();
        const int tile = (row0 & (TT - 1)) >> 7;
#pragma unroll
        for (int i = 0; i < 8; i++) {
            const int flat = i * 256 + tid;          // 16B chunk id 0..2047
            const int h_l  = flat >> 10;
            const int off  = (flat & 1023) * 8;
            unsigned short* dst = Qf + (size_t)(b * HH + h0 + h_l) * 262144
                                + (size_t)tile * 8192 + off;
            *(uint4*)dst = *(const uint4*)&sT[h_l * 8192 + off];
        }
    } else {
        const int voff = (proj == 2) ? 4 : 0;
#pragma unroll
        for (int ib = 0; ib < 4; ib++) {
#pragma unroll
            for (int r = 0; r < 4; r++) {
                const int tt128 = wm * 64 + ib * 16 + lr * 4 + r;
                const float mval = mask[row0 + tt128];
                const int chunk = tt128 >> 6, tt6 = tt128 & 63;
                const int rbase = (wn * 2 + chunk) * 4096 +
                                  ((tt6 >> 3) & 3) * 128 + lc * 8 + (tt6 & 7);
                const int t5 = (tt6 >> 5) * 4 * 512;
#pragma unroll
                for (int jb = 0; jb < 4; jb++)
                    sT[rbase + t5 + jb * 512] = (short)f2bf(acc[ib][jb][r] * mval);
            }
        }
        __syncthreads();
        const int gc0 = (row0 & (TT - 1)) >> 6;
#pragma unroll
        for (int i = 0; i < 8; i++) {
            const int flat = i * 256 + tid;          // 16B chunk id 0..2047
            const int bf = flat >> 6;                // 1KB block 0..31
            const int wi = flat & 63;
            const int h_l = bf >> 4, chunk = (bf >> 3) & 1;
            const int tt5 = (bf >> 2) & 1, nb = bf & 3;
            const int lidx = (h_l * 2 + chunk) * 4096 + (tt5 * 4 + nb) * 512 + wi * 8;
            const size_t gidx = (size_t)(b * HH + h0 + h_l) * 524288
                              + (size_t)(gc0 + chunk) * 8192
                              + (size_t)(tt5 * 8 + nb + voff) * 512 + wi * 8;
            *(uint4*)&KVf[gidx] = *(const uint4*)&sT[lidx];
        }
    }
}

// ---------------------------------------------------------------------------
// out: C(16384x1024) = attb @ WoutT^T + bias, fp32 row-major. Triple-buffer
// + counted vmcnt (same T4 structure as qkv) + XCD remap (1024 = 8x16x8).
// ---------------------------------------------------------------------------
__global__ __launch_bounds__(256) void out_k(
    const unsigned short* __restrict__ Abf, const unsigned short* __restrict__ BT,
    const float* __restrict__ bias, float* __restrict__ C)
{
    __shared__ short sMem[24576];   // 48 KB: 3 x (A 8KB ++ B 8KB)
    const int tid = threadIdx.x;
    const int w  = tid >> 6, ln = tid & 63;
    const int wm = w & 1, wn = w >> 1;
    const int id  = blockIdx.y * 8 + blockIdx.x;
    const int xcd = id & 7, kk = id >> 3;          // kk in [0,128)
    const int row0 = (xcd * 16 + (kk >> 3)) * 128;
    const int col0 = (kk & 7) * 128;
    const int lr = ln >> 4, lc = ln & 15;

    f32x4 acc[4][4];
#pragma unroll
    for (int i = 0; i < 4; i++)
#pragma unroll
        for (int j = 0; j < 4; j++) acc[i][j] = (f32x4){0.f, 0.f, 0.f, 0.f};

    const int ia0 = 2 * w, ia1 = 2 * w + 1;
    const size_t gA0 = (size_t)(row0 + ia0 * 16 + lc) * 1024 + lr * 8;
    const size_t gA1 = (size_t)(row0 + ia1 * 16 + lc) * 1024 + lr * 8;
    const size_t gB0 = (size_t)(col0 + ia0 * 16 + lc) * 1024 + lr * 8;
    const size_t gB1 = (size_t)(col0 + ia1 * 16 + lc) * 1024 + lr * 8;

    auto STAGE = [&](int buf, int k0) {
        short* bb = sMem + buf * 8192;
        GLD16(&bb[ia0 * 512], Abf + gA0 + k0);
        GLD16(&bb[ia1 * 512], Abf + gA1 + k0);
        GLD16(&bb[4096 + ia0 * 512], BT + gB0 + k0);
        GLD16(&bb[4096 + ia1 * 512], BT + gB1 + k0);
    };

    STAGE(0, 0);
    STAGE(1, 32);
    asm volatile("s_waitcnt vmcnt(4)" ::: "memory");
    __builtin_amdgcn_s_barrier();
    for (int t = 0; t < 32; t++) {
        STAGE((t + 2) % 3, (t + 2 < 32) ? (t + 2) * 32 : 0);
        const short* bb = sMem + (t % 3) * 8192;
        bf16x8 af[4], bfr[4];
#pragma unroll
        for (int ib = 0; ib < 4; ib++)
            af[ib] = *(const bf16x8*)&bb[(wm * 4 + ib) * 512 + ln * 8];
#pragma unroll
        for (int jb = 0; jb < 4; jb++)
            bfr[jb] = *(const bf16x8*)&bb[4096 + (wn * 4 + jb) * 512 + ln * 8];
#pragma unroll
        for (int ib = 0; ib < 4; ib++)
#pragma unroll
            for (int jb = 0; jb < 4; jb++)
                acc[ib][jb] = __builtin_amdgcn_mfma_f32_16x16x32_bf16(
                    af[ib], bfr[jb], acc[ib][jb], 0, 0, 0);
        asm volatile("s_waitcnt vmcnt(4)" ::: "memory");
        __builtin_amdgcn_s_barrier();
    }

#pragma unroll
    for (int ib = 0; ib < 4; ib++) {
#pragma unroll
        for (int r = 0; r < 4; r++) {
            const int gr = row0 + wm * 64 + ib * 16 + lr * 4 + r;
#pragma unroll
            for (int jb = 0; jb < 4; jb++) {
                const int col = col0 + wn * 64 + jb * 16 + lc;
                C[(size_t)gr * 1024 + col] = acc[ib][jb][r] + bias[col];
            }
        }
    }
}

// ---------------------------------------------------------------------------
// projm: error-compensated bf16x2 MFMA GEMM for the assignment projections.
// (2-phase dbuf kept: 3 buffers would need 96KB LDS -> 1 block/CU.)
// ---------------------------------------------------------------------------
__global__ __launch_bounds__(256) void projm_k(
    const unsigned short* __restrict__ Ah, const unsigned short* __restrict__ Al,
    const unsigned short* __restrict__ Bh, const unsigned short* __restrict__ Bl,
    const float* __restrict__ mask, float* __restrict__ P)
{
    __shared__ short sAh[2][4096];
    __shared__ short sAl[2][4096];
    __shared__ short sBh[2][4096];
    __shared__ short sBl[2][4096];
    const int tid = threadIdx.x;
    const int w  = tid >> 6;
    const int ln = tid & 63;
    const int wm = w & 1, wn = w >> 1;
    const int id  = blockIdx.y * 4 + blockIdx.x;
    const int xcd = id & 7, kk = id >> 3;          // kk in [0,64)
    const int row0 = (xcd * 16 + (kk >> 2)) * 128;
    const int col0 = (kk & 3) * 128;
    const int lr = ln >> 4, lc = ln & 15;

    f32x4 acc[4][4];
#pragma unroll
    for (int i = 0; i < 4; i++)
#pragma unroll
        for (int j = 0; j < 4; j++) acc[i][j] = (f32x4){0.f, 0.f, 0.f, 0.f};

    const int ia0 = 2 * w, ia1 = 2 * w + 1;
    const size_t gA0 = (size_t)(row0 + ia0 * 16 + lc) * 1024 + lr * 8;
    const size_t gA1 = (size_t)(row0 + ia1 * 16 + lc) * 1024 + lr * 8;
    const size_t gB0 = (size_t)(col0 + ia0 * 16 + lc) * 1024 + lr * 8;
    const size_t gB1 = (size_t)(col0 + ia1 * 16 + lc) * 1024 + lr * 8;

    auto STAGE = [&](int buf, int k0) {
        GLD16(&sAh[buf][ia0 * 512], Ah + gA0 + k0);
        GLD16(&sAh[buf][ia1 * 512], Ah + gA1 + k0);
        GLD16(&sAl[buf][ia0 * 512], Al + gA0 + k0);
        GLD16(&sAl[buf][ia1 * 512], Al + gA1 + k0);
        GLD16(&sBh[buf][ia0 * 512], Bh + gB0 + k0);
        GLD16(&sBh[buf][ia1 * 512], Bh + gB1 + k0);
        GLD16(&sBl[buf][ia0 * 512], Bl + gB0 + k0);
        GLD16(&sBl[buf][ia1 * 512], Bl + gB1 + k0);
    };

    STAGE(0, 0);
    __syncthreads();
    for (int t = 0; t < 32; t++) {
        const int cur = t & 1;
        if (t < 31) STAGE(cur ^ 1, (t + 1) * 32);
        bf16x8 ah[4], al[4], bh[4], bl[4];
#pragma unroll
        for (int ib = 0; ib < 4; ib++) {
            ah[ib] = *(const bf16x8*)&sAh[cur][(wm * 4 + ib) * 512 + ln * 8];
            al[ib] = *(const bf16x8*)&sAl[cur][(wm * 4 + ib) * 512 + ln * 8];
        }
#pragma unroll
        for (int jb = 0; jb < 4; jb++) {
            bh[jb] = *(const bf16x8*)&sBh[cur][(wn * 4 + jb) * 512 + ln * 8];
            bl[jb] = *(const bf16x8*)&sBl[cur][(wn * 4 + jb) * 512 + ln * 8];
        }
#pragma unroll
        for (int ib = 0; ib < 4; ib++)
#pragma unroll
            for (int jb = 0; jb < 4; jb++) {
                acc[ib][jb] = __builtin_amdgcn_mfma_f32_16x16x32_bf16(
                    ah[ib], bh[jb], acc[ib][jb], 0, 0, 0);
                acc[ib][jb] = __builtin_amdgcn_mfma_f32_16x16x32_bf16(
                    ah[ib], bl[jb], acc[ib][jb], 0, 0, 0);
                acc[ib][jb] = __builtin_amdgcn_mfma_f32_16x16x32_bf16(
                    al[ib], bh[jb], acc[ib][jb], 0, 0, 0);
            }
        __syncthreads();
    }

#pragma unroll
    for (int ib = 0; ib < 4; ib++) {
#pragma unroll
        for (int r = 0; r < 4; r++) {
            const int gr = row0 + wm * 64 + ib * 16 + lr * 4 + r;
            const float mval = mask[gr];
            const int b = gr >> 12, t = gr & (TT - 1);
#pragma unroll
            for (int jb = 0; jb < 4; jb++) {
                const int c = col0 + wn * 64 + jb * 16 + lc;   // 0..511
                const int h = c >> 5, p = c & 31;
                P[(((size_t)(b * HH + h) * TT + t) * 32) + p] =
                    acc[ib][jb][r] * mval;
            }
        }
    }
}

// ---------------------------------------------------------------------------
// wproj: Wproj[k][h*32+p] = sum_d Wk[k][h*64+d] * planesT[d][p].  (fp32)
// ---------------------------------------------------------------------------
__global__ __launch_bounds__(256) void wproj_k(
    const float* __restrict__ Wk, const float* __restrict__ planesT,
    float* __restrict__ Wp)
{
    __shared__ float sW[1024];
    __shared__ float sP[2048];
    const int tid = threadIdx.x;
    const int k = blockIdx.x;
    for (int i = tid; i < 1024; i += 256) sW[i] = Wk[(size_t)k * 1024 + i];
    for (int i = tid; i < 2048; i += 256) sP[i] = planesT[i];
    __syncthreads();
#pragma unroll
    for (int c0 = 0; c0 < 2; c0++) {
        const int c = c0 * 256 + tid;          // 0..511
        const int h = c >> 5, p = c & 31;
        float s = 0.f;
#pragma unroll
        for (int d = 0; d < 64; d++)
            s = fmaf(sW[h * 64 + d], sP[d * 32 + p], s);
        Wp[(size_t)k * 512 + c] = s;
    }
}

// ---------------------------------------------------------------------------
// Zero-fill gBK ++ gBV ++ gA (contiguous, 1,056,768 floats).
// ---------------------------------------------------------------------------
__global__ __launch_bounds__(256) void zero_k(float* __restrict__ p)
{
    const size_t i = ((size_t)blockIdx.x * 256 + threadIdx.x) * 4;
    *(float4*)&p[i] = make_float4(0.f, 0.f, 0.f, 0.f);
}

// ---------------------------------------------------------------------------
// Assignment: reads precomputed fp32-accurate proj.
// ---------------------------------------------------------------------------
__global__ __launch_bounds__(256) void assign_k(
    const float* __restrict__ Pj, const float* __restrict__ protosT,
    const float* __restrict__ logit_temp,
    unsigned char* __restrict__ aIdx, float* __restrict__ aW,
    float* __restrict__ gA)
{
    __shared__ float sPr[4][16];
    __shared__ float sCnt[SS];
    const int tid = threadIdx.x;
    const int tc = blockIdx.x;
    const int bh = blockIdx.y;

    if (tid < 64)  ((float*)sPr)[tid] = protosT[tid];
    if (tid < SS)  sCnt[tid] = 0.f;
    __syncthreads();

    const float scale = fminf(fmaxf(__expf(logit_temp[0]), 0.01f), 20.0f);
    const float inv_scale = 1.0f / scale;

    const int t = tc * 256 + tid;
    const float* pr = Pj + ((size_t)bh * TT + t) * 32;
    float proj[32];
#pragma unroll
    for (int j = 0; j < 8; j++) {
        const float4 v = *(const float4*)&pr[j * 4];
        proj[j * 4 + 0] = v.x; proj[j * 4 + 1] = v.y;
        proj[j * 4 + 2] = v.z; proj[j * 4 + 3] = v.w;
    }
#pragma unroll
    for (int p = 0; p < 32; p++) proj[p] = tanhf(proj[p]) * inv_scale;

    unsigned char idx[16];
    float wv[16];
#pragma unroll
    for (int l = 0; l < 8; l++) {
        float g[16];
#pragma unroll
        for (int r = 0; r < 16; r++)
            g[r] = proj[l * 4 + 0] * sPr[0][r] + proj[l * 4 + 1] * sPr[1][r] +
                   proj[l * 4 + 2] * sPr[2][r] + proj[l * 4 + 3] * sPr[3][r];
        float mx = g[0];
#pragma unroll
        for (int r = 1; r < 16; r++) mx = fmaxf(mx, g[r]);
        float Zs = 0.f;
#pragma unroll
        for (int r = 0; r < 16; r++) Zs += __expf(g[r] - mx);
        int a = 0; float ga = g[0];
#pragma unroll
        for (int r = 1; r < 16; r++) { if (g[r] > ga) { ga = g[r]; a = r; } }
        int b2 = (a == 0) ? 1 : 0; float gb = g[b2];
#pragma unroll
        for (int r = 0; r < 16; r++) { if (r != a && g[r] > gb) { gb = g[r]; b2 = r; } }
        const float pa = __expf(ga - mx) / Zs;
        const float pb = __expf(gb - mx) / Zs;
        const float den = pa + pb + 1e-6f;
        const float wa = pa / den, wb = pb / den;
        idx[l * 2 + 0] = (unsigned char)(l * 16 + a);  wv[l * 2 + 0] = wa;
        idx[l * 2 + 1] = (unsigned char)(l * 16 + b2); wv[l * 2 + 1] = wb;
        atomicAdd(&sCnt[l * 16 + a],  wa);
        atomicAdd(&sCnt[l * 16 + b2], wb);
    }
    const size_t off = (size_t)bh * TT + t;
    uint32_t pk[4];
#pragma unroll
    for (int j = 0; j < 4; j++)
        pk[j] = (uint32_t)idx[j * 4] | ((uint32_t)idx[j * 4 + 1] << 8) |
                ((uint32_t)idx[j * 4 + 2] << 16) | ((uint32_t)idx[j * 4 + 3] << 24);
    *(uint4*)&aIdx[off * 16] = make_uint4(pk[0], pk[1], pk[2], pk[3]);
#pragma unroll
    for (int j = 0; j < 4; j++)
        *(float4*)&aW[off * 16 + j * 4] =
            make_float4(wv[j * 4], wv[j * 4 + 1], wv[j * 4 + 2], wv[j * 4 + 3]);
    __syncthreads();
    if (tid < SS) atomicAdd(&gA[bh * SS + tid], sCnt[tid]);
}

// ---------------------------------------------------------------------------
// Scatter as MFMA GEMM. KV tiles arrive pre-formatted (KVf) -> 4 GLD16/wave.
// ---------------------------------------------------------------------------
__global__ __launch_bounds__(256) void scatter4_k(
    const unsigned short* __restrict__ KVf,
    const unsigned char* __restrict__ aIdx, const float* __restrict__ aW,
    float* __restrict__ gBK, float* __restrict__ gBV)
{
    __shared__ short sA[8192];
    __shared__ short sB[8192];
    const int tid = threadIdx.x;
    const int tc = blockIdx.x;   // 8
    const int bh = blockIdx.y;   // 64
    const int w  = tid >> 6, ln = tid & 63;
    const int wm = w & 1, wn = w >> 1;

    f32x4 acc[4][4];
#pragma unroll
    for (int i = 0; i < 4; i++)
#pragma unroll
        for (int j = 0; j < 4; j++) acc[i][j] = (f32x4){0.f, 0.f, 0.f, 0.f};

    const size_t kvbase = (size_t)bh * 524288;
    const int ptt = tid >> 2, pg = tid & 3;

    for (int c = 0; c < 8; c++) {
        __syncthreads();                 // prior MFMA reads of sA/sB done
        const size_t cbase = kvbase + (size_t)(tc * 8 + c) * 8192;
#pragma unroll
        for (int i = 0; i < 4; i++) {
            const int seg = w * 4 + i;   // wave-uniform
            GLD16(&sB[seg * 512], KVf + cbase + seg * 512 + ln * 8);
        }
        {   // zero P^T region (16 KB)
            const uint4 z = make_uint4(0u, 0u, 0u, 0u);
#pragma unroll
            for (int r = 0; r < 4; r++)
                *(uint4*)&sA[(r * 256 + tid) * 8] = z;
        }
        __syncthreads();                 // zero visible
        {   // scatter P^T: A(s = idx, k = ptt)
            const int t0 = tc * 512 + c * 64;
            const size_t off = (size_t)bh * TT + (t0 + ptt);
            const uint32_t pk = ((const uint32_t*)aIdx)[off * 4 + pg];
            const float4 wv = *(const float4*)&aW[off * 16 + pg * 4];
            const float w4[4] = {wv.x, wv.y, wv.z, wv.w};
#pragma unroll
            for (int q = 0; q < 4; q++) {
                const int s = (pk >> (8 * q)) & 255;
                sA[((ptt >> 5) * 8 + (s >> 4)) * 512 + ((ptt >> 3) & 3) * 128 +
                   (s & 15) * 8 + (ptt & 7)] = f2bf(w4[q]);
            }
        }
        __syncthreads();                 // tiles ready (drains GLD16 vmcnt)
#pragma unroll
        for (int ks = 0; ks < 2; ks++) {
            bf16x8 af[4], bfr[4];
#pragma unroll
            for (int ib = 0; ib < 4; ib++)
                af[ib] = *(const bf16x8*)&sA[(ks * 8 + wm * 4 + ib) * 512 + ln * 8];
#pragma unroll
            for (int jb = 0; jb < 4; jb++)
                bfr[jb] = *(const bf16x8*)&sB[(ks * 8 + wn * 4 + jb) * 512 + ln * 8];
#pragma unroll
            for (int ib = 0; ib < 4; ib++)
#pragma unroll
                for (int jb = 0; jb < 4; jb++)
                    acc[ib][jb] = __builtin_amdgcn_mfma_f32_16x16x32_bf16(
                        af[ib], bfr[jb], acc[ib][jb], 0, 0, 0);
        }
    }

    const int lr = ln >> 4, lc = ln & 15;
#pragma unroll
    for (int ib = 0; ib < 4; ib++) {
#pragma unroll
        for (int r = 0; r < 4; r++) {
            const int s = wm * 64 + ib * 16 + lr * 4 + r;
#pragma unroll
            for (int jb = 0; jb < 4; jb++) {
                const int col = wn * 64 + jb * 16 + lc;
                if (col < 64)
                    atomicAdd(&gBK[(size_t)bh * (SS * DIMM) + s * DIMM + col],
                              acc[ib][jb][r]);
                else
                    atomicAdd(&gBV[(size_t)bh * (SS * DIMM) + s * DIMM + (col - 64)],
                              acc[ib][jb][r]);
            }
        }
    }
}

// ---------------------------------------------------------------------------
// bprep: bucket K/V fp32 -> count-normalized bf16 fragment-linear layouts.
// ---------------------------------------------------------------------------
__global__ __launch_bounds__(256) void bprep_k(
    const float* __restrict__ gBK, const float* __restrict__ gBV,
    const float* __restrict__ gA,
    unsigned short* __restrict__ Kf, unsigned short* __restrict__ VTf)
{
    __shared__ float sInv[SS];
    const int tid = threadIdx.x;
    const int bh = blockIdx.y;
    if (tid < SS) sInv[tid] = 1.0f / (gA[bh * SS + tid] + 1e-6f);
    __syncthreads();
#pragma unroll
    for (int it = 0; it < 8; it++) {
        const int i = (blockIdx.x * 8 + it) * 256 + tid;   // 0..8191
        const int s = i >> 6, d = i & 63;
        const float kv = gBK[(size_t)bh * 8192 + i] * sInv[s];
        const float vv = gBV[(size_t)bh * 8192 + i] * sInv[s];
        const int ek = ((s >> 4) * 2 + (d >> 5)) * 512 +
                       ((s & 15) + ((d >> 3) & 3) * 16) * 8 + (d & 7);
        const int ev = ((d >> 4) * 4 + (s >> 5)) * 512 +
                       ((d & 15) + ((s >> 3) & 3) * 16) * 8 + (s & 7);
        Kf[(size_t)bh * 8192 + ek]  = f2bf(kv);
        VTf[(size_t)bh * 8192 + ev] = f2bf(vv);
    }
}

// ---------------------------------------------------------------------------
// MFMA attention (unchanged).
// ---------------------------------------------------------------------------
__global__ __launch_bounds__(256) void attn_m(
    const unsigned short* __restrict__ Qf, const unsigned short* __restrict__ Kf,
    const unsigned short* __restrict__ VTf, unsigned short* __restrict__ attb)
{
    __shared__ short sQ[8192];
    __shared__ short sK[8192];
    __shared__ short sVT[8192];
    __shared__ short sP[16384];
    const int tid = threadIdx.x;
    const int tc = blockIdx.x;     // 32 tiles of 128 tokens
    const int bh = blockIdx.y;     // 64
    const int w = tid >> 6, l = tid & 63;

    const size_t qbase  = (size_t)bh * 262144 + (size_t)tc * 8192;
    const size_t kvbase = (size_t)bh * 8192;
#pragma unroll
    for (int i = 0; i < 4; i++) {
        const int o = (i * 256 + w * 64) * 8;
        GLD16(&sQ[o],  Qf  + qbase  + o + l * 8);
        GLD16(&sK[o],  Kf  + kvbase + o + l * 8);
        GLD16(&sVT[o], VTf + kvbase + o + l * 8);
    }
    __syncthreads();

    f32x4 acc[2][8];
#pragma unroll
    for (int i = 0; i < 2; i++)
#pragma unroll
        for (int j = 0; j < 8; j++) acc[i][j] = (f32x4){0.f, 0.f, 0.f, 0.f};

#pragma unroll
    for (int ks = 0; ks < 2; ks++) {
        const bf16x8 a0 = *(const bf16x8*)&sQ[((w * 2 + 0) * 2 + ks) * 512 + l * 8];
        const bf16x8 a1 = *(const bf16x8*)&sQ[((w * 2 + 1) * 2 + ks) * 512 + l * 8];
#pragma unroll
        for (int jb = 0; jb < 8; jb++) {
            const bf16x8 b = *(const bf16x8*)&sK[(jb * 2 + ks) * 512 + l * 8];
            acc[0][jb] = __builtin_amdgcn_mfma_f32_16x16x32_bf16(a0, b, acc[0][jb], 0, 0, 0);
            acc[1][jb] = __builtin_amdgcn_mfma_f32_16x16x32_bf16(a1, b, acc[1][jb], 0, 0, 0);
        }
    }

#pragma unroll
    for (int ib = 0; ib < 2; ib++) {
        const int mb = w * 2 + ib;
#pragma unroll
        for (int r = 0; r < 4; r++) {
            float v[8];
            float mx = -INFINITY;
#pragma unroll
            for (int jb = 0; jb < 8; jb++) {
                v[jb] = acc[ib][jb][r] * 0.125f;
                mx = fmaxf(mx, v[jb]);
            }
            mx = fmaxf(mx, __shfl_xor(mx, 1));
            mx = fmaxf(mx, __shfl_xor(mx, 2));
            mx = fmaxf(mx, __shfl_xor(mx, 4));
            mx = fmaxf(mx, __shfl_xor(mx, 8));
            float Z = 0.f;
#pragma unroll
            for (int jb = 0; jb < 8; jb++) { v[jb] = __expf(v[jb] - mx); Z += v[jb]; }
            Z += __shfl_xor(Z, 1);
            Z += __shfl_xor(Z, 2);
            Z += __shfl_xor(Z, 4);
            Z += __shfl_xor(Z, 8);
            const float invZ = 1.0f / Z;
            const int ttl = (l >> 4) * 4 + r;
#pragma unroll
            for (int jb = 0; jb < 8; jb++) {
                int e = (mb * 4 + (jb >> 1)) * 512 +
                        (ttl + (((jb * 2 + ((l >> 3) & 1)) & 3) * 16)) * 8 + (l & 7);
                e ^= ((e >> 7) & 3) << 4;
                sP[e] = (short)f2bf(v[jb] * invZ);
            }
        }
    }

    f32x4 acc2[2][4];
#pragma unroll
    for (int i = 0; i < 2; i++)
#pragma unroll
        for (int j = 0; j < 4; j++) acc2[i][j] = (f32x4){0.f, 0.f, 0.f, 0.f};

#pragma unroll
    for (int ks = 0; ks < 4; ks++) {
        bf16x8 a[2];
#pragma unroll
        for (int ib = 0; ib < 2; ib++) {
            int ia = ((w * 2 + ib) * 4 + ks) * 512 + l * 8;
            ia ^= ((ia >> 7) & 3) << 4;
            a[ib] = *(const bf16x8*)&sP[ia];
        }
#pragma unroll
        for (int jb = 0; jb < 4; jb++) {
            const bf16x8 b = *(const bf16x8*)&sVT[(jb * 4 + ks) * 512 + l * 8];
            acc2[0][jb] = __builtin_amdgcn_mfma_f32_16x16x32_bf16(a[0], b, acc2[0][jb], 0, 0, 0);
            acc2[1][jb] = __builtin_amdgcn_mfma_f32_16x16x32_bf16(a[1], b, acc2[1][jb], 0, 0, 0);
        }
    }

    const int b = bh >> 4, h = bh & 15;
#pragma unroll
    for (int ib = 0; ib < 2; ib++) {
#pragma unroll
        for (int r = 0; r < 4; r++) {
            const int t = tc * 128 + w * 32 + ib * 16 + (l >> 4) * 4 + r;
            unsigned short* outp = attb + ((size_t)(b * TT + t)) * DD + h * DIMM;
#pragma unroll
            for (int jb = 0; jb < 4; jb++)
                outp[jb * 16 + (l & 15)] = f2bf(acc2[ib][jb][r]);
        }
    }
}

// ---------------------------------------------------------------------------
// Launcher. Workspace (float offsets):
//   ws+0: Qf bf16 32MB (Wp/WphT/WplT scratch there before qkv) |
//   ws+(1<<24): BTall bf16 6MB (region otherwise dead) |
//   ws+(2<<24): xlo (until projm) -> KVf bf16 33.5MB (qkv..scatter) ->
//     attb bf16 (after scatter); WoutT at ws+41943040 (disjoint) |
//   ws+(3<<24): gBK | +512K gBV | +512K gA |
//   ws+51388416: xb (dead after qkv; then aW; aIdx at 55582720;
//     Kf 56631296; VTf 56893440).
//   d_out: Pj fp32 [0, 8388608) — overwritten by final out_k.
// ---------------------------------------------------------------------------
extern "C" void kernel_launch(void* const* d_in, const int* in_sizes, int n_in,
                              void* d_out, int out_size, void* d_ws, size_t ws_size,
                              hipStream_t stream)
{
    const float* x       = (const float*)d_in[0];
    const float* mask    = (const float*)d_in[1];
    const float* Wq      = (const float*)d_in[2];
    const float* Wk      = (const float*)d_in[3];
    const float* Wv      = (const float*)d_in[4];
    const float* Wout    = (const float*)d_in[5];
    const float* b_out   = (const float*)d_in[6];
    const float* planesT = (const float*)d_in[7];
    const float* protosT = (const float*)d_in[8];
    const float* ltemp   = (const float*)d_in[9];
    float* out = (float*)d_out;

    float* ws  = (float*)d_ws;
    float* gBK = ws + (3u << 24);
    float* gBV = gBK + 524288;
    float* gA  = gBV + 524288;
    unsigned short* Qf    = (unsigned short*)ws;
    unsigned short* BTall = (unsigned short*)(ws + (1u << 24));
    unsigned short* KVf   = (unsigned short*)(ws + (2u << 24));
    unsigned short* xlo   = KVf;                             // dead before qkv
    unsigned short* xb    = (unsigned short*)(ws + 51388416);
    float*          Wp    = ws;                              // dead before qkv
    unsigned short* WphT  = (unsigned short*)(ws + 524288);
    unsigned short* WplT  = (unsigned short*)(ws + 786432);
    float*          aW    = ws + 51388416;                   // aliases xb (dead)
    unsigned char*  aIdx  = (unsigned char*)(ws + 55582720);
    unsigned short* Kf    = (unsigned short*)(ws + 56631296);
    unsigned short* VTf   = (unsigned short*)(ws + 56893440);
    unsigned short* attb  = KVf;                             // KVf dead after scatter
    unsigned short* WoutT = (unsigned short*)(ws + 41943040);
    float*          Pj    = (float*)d_out;                   // d_out[0 : 8388608)

    const dim3 tg(32, 32);     // transpose grid
    const dim3 t2g(16, 32);    // Wp transpose grid
    const dim3 pg(4, 128);     // projm grid
    const dim3 qg(24, 128);    // fused qkv grid
    const dim3 og(8, 128);     // out gemm grid

    cvt2_k<<<8192, 256, 0, stream>>>(x, xb, xlo);

    // assignment projections (xlo in KVf region; Wp/WphT/WplT in Qf region)
    wproj_k<<<1024, 256, 0, stream>>>(Wk, planesT, Wp);
    tr2_k<<<t2g, 256, 0, stream>>>(Wp, WphT, WplT);
    projm_k<<<pg, 256, 0, stream>>>(xb, xlo, WphT, WplT, mask, Pj);

    // fused Q/K/V projection (BTall in its own dead region)
    tr_k<<<tg, 256, 0, stream>>>(Wq, BTall);
    tr_k<<<tg, 256, 0, stream>>>(Wk, BTall + 1048576);
    tr_k<<<tg, 256, 0, stream>>>(Wv, BTall + 2097152);
    qkv_k<<<qg, 256, 0, stream>>>(xb, BTall, mask, Qf, KVf);

    zero_k<<<1032, 256, 0, stream>>>(gBK);                   // gBK ++ gBV ++ gA
    assign_k<<<dim3(16, 64), 256, 0, stream>>>(Pj, protosT, ltemp, aIdx, aW, gA);
    scatter4_k<<<dim3(8, 64), 256, 0, stream>>>(KVf, aIdx, aW, gBK, gBV);

    bprep_k<<<dim3(4, 64), 256, 0, stream>>>(gBK, gBV, gA, Kf, VTf);
    tr_k<<<tg, 256, 0, stream>>>(Wout, WoutT);
    attn_m<<<dim3(32, 64), 256, 0, stream>>>(Qf, Kf, VTf, attb);

    out_k<<<og, 256, 0, stream>>>(attb, WoutT, b_out, out);
}